// Round 20
// baseline (750.152 us; speedup 1.0000x reference)
//
#include <hip/hip_runtime.h>
#include <math.h>

#define LSEQ   16384
#define DM     128
#define DI     256
#define DSTATE 64
#define NH     4
#define HD     64
#define CONVD  384
#define DPROJ  644
#define NDIR   6
#define NCHUNK 256      // LSEQ/64
#define BSTR   136      // padded epilogue row stride (u16): 272B = 17x16B

typedef unsigned short u16;
typedef __attribute__((ext_vector_type(8))) __bf16 bf16x8;
typedef __attribute__((ext_vector_type(4))) float f32x4;

union U8 { uint4 v; u16 h[8]; };

__device__ __constant__ int ORD[6][3] = {{0,1,2},{0,2,1},{1,0,2},{1,2,0},{2,0,1},{2,1,0}};

__device__ __forceinline__ float softplus_f(float x){
  float ax = fabsf(x);
  return fmaxf(x, 0.f) + log1pf(__expf(-ax));
}
__device__ __forceinline__ float silu_f(float x){
  return x / (1.f + __expf(-x));
}
__device__ __forceinline__ u16 f2b(float f){
  unsigned u = __float_as_uint(f);
  unsigned r = (u + 0x7fffu + ((u >> 16) & 1u)) >> 16;
  return (u16)r;
}
__device__ __forceinline__ float b2f(u16 h){
  return __uint_as_float(((unsigned)h) << 16);
}
// XOR swizzle for [rows][128B] bf16 LDS tiles: conflict-free ds_read_b128 (T2)
__device__ __forceinline__ int SWZ(int r, int cb){
  return r*128 + (cb ^ ((r & 7) << 4));
}
// swizzle for 256B-row LDS tiles (inproj As)
__device__ __forceinline__ int SWZ2(int r, int cb){
  return r*256 + (cb ^ ((r & 7) << 4));
}
// swizzle for 512B-row LDS tiles (chunk2 Ylds)
__device__ __forceinline__ int SWZ4(int r, int cb){
  return r*512 + (cb ^ ((r & 7) << 4));
}

// ---------------- weight convert to bf16 (+ cursor zeroing) ----------------
#define NW0 (12*768*128)
#define NW1 (12*128*256)
#define NW2 (128*768)
__global__ __launch_bounds__(256) void k_cvt(const float* __restrict__ in_w,
                                             const float* __restrict__ out_w,
                                             const float* __restrict__ fuse_w,
                                             u16* __restrict__ wi, u16* __restrict__ wo,
                                             u16* __restrict__ wf, int* __restrict__ cursor){
  int i = blockIdx.x*256 + threadIdx.x;
  if (i < NDIR*1024) cursor[i] = 0;
  if (i < NW0){
    int dj = i / (768*128), rem = i % (768*128), r = rem >> 7, c = rem & 127;
    float v = (r < DPROJ) ? in_w[((size_t)dj*DPROJ + r)*128 + c] : 0.f;
    wi[i] = f2b(v);
  } else if (i < NW0 + NW1){
    int k = i - NW0;
    wo[k] = f2b(out_w[k]);
  } else if (i < NW0 + NW1 + NW2){
    int k = i - NW0 - NW1;
    wf[k] = f2b(fuse_w[k]);
  }
}

// ---------------- sort ----------------
__global__ __launch_bounds__(256) void k_sort1(const int* __restrict__ coords,
                                               unsigned long long* __restrict__ skey,
                                               int* __restrict__ cursor){
  int i = blockIdx.x*256 + threadIdx.x;
  if (i >= NDIR*LSEQ) return;
  int d = i >> 14, t = i & 16383;
  unsigned k = ((unsigned)coords[t*4 + ORD[d][0]] << 20)
             | ((unsigned)coords[t*4 + ORD[d][1]] << 10)
             |  (unsigned)coords[t*4 + ORD[d][2]];
  skey[i] = ((unsigned long long)k << 14) | (unsigned long long)t;
  atomicAdd(&cursor[(d << 10) + (k >> 20)], 1);
}

__global__ void k_sort_scan(int* __restrict__ cursor, int* __restrict__ starts){
  __shared__ int sh[1024];
  int d = blockIdx.x, t = threadIdx.x;
  int v = cursor[d*1024 + t];
  sh[t] = v; __syncthreads();
  for (int off = 1; off < 1024; off <<= 1){
    int a = (t >= off) ? sh[t-off] : 0;
    __syncthreads();
    sh[t] += a;
    __syncthreads();
  }
  int incl = sh[t], excl = incl - v;
  starts[d*1025 + t] = excl;
  cursor[d*1024 + t] = excl;
  if (t == 1023) starts[d*1025 + 1024] = incl;
}

__global__ __launch_bounds__(256) void k_sort_scatter(const unsigned long long* __restrict__ skey,
                                                      unsigned long long* __restrict__ skey2,
                                                      int* __restrict__ cursor){
  int i = blockIdx.x*256 + threadIdx.x;
  if (i >= NDIR*LSEQ) return;
  int d = i >> 14;
  unsigned long long v = skey[i];
  int b = (int)(v >> 34);
  int pos = atomicAdd(&cursor[(d << 10) + b], 1);
  skey2[(size_t)d*LSEQ + pos] = v;
}

__global__ __launch_bounds__(256) void k_sort_rank(const unsigned long long* __restrict__ skey2,
                                                   const int* __restrict__ starts,
                                                   int* __restrict__ idx){
  int i = blockIdx.x*256 + threadIdx.x;
  if (i >= NDIR*LSEQ) return;
  int d = i >> 14;
  unsigned long long v = skey2[i];
  int b = (int)(v >> 34);
  int s = starts[d*1025 + b], e = starts[d*1025 + b + 1];
  int r = s;
  for (int q = s; q < e; ++q) r += (skey2[(size_t)d*LSEQ + q] < v);
  int orig = (int)(v & 16383ULL);
  idx[(size_t)d*LSEQ + r] = orig;
}

// ---------------- gather ----------------
__global__ __launch_bounds__(256) void k_gather(const float* __restrict__ vec, const int* __restrict__ idx,
                                                float* __restrict__ x, int d_base, int nd){
  int i = blockIdx.x*256 + threadIdx.x;
  if (i >= nd*LSEQ*32) return;
  int c4 = i & 31, r = (i >> 5) & 16383, dz = i >> 19;
  int src = idx[(size_t)(d_base+dz)*LSEQ + r];
  ((float4*)x)[((size_t)dz*LSEQ + r)*32 + c4] = ((const float4*)vec)[(size_t)src*32 + c4];
}

// ---------------- in_proj: 64-row tiles, ONE output n-tile per block; fused LN + conv+silu ----------------
__global__ __launch_bounds__(256) void k_inproj(const float* __restrict__ xres,
    const float* __restrict__ lnw, const float* __restrict__ lnb,
    const u16* __restrict__ wbf, const float* __restrict__ dt_bias,
    const float* __restrict__ conv_w, const float* __restrict__ conv_b,
    u16* __restrict__ zbuf, u16* __restrict__ xact, u16* __restrict__ bnd,
    float* __restrict__ dtb, int d_base, int j){
  __shared__ __align__(16) u16 As[64*128];   // 16KB (row stride 256B, swizzled)
  __shared__ __align__(16) u16 Bs[64*BSTR];  // 17KB (weights use first 16KB w/ SWZ; epilogue uses padded stride)
  __shared__ float cwsh[128][4];
  __shared__ float cbsh[128];
  int bn = blockIdx.x, mt = blockIdx.y, dz = blockIdx.z, tid = threadIdx.x;
  int dj = (d_base+dz)*2 + j;
  int l = tid & 63, w = tid >> 6, wr = w >> 1, wc = w & 1;
  // ---- parallel LN: 2 threads per row (r15 summation order) ----
  if (tid < 128){
    int r = tid >> 1, half = tid & 1;
    const float4* xr = (const float4*)(xres + ((size_t)dz*LSEQ + (size_t)mt*64 + r)*DM + half*64);
    float4 v[16];
    #pragma unroll
    for (int q = 0; q < 16; ++q) v[q] = xr[q];
    float s = 0.f, ss2 = 0.f;
    #pragma unroll
    for (int q = 0; q < 16; ++q){
      s   += v[q].x + v[q].y + v[q].z + v[q].w;
      ss2 += v[q].x*v[q].x + v[q].y*v[q].y + v[q].z*v[q].z + v[q].w*v[q].w;
    }
    s += __shfl_xor(s, 1); ss2 += __shfl_xor(ss2, 1);
    float mu = s*(1.f/128.f);
    float var = ss2*(1.f/128.f) - mu*mu;
    float inv = rsqrtf(var + 1e-5f);
    const float4* w4 = (const float4*)(lnw + (size_t)dj*DM) + half*16;
    const float4* b4 = (const float4*)(lnb + (size_t)dj*DM) + half*16;
    #pragma unroll
    for (int g = 0; g < 8; ++g){
      float4 a = v[2*g], b = v[2*g+1];
      float4 wa = w4[2*g], wb = w4[2*g+1];
      float4 ba = b4[2*g], bb = b4[2*g+1];
      U8 pk;
      pk.h[0] = f2b((a.x-mu)*inv*wa.x + ba.x);
      pk.h[1] = f2b((a.y-mu)*inv*wa.y + ba.y);
      pk.h[2] = f2b((a.z-mu)*inv*wa.z + ba.z);
      pk.h[3] = f2b((a.w-mu)*inv*wa.w + ba.w);
      pk.h[4] = f2b((b.x-mu)*inv*wb.x + bb.x);
      pk.h[5] = f2b((b.y-mu)*inv*wb.y + bb.y);
      pk.h[6] = f2b((b.z-mu)*inv*wb.z + bb.z);
      pk.h[7] = f2b((b.w-mu)*inv*wb.w + bb.w);
      int c0 = half*64 + g*8;
      *(uint4*)((char*)As + SWZ2(r, c0*2)) = pk.v;
    }
  }
  __syncthreads();
  {
    const u16* Wd = wbf + (size_t)dj*768*DM + (size_t)bn*128*DM;
    f32x4 acc[2][4] = {};
    for (int kt = 0; kt < 2; ++kt){
      #pragma unroll
      for (int it = 0; it < 4; ++it){
        int idx = it*256 + tid, r = idx >> 3, slot = idx & 7;
        uint4 vb = *(const uint4*)(Wd + (size_t)r*DM + kt*64 + slot*8);
        *(uint4*)((char*)Bs + SWZ(r, slot*16)) = vb;
      }
      __syncthreads();
      #pragma unroll
      for (int ks = 0; ks < 64; ks += 32){
        bf16x8 a[2], b[4];
        int cbb = (ks + (l >> 4)*8)*2;
        int kea = kt*64 + ks + (l >> 4)*8;
        #pragma unroll
        for (int i = 0; i < 2; ++i){
          int ra = wr*32 + i*16 + (l & 15);
          a[i] = *(bf16x8*)((char*)As + SWZ2(ra, kea*2));
        }
        #pragma unroll
        for (int i = 0; i < 4; ++i)
          b[i] = *(bf16x8*)((char*)Bs + SWZ(wc*64 + i*16 + (l & 15), cbb));
        #pragma unroll
        for (int i = 0; i < 2; ++i)
          #pragma unroll
          for (int jn = 0; jn < 4; ++jn)
            acc[i][jn] = __builtin_amdgcn_mfma_f32_16x16x32_bf16(a[i], b[jn], acc[i][jn], 0, 0, 0);
      }
      __syncthreads();
    }
    if (bn < 2){
      // z columns: stage 64x128 tile into Bs (padded stride), 16B coalesced writes
      #pragma unroll
      for (int i = 0; i < 2; ++i)
        #pragma unroll
        for (int jn = 0; jn < 4; ++jn)
          #pragma unroll
          for (int r = 0; r < 4; ++r){
            int m = wr*32 + i*16 + (l >> 4)*4 + r, n = wc*64 + jn*16 + (l & 15);
            Bs[m*BSTR + n] = f2b(acc[i][jn][r]);
          }
      __syncthreads();
      u16* dst = zbuf + ((size_t)dz*LSEQ + (size_t)mt*64)*DI + bn*128;
      #pragma unroll
      for (int it = 0; it < 4; ++it){
        int idx = it*256 + tid, r = idx >> 4, slot = idx & 15;
        uint4 v = *(uint4*)(Bs + r*BSTR + slot*8);
        *(uint4*)(dst + (size_t)r*DI + slot*8) = v;
      }
    } else if (bn < 5){
      // xBC columns: stage raw tile (padded stride), load conv weights, fused conv+silu + boundary store
      int xco0 = bn*128 - 256;
      #pragma unroll
      for (int i = 0; i < 2; ++i)
        #pragma unroll
        for (int jn = 0; jn < 4; ++jn)
          #pragma unroll
          for (int r = 0; r < 4; ++r){
            int m = wr*32 + i*16 + (l >> 4)*4 + r, n = wc*64 + jn*16 + (l & 15);
            Bs[m*BSTR + n] = f2b(acc[i][jn][r]);
          }
      if (tid < 128){
        const float* wp = conv_w + ((size_t)dj*CONVD + xco0 + tid)*4;
        cwsh[tid][0]=wp[0]; cwsh[tid][1]=wp[1]; cwsh[tid][2]=wp[2]; cwsh[tid][3]=wp[3];
        cbsh[tid] = conv_b[(size_t)dj*CONVD + xco0 + tid];
      }
      __syncthreads();
      u16* bt = bnd + ((size_t)(dz*NCHUNK + mt)*6)*CONVD + xco0;
      u16* xdst = xact + ((size_t)dz*LSEQ + (size_t)mt*64)*CONVD + xco0;
      #pragma unroll
      for (int it = 0; it < 4; ++it){
        int idx = it*256 + tid, r = idx >> 4, slot = idx & 15;
        int colbase = slot*8;
        if (r < 3){
          uint4 v = *(uint4*)(Bs + r*BSTR + colbase);
          *(uint4*)(bt + (size_t)r*CONVD + colbase) = v;
        } else {
          if (r >= 61){
            uint4 v = *(uint4*)(Bs + r*BSTR + colbase);
            *(uint4*)(bt + (size_t)(r-58)*CONVD + colbase) = v;
          }
          U8 tp[4];
          #pragma unroll
          for (int k = 0; k < 4; ++k)
            tp[k].v = *(uint4*)(Bs + (r-3+k)*BSTR + colbase);
          U8 o;
          #pragma unroll
          for (int k2 = 0; k2 < 8; ++k2){
            int c = colbase + k2;
            float v = b2f(tp[0].h[k2])*cwsh[c][0] + b2f(tp[1].h[k2])*cwsh[c][1]
                    + b2f(tp[2].h[k2])*cwsh[c][2] + b2f(tp[3].h[k2])*cwsh[c][3] + cbsh[c];
            o.h[k2] = f2b(silu_f(v));
          }
          *(uint4*)(xdst + (size_t)r*CONVD + colbase) = o.v;
        }
      }
    } else {
      #pragma unroll
      for (int i = 0; i < 2; ++i)
        #pragma unroll
        for (int jn = 0; jn < 4; ++jn)
          #pragma unroll
          for (int r = 0; r < 4; ++r){
            int m = wr*32 + i*16 + (l >> 4)*4 + r, n = wc*64 + jn*16 + (l & 15);
            if (n < 4){
              float v = acc[i][jn][r] + dt_bias[dj*4 + n];
              dtb[((size_t)dz*LSEQ + (size_t)mt*64 + m)*4 + n] = softplus_f(v);
            }
          }
    }
  }
}

// ---------------- conv fixup: rows 0..2 of each 64-row tile from boundary buffer ----------------
__global__ __launch_bounds__(256) void k_convfix(const u16* __restrict__ bnd,
    const float* __restrict__ conv_w, const float* __restrict__ conv_b,
    u16* __restrict__ xact, int d_base, int j){
  int mt = blockIdx.x, dz = blockIdx.y, tid = threadIdx.x;
  int dj = (d_base+dz)*2 + j;
  if (tid >= 144) return;
  int r = tid / 48, cg = tid % 48;
  int col = cg*8;
  const u16* bcur  = bnd + ((size_t)(dz*NCHUNK + mt)*6)*CONVD;
  const u16* bprev = bnd + ((size_t)(dz*NCHUNK + mt - 1)*6)*CONVD;
  U8 tp[4];
  #pragma unroll
  for (int k = 0; k < 4; ++k){
    int grow = r - 3 + k;
    if (grow >= 0) tp[k].v = *(const uint4*)(bcur + (size_t)grow*CONVD + col);
    else if (mt > 0) tp[k].v = *(const uint4*)(bprev + (size_t)(6 + grow)*CONVD + col);
    else tp[k].v = make_uint4(0,0,0,0);
  }
  U8 o;
  #pragma unroll
  for (int k2 = 0; k2 < 8; ++k2){
    int c = col + k2;
    const float* wp = conv_w + ((size_t)dj*CONVD + c)*4;
    float v = b2f(tp[0].h[k2])*wp[0] + b2f(tp[1].h[k2])*wp[1]
            + b2f(tp[2].h[k2])*wp[2] + b2f(tp[3].h[k2])*wp[3] + conv_b[(size_t)dj*CONVD + c];
    o.h[k2] = f2b(silu_f(v));
  }
  *(uint4*)(xact + ((size_t)dz*LSEQ + (size_t)mt*64 + r)*CONVD + col) = o.v;
}

// ---------------- chunk kernel 1: dt-scan fused; two-stage transpose; G, Y1, S^T ----------------
__global__ __launch_bounds__(256) void k_chunk1(const u16* __restrict__ xact, const float* __restrict__ dtb,
    const float* __restrict__ A_log, const float* __restrict__ Dskip,
    u16* __restrict__ E, u16* __restrict__ y1, float* __restrict__ ltot, int d_base, int j){
  __shared__ __align__(16) u16 sB[4096], sC[4096], sM[4096], sXt[4096], sBw[4096];
  __shared__ float sLl[4][64], sdt[4][64];
  __shared__ float wexp[64];
  int c = blockIdx.x, dz = blockIdx.y, tid = threadIdx.x;
  int dj = (d_base+dz)*2 + j;
  int l = tid & 63, w = tid >> 6, wr = w >> 1, wc = w & 1;
  int mb = wr*32, nb = wc*32;
  int row0 = c*64;
  const u16* xa = xact + ((size_t)dz*LSEQ + row0)*CONVD;
  // per-wave dt scan: wave w = head w
  {
    float4 d4 = *(const float4*)(dtb + ((size_t)dz*LSEQ + row0 + l)*4);
    float dt = (w==0)?d4.x:((w==1)?d4.y:((w==2)?d4.z:d4.w));
    float A = -__expf(A_log[dj*4 + w]);
    float v = dt * A;
    #pragma unroll
    for (int o = 1; o < 64; o <<= 1){ float pv = __shfl_up(v, o); if (l >= o) v += pv; }
    sdt[w][l] = dt; sLl[w][l] = v;
    if (l == 63) ltot[((size_t)(dz*NCHUNK + c))*NH + w] = v;
  }
  // stage B (cols 256..319) and C (cols 320..383)
  #pragma unroll
  for (int it = 0; it < 2; ++it){
    int idx = it*256 + tid, t = idx >> 3, slot = idx & 7;
    uint4 vB = *(const uint4*)(xa + (size_t)t*CONVD + 256 + slot*8);
    uint4 vC = *(const uint4*)(xa + (size_t)t*CONVD + 320 + slot*8);
    *(uint4*)((char*)sB + SWZ(t, slot*16)) = vB;
    *(uint4*)((char*)sC + SWZ(t, slot*16)) = vC;
  }
  __syncthreads();
  // G[t][s] = sum_n C[t][n]*B[s][n]
  f32x4 g[2][2] = {};
  #pragma unroll
  for (int ks = 0; ks < 64; ks += 32){
    bf16x8 a[2], b[2];
    int cb = (ks + (l >> 4)*8)*2;
    #pragma unroll
    for (int i = 0; i < 2; ++i){
      a[i] = *(bf16x8*)((char*)sC + SWZ(mb + i*16 + (l & 15), cb));
      b[i] = *(bf16x8*)((char*)sB + SWZ(nb + i*16 + (l & 15), cb));
    }
    #pragma unroll
    for (int i = 0; i < 2; ++i)
      #pragma unroll
      for (int jn = 0; jn < 2; ++jn)
        g[i][jn] = __builtin_amdgcn_mfma_f32_16x16x32_bf16(a[i], b[jn], g[i][jn], 0, 0, 0);
  }
  for (int h = 0; h < NH; ++h){
    __syncthreads();
    if (tid < 64) wexp[tid] = __expf(sLl[h][63] - sLl[h][tid]) * sdt[h][tid];
    // stage X row-major into sC (vectorized)
    #pragma unroll
    for (int it = 0; it < 2; ++it){
      int idx = it*256 + tid, s = idx >> 3, slot = idx & 7;
      uint4 xv = *(const uint4*)(xa + (size_t)s*CONVD + h*64 + slot*8);
      *(uint4*)((char*)sC + SWZ(s, slot*16)) = xv;
    }
    // build M[t][s]
    #pragma unroll
    for (int i = 0; i < 2; ++i)
      #pragma unroll
      for (int jn = 0; jn < 2; ++jn)
        #pragma unroll
        for (int r = 0; r < 4; ++r){
          int t = mb + i*16 + (l >> 4)*4 + r;
          int s = nb + jn*16 + (l & 15);
          float v = (s <= t) ? g[i][jn][r]*__expf(sLl[h][t]-sLl[h][s])*sdt[h][s] : 0.f;
          *(u16*)((char*)sM + SWZ(t, s*2)) = f2b(v);
        }
    __syncthreads();
    // two-stage transpose: Xt[n][s] = X[s][n]; Bw[n][s] = B[s][n]*wexp[s]
    #pragma unroll
    for (int it = 0; it < 2; ++it){
      int idx = it*256 + tid, n = idx & 63, so = idx >> 6;
      U8 xo, bo;
      #pragma unroll
      for (int k = 0; k < 8; ++k){
        int s = so*8 + k;
        u16 xv = *(u16*)((char*)sC + SWZ(s, n*2));
        u16 bv = *(u16*)((char*)sB + SWZ(s, n*2));
        xo.h[k] = xv;
        bo.h[k] = f2b(b2f(bv) * wexp[s]);
      }
      *(uint4*)((char*)sXt + SWZ(n, so*16)) = xo.v;
      *(uint4*)((char*)sBw + SWZ(n, so*16)) = bo.v;
    }
    __syncthreads();
    // Y1 = M x Xt ; S^T = Xt x Bw
    f32x4 y1a[2][2] = {}, ssa[2][2] = {};
    #pragma unroll
    for (int ks = 0; ks < 64; ks += 32){
      int cb = (ks + (l >> 4)*8)*2;
      bf16x8 am[2], ax[2], bx[2], bw2[2];
      #pragma unroll
      for (int i = 0; i < 2; ++i){
        am[i]  = *(bf16x8*)((char*)sM  + SWZ(mb + i*16 + (l & 15), cb));
        ax[i]  = *(bf16x8*)((char*)sXt + SWZ(mb + i*16 + (l & 15), cb));
        bx[i]  = *(bf16x8*)((char*)sXt + SWZ(nb + i*16 + (l & 15), cb));
        bw2[i] = *(bf16x8*)((char*)sBw + SWZ(nb + i*16 + (l & 15), cb));
      }
      #pragma unroll
      for (int i = 0; i < 2; ++i)
        #pragma unroll
        for (int jn = 0; jn < 2; ++jn){
          y1a[i][jn] = __builtin_amdgcn_mfma_f32_16x16x32_bf16(am[i], bx[jn], y1a[i][jn], 0, 0, 0);
          ssa[i][jn] = __builtin_amdgcn_mfma_f32_16x16x32_bf16(ax[i], bw2[jn], ssa[i][jn], 0, 0, 0);
        }
    }
    __syncthreads();   // all waves done reading sM/sBw
    float dsk = Dskip[dj*NH + h];
    #pragma unroll
    for (int i = 0; i < 2; ++i)
      #pragma unroll
      for (int jn = 0; jn < 2; ++jn)
        #pragma unroll
        for (int r = 0; r < 4; ++r){
          int m = mb + i*16 + (l >> 4)*4 + r, n = nb + jn*16 + (l & 15);
          float xsv = b2f(*(u16*)((char*)sXt + SWZ(n, m*2)));
          *(u16*)((char*)sM  + SWZ(m, n*2)) = f2b(y1a[i][jn][r] + dsk * xsv);
          *(u16*)((char*)sBw + SWZ(m, n*2)) = f2b(ssa[i][jn][r]);
        }
    __syncthreads();
    u16* yr = y1 + ((size_t)dz*LSEQ + row0)*DI + h*64;
    u16* Ep = E + ((size_t)(dz*NCHUNK + c)*NH + h)*4096;
    #pragma unroll
    for (int it = 0; it < 2; ++it){
      int idx = it*256 + tid, r = idx >> 3, slot = idx & 7;
      uint4 vy = *(uint4*)((char*)sM  + SWZ(r, slot*16));
      uint4 ve = *(uint4*)((char*)sBw + SWZ(r, slot*16));
      *(uint4*)(yr + (size_t)r*DI + slot*8) = vy;
      *(uint4*)(Ep + r*64 + slot*8) = ve;
    }
  }
}

// ---------------- sequential carry over chunks, in-place on bf16 E, depth-16 prefetch ----------------
__global__ __launch_bounds__(256) void k_seq(u16* __restrict__ E, const float* __restrict__ ltot, int nd){
  int i = blockIdx.x*256 + threadIdx.x;
  if (i >= nd*16384) return;
  int dz = i >> 14, h = (i >> 12) & 3, np = i & 4095;
  const int stride = 16384;
  size_t base = (size_t)dz*NCHUNK*stride + (size_t)h*4096 + np;
  const float* lt = ltot + (size_t)dz*NCHUNK*NH + h;
  u16 eb[16]; float pb[16];
  #pragma unroll
  for (int q = 0; q < 16; ++q){ eb[q] = E[base + (size_t)q*stride]; pb[q] = lt[q*NH]; }
  float carry = 0.f;
  for (int cc = 0; cc < 256; cc += 16){
    u16 e2[16]; float p2[16];
    if (cc + 16 < 256){
      #pragma unroll
      for (int q = 0; q < 16; ++q){
        e2[q] = E[base + (size_t)(cc+16+q)*stride];
        p2[q] = lt[(cc+16+q)*NH];
      }
    }
    #pragma unroll
    for (int q = 0; q < 16; ++q){
      u16 cv = f2b(carry);
      carry = fmaf(__expf(pb[q]), carry, b2f(eb[q]));
      E[base + (size_t)(cc+q)*stride] = cv;
    }
    #pragma unroll
    for (int q = 0; q < 16; ++q){ eb[q] = e2[q]; pb[q] = p2[q]; }
  }
}

// ---------------- chunk kernel 2: Y2 MFMA; gate+RMS in LDS; fused out_proj (+residual/scatter) ----------------
__global__ __launch_bounds__(256) void k_chunk2(const u16* __restrict__ xact, const float* __restrict__ dtb,
    const float* __restrict__ A_log, const u16* __restrict__ zbuf, const u16* __restrict__ y1,
    const u16* __restrict__ E, const float* __restrict__ norm_w, const u16* __restrict__ wo,
    float* __restrict__ x, const int* __restrict__ sidx, u16* __restrict__ multi,
    int d_base, int j){
  __shared__ __align__(16) u16 SH[24576];   // 48KB: sC(8K) sHt(8K) Ylds(32K); Bs reuses sC+sHt
  u16* sC   = SH;
  u16* sHt  = SH + 4096;
  u16* Ylds = SH + 8192;
  u16* Bs   = SH;             // phase C weight tile / scatter staging (16KB)
  __shared__ float sLl[4][64];
  __shared__ float nws[256];
  int c = blockIdx.x, dz = blockIdx.y, tid = threadIdx.x;
  int dj = (d_base+dz)*2 + j;
  int l = tid & 63, w = tid >> 6, wr = w >> 1, wc = w & 1;
  int mb = wr*32, nb = wc*32;
  int row0 = c*64;
  const u16* xa = xact + ((size_t)dz*LSEQ + row0)*CONVD;
  if (tid < 64) ((float4*)nws)[tid] = ((const float4*)(norm_w + (size_t)dj*DI))[tid];
  // dt scan
  {
    float4 d4 = *(const float4*)(dtb + ((size_t)dz*LSEQ + row0 + l)*4);
    float dt = (w==0)?d4.x:((w==1)?d4.y:((w==2)?d4.z:d4.w));
    float A = -__expf(A_log[dj*4 + w]);
    float v = dt * A;
    #pragma unroll
    for (int o = 1; o < 64; o <<= 1){ float pv = __shfl_up(v, o); if (l >= o) v += pv; }
    sLl[w][l] = v;
  }
  // stage C (cols 320..383)
  #pragma unroll
  for (int it = 0; it < 2; ++it){
    int idx = it*256 + tid, t = idx >> 3, slot = idx & 7;
    uint4 vC = *(const uint4*)(xa + (size_t)t*CONVD + 320 + slot*8);
    *(uint4*)((char*)sC + SWZ(t, slot*16)) = vC;
  }
  // phase A: per-head MFMA, scaled Y2 into Ylds
  for (int h = 0; h < NH; ++h){
    __syncthreads();
    const u16* Hp = E + ((size_t)(dz*NCHUNK + c)*NH + h)*4096;
    #pragma unroll
    for (int it = 0; it < 2; ++it){
      int idx = it*256 + tid, p = idx >> 3, ng = idx & 7;
      uint4 v = *(const uint4*)(Hp + (size_t)p*64 + ng*8);
      *(uint4*)((char*)sHt + SWZ(p, ng*16)) = v;
    }
    __syncthreads();
    f32x4 acc[2][2] = {};
    #pragma unroll
    for (int ks = 0; ks < 64; ks += 32){
      int cb = (ks + (l >> 4)*8)*2;
      bf16x8 a[2], b[2];
      #pragma unroll
      for (int i = 0; i < 2; ++i){
        a[i] = *(bf16x8*)((char*)sC  + SWZ(mb + i*16 + (l & 15), cb));
        b[i] = *(bf16x8*)((char*)sHt + SWZ(nb + i*16 + (l & 15), cb));
      }
      #pragma unroll
      for (int i = 0; i < 2; ++i)
        #pragma unroll
        for (int jn = 0; jn < 2; ++jn)
          acc[i][jn] = __builtin_amdgcn_mfma_f32_16x16x32_bf16(a[i], b[jn], acc[i][jn], 0, 0, 0);
    }
    #pragma unroll
    for (int i = 0; i < 2; ++i)
      #pragma unroll
      for (int jn = 0; jn < 2; ++jn)
        #pragma unroll
        for (int r = 0; r < 4; ++r){
          int m = mb + i*16 + (l >> 4)*4 + r, n = nb + jn*16 + (l & 15);
          float e = __expf(sLl[h][m]);
          *(u16*)((char*)Ylds + SWZ4(m, (h*64 + n)*2)) = f2b(e * acc[i][jn][r]);
        }
  }
  __syncthreads();
  // phase B: row-parallel gate + RMSNorm, in-place normalized yn into Ylds
  {
    int r = tid >> 2, q = tid & 3;
    size_t rowbase = ((size_t)dz*LSEQ + row0 + r)*DI + q*64;
    float ssq = 0.f;
    U8 gs[8];
    #pragma unroll
    for (int v = 0; v < 8; ++v){
      U8 y2u; y2u.v = *(uint4*)((char*)Ylds + SWZ4(r, (q*64 + v*8)*2));
      U8 y1u; y1u.v = *(const uint4*)(y1 + rowbase + v*8);
      U8 zu;  zu.v  = *(const uint4*)(zbuf + rowbase + v*8);
      #pragma unroll
      for (int k = 0; k < 8; ++k){
        float gv = (b2f(y1u.h[k]) + b2f(y2u.h[k])) * silu_f(b2f(zu.h[k]));
        ssq += gv*gv;
        gs[v].h[k] = f2b(gv);
      }
    }
    ssq += __shfl_xor(ssq, 1);
    ssq += __shfl_xor(ssq, 2);
    float rr = rsqrtf(ssq * (1.f/256.f) + 1e-5f);
    #pragma unroll
    for (int v = 0; v < 8; ++v){
      U8 o;
      #pragma unroll
      for (int k = 0; k < 8; ++k)
        o.h[k] = f2b(b2f(gs[v].h[k]) * rr * nws[q*64 + v*8 + k]);
      *(uint4*)((char*)Ylds + SWZ4(r, (q*64 + v*8)*2)) = o.v;
    }
  }
  __syncthreads();
  // phase C: out_proj GEMM  yn[64x256] @ wo[dj][128x256]^T
  const u16* Bg = wo + (size_t)dj*DM*DI;
  f32x4 acc2[2][4] = {};
  for (int kt = 0; kt < 4; ++kt){
    #pragma unroll
    for (int it = 0; it < 4; ++it){
      int idx = it*256 + tid, r = idx >> 3, slot = idx & 7;
      uint4 vb = *(const uint4*)(Bg + (size_t)r*DI + kt*64 + slot*8);
      *(uint4*)((char*)Bs + SWZ(r, slot*16)) = vb;
    }
    __syncthreads();
    #pragma unroll
    for (int ks = 0; ks < 64; ks += 32){
      bf16x8 a[2], b[4];
      int cb = (ks + (l >> 4)*8)*2;
      int kcol = kt*64 + ks + (l >> 4)*8;
      #pragma unroll
      for (int i = 0; i < 2; ++i)
        a[i] = *(bf16x8*)((char*)Ylds + SWZ4(wr*32 + i*16 + (l & 15), kcol*2));
      #pragma unroll
      for (int i = 0; i < 4; ++i)
        b[i] = *(bf16x8*)((char*)Bs + SWZ(wc*64 + i*16 + (l & 15), cb));
      #pragma unroll
      for (int i = 0; i < 2; ++i)
        #pragma unroll
        for (int jn = 0; jn < 4; ++jn)
          acc2[i][jn] = __builtin_amdgcn_mfma_f32_16x16x32_bf16(a[i], b[jn], acc2[i][jn], 0, 0, 0);
    }
    __syncthreads();
  }
  float* xr = x + ((size_t)dz*LSEQ + row0)*DM;
  if (j == 0){
    #pragma unroll
    for (int i = 0; i < 2; ++i)
      #pragma unroll
      for (int jn = 0; jn < 4; ++jn)
        #pragma unroll
        for (int r = 0; r < 4; ++r){
          int m = wr*32 + i*16 + (l >> 4)*4 + r, n = wc*64 + jn*16 + (l & 15);
          xr[(size_t)m*DM + n] += acc2[i][jn][r];
        }
  } else {
    // residual + convert -> Bs (64x128), then row-scatter into multi
    #pragma unroll
    for (int i = 0; i < 2; ++i)
      #pragma unroll
      for (int jn = 0; jn < 4; ++jn)
        #pragma unroll
        for (int r = 0; r < 4; ++r){
          int m = wr*32 + i*16 + (l >> 4)*4 + r, n = wc*64 + jn*16 + (l & 15);
          float res = xr[(size_t)m*DM + n] + acc2[i][jn][r];
          Bs[m*128 + n] = f2b(res);
        }
    __syncthreads();
    const int* ip = sidx + (size_t)(d_base+dz)*LSEQ + row0;
    #pragma unroll
    for (int it = 0; it < 4; ++it){
      int e = it*256 + tid, r = e >> 4, slot = e & 15;
      int orig = ip[r];
      uint4 v = *(uint4*)(Bs + r*128 + slot*8);
      *(uint4*)(multi + (size_t)orig*768 + (size_t)(d_base+dz)*128 + slot*8) = v;
    }
  }
}

// ---------------- fuse: fused LN(768) + GEMM + bias + exact gelu; N-split x2 ----------------
__global__ __launch_bounds__(256) void k_fuse(const u16* __restrict__ multi, const u16* __restrict__ wbf,
                                              const float* __restrict__ lnw, const float* __restrict__ lnb,
                                              const float* __restrict__ fb, float* __restrict__ out){
  __shared__ __align__(16) u16 As[64*64];    // 8KB
  __shared__ __align__(16) u16 Bs[64*64];    // 8KB
  __shared__ float swn[768], sbn[768], smu[64], sinv[64];
  int nh = blockIdx.x, mt = blockIdx.y, tid = threadIdx.x;
  int l = tid & 63, w = tid >> 6, wr = w >> 1, wc = w & 1;
  for (int e = tid; e < 192; e += 256){
    ((float4*)swn)[e] = ((const float4*)lnw)[e];
    ((float4*)sbn)[e] = ((const float4*)lnb)[e];
  }
  {
    int r = tid >> 2, q = tid & 3;
    const u16* row = multi + ((size_t)(mt*64 + r))*768 + q*192;
    float s = 0.f, ss = 0.f;
    #pragma unroll
    for (int v = 0; v < 24; ++v){
      U8 u; u.v = *(const uint4*)(row + v*8);
      #pragma unroll
      for (int k = 0; k < 8; ++k){ float f = b2f(u.h[k]); s += f; ss += f*f; }
    }
    s += __shfl_xor(s, 1); s += __shfl_xor(s, 2);
    ss += __shfl_xor(ss, 1); ss += __shfl_xor(ss, 2);
    if (q == 0){
      float mu = s * (1.f/768.f);
      smu[r] = mu;
      sinv[r] = rsqrtf(ss * (1.f/768.f) - mu*mu + 1e-5f);
    }
  }
  __syncthreads();
  const u16* Ag = multi + (size_t)mt*64*768;
  const u16* Wg = wbf + (size_t)nh*64*768;
  f32x4 acc[2][2] = {};
  for (int kt = 0; kt < 12; ++kt){
    #pragma unroll
    for (int it = 0; it < 2; ++it){
      int e = it*256 + tid, r = e >> 3, slot = e & 7;
      U8 u; u.v = *(const uint4*)(Ag + (size_t)r*768 + kt*64 + slot*8);
      float mu = smu[r], inv = sinv[r];
      U8 o;
      #pragma unroll
      for (int k = 0; k < 8; ++k){
        int col = kt*64 + slot*8 + k;
        o.h[k] = f2b((b2f(u.h[k]) - mu)*inv*swn[col] + sbn[col]);
      }
      *(uint4*)((char*)As + SWZ(r, slot*16)) = o.v;
    }
    #pragma unroll
    for (int it = 0; it < 2; ++it){
      int e = it*256 + tid, r = e >> 3, slot = e & 7;
      uint4 vb = *(const uint4*)(Wg + (size_t)r*768 + kt*64 + slot*8);
      *(uint4*)((char*)Bs + SWZ(r, slot*16)) = vb;
    }
    __syncthreads();
    #pragma unroll
    for (int ks = 0; ks < 64; ks += 32){
      bf16x8 a[2], b[2];
      int cb = (ks + (l >> 4)*8)*2;
      #pragma unroll
      for (int i = 0; i < 2; ++i)
        a[i] = *(bf16x8*)((char*)As + SWZ(wr*32 + i*16 + (l & 15), cb));
      #pragma unroll
      for (int i = 0; i < 2; ++i)
        b[i] = *(bf16x8*)((char*)Bs + SWZ(wc*32 + i*16 + (l & 15), cb));
      #pragma unroll
      for (int i = 0; i < 2; ++i)
        #pragma unroll
        for (int jn = 0; jn < 2; ++jn)
          acc[i][jn] = __builtin_amdgcn_mfma_f32_16x16x32_bf16(a[i], b[jn], acc[i][jn], 0, 0, 0);
    }
    __syncthreads();
  }
  #pragma unroll
  for (int i = 0; i < 2; ++i)
    #pragma unroll
    for (int jn = 0; jn < 2; ++jn)
      #pragma unroll
      for (int r = 0; r < 4; ++r){
        int m = wr*32 + i*16 + (l >> 4)*4 + r;
        int n = nh*64 + wc*32 + jn*16 + (l & 15);
        float v = acc[i][jn][r] + fb[n];
        float gl = 0.5f * v * (1.f + erff(v * 0.70710678118654752f));
        out[(size_t)(mt*64 + m)*DM + n] = gl;
      }
}

extern "C" void kernel_launch(void* const* d_in, const int* in_sizes, int n_in,
                              void* d_out, int out_size, void* d_ws, size_t ws_size,
                              hipStream_t stream){
  (void)in_sizes; (void)n_in; (void)out_size;
  const float* vectors  = (const float*)d_in[0];
  const int*   coords   = (const int*)d_in[1];
  const float* ln_w     = (const float*)d_in[2];
  const float* ln_b     = (const float*)d_in[3];
  const float* in_w     = (const float*)d_in[4];
  const float* conv_w   = (const float*)d_in[5];
  const float* conv_b   = (const float*)d_in[6];
  const float* dt_bias  = (const float*)d_in[7];
  const float* A_log    = (const float*)d_in[8];
  const float* D_skip   = (const float*)d_in[9];
  const float* norm_w   = (const float*)d_in[10];
  const float* out_w    = (const float*)d_in[11];
  const float* fuse_lw  = (const float*)d_in[12];
  const float* fuse_lb  = (const float*)d_in[13];
  const float* fuse_w   = (const float*)d_in[14];
  const float* fuse_b   = (const float*)d_in[15];
  float* out = (float*)d_out;

  char* p = (char*)d_ws;
  auto carve = [&](size_t bytes)->char*{
    char* r = p; p += (bytes + 255) & ~(size_t)255; return r;
  };
  int* idxb = (int*)carve((size_t)NDIR*LSEQ*4);
  unsigned long long* skey  = (unsigned long long*)carve((size_t)NDIR*LSEQ*8);
  unsigned long long* skey2 = (unsigned long long*)carve((size_t)NDIR*LSEQ*8);
  int* starts = (int*)carve((size_t)NDIR*1025*4);
  int* cursor = (int*)carve((size_t)NDIR*1024*4);
  u16* multi = (u16*)carve((size_t)LSEQ*768*2);
  u16* wbf_in   = (u16*)carve((size_t)NW0*2);
  u16* wbf_out  = (u16*)carve((size_t)NW1*2);
  u16* wbf_fuse = (u16*)carve((size_t)NW2*2);

  size_t fixed = (size_t)(p - (char*)d_ws);
  auto need = [&](int nd)->size_t{
    size_t s = 0; auto a = [&](size_t b){ s += (b + 255) & ~(size_t)255; };
    a((size_t)nd*LSEQ*DM*4);      // xbuf (f32 residual)
    a((size_t)nd*LSEQ*DI*2);      // zbuf (bf16)
    a((size_t)nd*LSEQ*CONVD*2);   // xact (bf16, conv'd)
    a((size_t)nd*NCHUNK*6*CONVD*2); // bnd (boundary rows)
    a((size_t)nd*LSEQ*NH*4);      // dtb (f32)
    a((size_t)nd*NCHUNK*NH*4);    // ltot (f32)
    a((size_t)nd*LSEQ*DI*2);      // y1 (bf16)
    a((size_t)nd*NCHUNK*NH*DSTATE*HD*2); // E (bf16, in-place scan)
    return s;
  };
  // adaptive batching: largest nd in {6,3,2,1} that fits the workspace
  int nd = 1;
  {
    const int cands[3] = {6, 3, 2};
    for (int ci = 0; ci < 3; ++ci){
      if (fixed + need(cands[ci]) <= ws_size){ nd = cands[ci]; break; }
    }
  }
  if (fixed + need(nd) > ws_size) return;  // insufficient workspace: no-op

  float* xbuf = (float*)carve((size_t)nd*LSEQ*DM*4);
  u16*   zbuf = (u16*)carve((size_t)nd*LSEQ*DI*2);
  u16*   xact = (u16*)carve((size_t)nd*LSEQ*CONVD*2);
  u16*   bnd  = (u16*)carve((size_t)nd*NCHUNK*6*CONVD*2);
  float* dtb  = (float*)carve((size_t)nd*LSEQ*NH*4);
  float* ltot = (float*)carve((size_t)nd*NCHUNK*NH*4);
  u16*   y1b  = (u16*)carve((size_t)nd*LSEQ*DI*2);
  u16*   Ebuf = (u16*)carve((size_t)nd*NCHUNK*NH*DSTATE*HD*2);

  k_cvt         <<<(NW0+NW1+NW2+255)/256, 256, 0, stream>>>(in_w, out_w, fuse_w, wbf_in, wbf_out, wbf_fuse, cursor);
  k_sort1       <<<(NDIR*LSEQ + 255)/256, 256, 0, stream>>>(coords, skey, cursor);
  k_sort_scan   <<<NDIR, 1024, 0, stream>>>(cursor, starts);
  k_sort_scatter<<<(NDIR*LSEQ + 255)/256, 256, 0, stream>>>(skey, skey2, cursor);
  k_sort_rank   <<<(NDIR*LSEQ + 255)/256, 256, 0, stream>>>(skey2, starts, idxb);

  for (int d_base = 0; d_base < NDIR; d_base += nd){
    k_gather<<<nd*2048, 256, 0, stream>>>(vectors, idxb, xbuf, d_base, nd);
    for (int j = 0; j < 2; ++j){
      k_inproj<<<dim3(6, LSEQ/64, nd), 256, 0, stream>>>(xbuf, ln_w, ln_b, wbf_in, dt_bias,
                                                         conv_w, conv_b, zbuf, xact, bnd, dtb, d_base, j);
      k_convfix<<<dim3(NCHUNK, nd), 256, 0, stream>>>(bnd, conv_w, conv_b, xact, d_base, j);
      k_chunk1<<<dim3(NCHUNK, nd), 256, 0, stream>>>(xact, dtb, A_log, D_skip,
                                                     Ebuf, y1b, ltot, d_base, j);
      k_seq   <<<(nd*16384 + 255)/256, 256, 0, stream>>>(Ebuf, ltot, nd);
      k_chunk2<<<dim3(NCHUNK, nd), 256, 0, stream>>>(xact, dtb, A_log, zbuf, y1b, Ebuf,
                                                     norm_w, wbf_out, xbuf, idxb, multi, d_base, j);
    }
  }
  k_fuse <<<dim3(2, LSEQ/64), 256, 0, stream>>>(multi, wbf_fuse, fuse_lw, fuse_lb, fuse_b, out);
}

// Round 21
// 733.712 us; speedup vs baseline: 1.0224x; 1.0224x over previous
//
#include <hip/hip_runtime.h>
#include <math.h>

#define LSEQ   16384
#define DM     128
#define DI     256
#define DSTATE 64
#define NH     4
#define HD     64
#define CONVD  384
#define DPROJ  644
#define NDIR   6
#define NCHUNK 256      // LSEQ/64

typedef unsigned short u16;
typedef __attribute__((ext_vector_type(8))) __bf16 bf16x8;
typedef __attribute__((ext_vector_type(4))) float f32x4;

union U8 { uint4 v; u16 h[8]; };

__device__ __constant__ int ORD[6][3] = {{0,1,2},{0,2,1},{1,0,2},{1,2,0},{2,0,1},{2,1,0}};

__device__ __forceinline__ float softplus_f(float x){
  float ax = fabsf(x);
  return fmaxf(x, 0.f) + log1pf(__expf(-ax));
}
__device__ __forceinline__ float silu_f(float x){
  return x / (1.f + __expf(-x));
}
__device__ __forceinline__ u16 f2b(float f){
  unsigned u = __float_as_uint(f);
  unsigned r = (u + 0x7fffu + ((u >> 16) & 1u)) >> 16;
  return (u16)r;
}
__device__ __forceinline__ float b2f(u16 h){
  return __uint_as_float(((unsigned)h) << 16);
}
// XOR swizzle for [rows][128B] bf16 LDS tiles: conflict-free ds_read_b128 (T2)
__device__ __forceinline__ int SWZ(int r, int cb){
  return r*128 + (cb ^ ((r & 7) << 4));
}
// swizzle for 256B-row LDS tiles (inproj As)
__device__ __forceinline__ int SWZ2(int r, int cb){
  return r*256 + (cb ^ ((r & 7) << 4));
}
// swizzle for 512B-row LDS tiles (chunk2 Ylds)
__device__ __forceinline__ int SWZ4(int r, int cb){
  return r*512 + (cb ^ ((r & 7) << 4));
}

// ---------------- weight convert to bf16 (+ cursor zeroing) ----------------
#define NW0 (12*768*128)
#define NW1 (12*128*256)
#define NW2 (128*768)
__global__ __launch_bounds__(256) void k_cvt(const float* __restrict__ in_w,
                                             const float* __restrict__ out_w,
                                             const float* __restrict__ fuse_w,
                                             u16* __restrict__ wi, u16* __restrict__ wo,
                                             u16* __restrict__ wf, int* __restrict__ cursor){
  int i = blockIdx.x*256 + threadIdx.x;
  if (i < NDIR*1024) cursor[i] = 0;
  if (i < NW0){
    int dj = i / (768*128), rem = i % (768*128), r = rem >> 7, c = rem & 127;
    float v = (r < DPROJ) ? in_w[((size_t)dj*DPROJ + r)*128 + c] : 0.f;
    wi[i] = f2b(v);
  } else if (i < NW0 + NW1){
    int k = i - NW0;
    wo[k] = f2b(out_w[k]);
  } else if (i < NW0 + NW1 + NW2){
    int k = i - NW0 - NW1;
    wf[k] = f2b(fuse_w[k]);
  }
}

// ---------------- sort ----------------
__global__ __launch_bounds__(256) void k_sort1(const int* __restrict__ coords,
                                               unsigned long long* __restrict__ skey,
                                               int* __restrict__ cursor){
  int i = blockIdx.x*256 + threadIdx.x;
  if (i >= NDIR*LSEQ) return;
  int d = i >> 14, t = i & 16383;
  unsigned k = ((unsigned)coords[t*4 + ORD[d][0]] << 20)
             | ((unsigned)coords[t*4 + ORD[d][1]] << 10)
             |  (unsigned)coords[t*4 + ORD[d][2]];
  skey[i] = ((unsigned long long)k << 14) | (unsigned long long)t;
  atomicAdd(&cursor[(d << 10) + (k >> 20)], 1);
}

__global__ void k_sort_scan(int* __restrict__ cursor, int* __restrict__ starts){
  __shared__ int sh[1024];
  int d = blockIdx.x, t = threadIdx.x;
  int v = cursor[d*1024 + t];
  sh[t] = v; __syncthreads();
  for (int off = 1; off < 1024; off <<= 1){
    int a = (t >= off) ? sh[t-off] : 0;
    __syncthreads();
    sh[t] += a;
    __syncthreads();
  }
  int incl = sh[t], excl = incl - v;
  starts[d*1025 + t] = excl;
  cursor[d*1024 + t] = excl;
  if (t == 1023) starts[d*1025 + 1024] = incl;
}

__global__ __launch_bounds__(256) void k_sort_scatter(const unsigned long long* __restrict__ skey,
                                                      unsigned long long* __restrict__ skey2,
                                                      int* __restrict__ cursor){
  int i = blockIdx.x*256 + threadIdx.x;
  if (i >= NDIR*LSEQ) return;
  int d = i >> 14;
  unsigned long long v = skey[i];
  int b = (int)(v >> 34);
  int pos = atomicAdd(&cursor[(d << 10) + b], 1);
  skey2[(size_t)d*LSEQ + pos] = v;
}

__global__ __launch_bounds__(256) void k_sort_rank(const unsigned long long* __restrict__ skey2,
                                                   const int* __restrict__ starts,
                                                   int* __restrict__ idx){
  int i = blockIdx.x*256 + threadIdx.x;
  if (i >= NDIR*LSEQ) return;
  int d = i >> 14;
  unsigned long long v = skey2[i];
  int b = (int)(v >> 34);
  int s = starts[d*1025 + b], e = starts[d*1025 + b + 1];
  int r = s;
  for (int q = s; q < e; ++q) r += (skey2[(size_t)d*LSEQ + q] < v);
  int orig = (int)(v & 16383ULL);
  idx[(size_t)d*LSEQ + r] = orig;
}

// ---------------- gather ----------------
__global__ __launch_bounds__(256) void k_gather(const float* __restrict__ vec, const int* __restrict__ idx,
                                                float* __restrict__ x, int d_base, int nd){
  int i = blockIdx.x*256 + threadIdx.x;
  if (i >= nd*LSEQ*32) return;
  int c4 = i & 31, r = (i >> 5) & 16383, dz = i >> 19;
  int src = idx[(size_t)(d_base+dz)*LSEQ + r];
  ((float4*)x)[((size_t)dz*LSEQ + r)*32 + c4] = ((const float4*)vec)[(size_t)src*32 + c4];
}

// ---------------- in_proj: 64-row tiles; fused LN; fused conv+silu (rows>=3) + boundary store ----------------
__global__ __launch_bounds__(256) void k_inproj(const float* __restrict__ xres,
    const float* __restrict__ lnw, const float* __restrict__ lnb,
    const u16* __restrict__ wbf, const float* __restrict__ dt_bias,
    const float* __restrict__ conv_w, const float* __restrict__ conv_b,
    u16* __restrict__ zbuf, u16* __restrict__ xact, u16* __restrict__ bnd,
    float* __restrict__ dtb, int d_base, int j){
  __shared__ __align__(16) u16 As[64*128];   // 16KB (row stride 256B, swizzled)
  __shared__ __align__(16) u16 Bs[128*64];   // 16KB (weights; reused as 64x128 epilogue buf)
  __shared__ float cwsh[128][4];
  __shared__ float cbsh[128];
  int bpair = blockIdx.x, mt = blockIdx.y, dz = blockIdx.z, tid = threadIdx.x;
  int dj = (d_base+dz)*2 + j;
  int l = tid & 63, w = tid >> 6, wr = w >> 1, wc = w & 1;
  // ---- parallel LN: 2 threads per row (r15 summation order) ----
  if (tid < 128){
    int r = tid >> 1, half = tid & 1;
    const float4* xr = (const float4*)(xres + ((size_t)dz*LSEQ + (size_t)mt*64 + r)*DM + half*64);
    float4 v[16];
    #pragma unroll
    for (int q = 0; q < 16; ++q) v[q] = xr[q];
    float s = 0.f, ss2 = 0.f;
    #pragma unroll
    for (int q = 0; q < 16; ++q){
      s   += v[q].x + v[q].y + v[q].z + v[q].w;
      ss2 += v[q].x*v[q].x + v[q].y*v[q].y + v[q].z*v[q].z + v[q].w*v[q].w;
    }
    s += __shfl_xor(s, 1); ss2 += __shfl_xor(ss2, 1);
    float mu = s*(1.f/128.f);
    float var = ss2*(1.f/128.f) - mu*mu;
    float inv = rsqrtf(var + 1e-5f);
    const float4* w4 = (const float4*)(lnw + (size_t)dj*DM) + half*16;
    const float4* b4 = (const float4*)(lnb + (size_t)dj*DM) + half*16;
    #pragma unroll
    for (int g = 0; g < 8; ++g){
      float4 a = v[2*g], b = v[2*g+1];
      float4 wa = w4[2*g], wb = w4[2*g+1];
      float4 ba = b4[2*g], bb = b4[2*g+1];
      U8 pk;
      pk.h[0] = f2b((a.x-mu)*inv*wa.x + ba.x);
      pk.h[1] = f2b((a.y-mu)*inv*wa.y + ba.y);
      pk.h[2] = f2b((a.z-mu)*inv*wa.z + ba.z);
      pk.h[3] = f2b((a.w-mu)*inv*wa.w + ba.w);
      pk.h[4] = f2b((b.x-mu)*inv*wb.x + bb.x);
      pk.h[5] = f2b((b.y-mu)*inv*wb.y + bb.y);
      pk.h[6] = f2b((b.z-mu)*inv*wb.z + bb.z);
      pk.h[7] = f2b((b.w-mu)*inv*wb.w + bb.w);
      int c0 = half*64 + g*8;
      *(uint4*)((char*)As + SWZ2(r, c0*2)) = pk.v;
    }
  }
  __syncthreads();
  for (int ib = 0; ib < 2; ++ib){
    int bn = bpair*2 + ib;
    const u16* Wd = wbf + (size_t)dj*768*DM + (size_t)bn*128*DM;
    f32x4 acc[2][4] = {};
    for (int kt = 0; kt < 2; ++kt){
      #pragma unroll
      for (int it = 0; it < 4; ++it){
        int idx = it*256 + tid, r = idx >> 3, slot = idx & 7;
        uint4 vb = *(const uint4*)(Wd + (size_t)r*DM + kt*64 + slot*8);
        *(uint4*)((char*)Bs + SWZ(r, slot*16)) = vb;
      }
      __syncthreads();
      #pragma unroll
      for (int ks = 0; ks < 64; ks += 32){
        bf16x8 a[2], b[4];
        int cbb = (ks + (l >> 4)*8)*2;
        int kea = kt*64 + ks + (l >> 4)*8;
        #pragma unroll
        for (int i = 0; i < 2; ++i){
          int ra = wr*32 + i*16 + (l & 15);
          a[i] = *(bf16x8*)((char*)As + SWZ2(ra, kea*2));
        }
        #pragma unroll
        for (int i = 0; i < 4; ++i)
          b[i] = *(bf16x8*)((char*)Bs + SWZ(wc*64 + i*16 + (l & 15), cbb));
        #pragma unroll
        for (int i = 0; i < 2; ++i)
          #pragma unroll
          for (int jn = 0; jn < 4; ++jn)
            acc[i][jn] = __builtin_amdgcn_mfma_f32_16x16x32_bf16(a[i], b[jn], acc[i][jn], 0, 0, 0);
      }
      __syncthreads();
    }
    if (bn < 2){
      // z columns: stage 64x128 tile into Bs (linear), 16B coalesced writes
      #pragma unroll
      for (int i = 0; i < 2; ++i)
        #pragma unroll
        for (int jn = 0; jn < 4; ++jn)
          #pragma unroll
          for (int r = 0; r < 4; ++r){
            int m = wr*32 + i*16 + (l >> 4)*4 + r, n = wc*64 + jn*16 + (l & 15);
            Bs[m*128 + n] = f2b(acc[i][jn][r]);
          }
      __syncthreads();
      u16* dst = zbuf + ((size_t)dz*LSEQ + (size_t)mt*64)*DI + bn*128;
      #pragma unroll
      for (int it = 0; it < 4; ++it){
        int idx = it*256 + tid, r = idx >> 4, slot = idx & 15;
        uint4 v = *(uint4*)(Bs + r*128 + slot*8);
        *(uint4*)(dst + (size_t)r*DI + slot*8) = v;
      }
      __syncthreads();
    } else if (bn < 5){
      // xBC columns: stage raw tile, load conv weights, then fused conv+silu (rows>=3) + boundary store
      int xco0 = bn*128 - 256;
      #pragma unroll
      for (int i = 0; i < 2; ++i)
        #pragma unroll
        for (int jn = 0; jn < 4; ++jn)
          #pragma unroll
          for (int r = 0; r < 4; ++r){
            int m = wr*32 + i*16 + (l >> 4)*4 + r, n = wc*64 + jn*16 + (l & 15);
            Bs[m*128 + n] = f2b(acc[i][jn][r]);
          }
      if (tid < 128){
        const float* wp = conv_w + ((size_t)dj*CONVD + xco0 + tid)*4;
        cwsh[tid][0]=wp[0]; cwsh[tid][1]=wp[1]; cwsh[tid][2]=wp[2]; cwsh[tid][3]=wp[3];
        cbsh[tid] = conv_b[(size_t)dj*CONVD + xco0 + tid];
      }
      __syncthreads();
      u16* bt = bnd + ((size_t)(dz*NCHUNK + mt)*6)*CONVD + xco0;
      u16* xdst = xact + ((size_t)dz*LSEQ + (size_t)mt*64)*CONVD + xco0;
      #pragma unroll
      for (int it = 0; it < 4; ++it){
        int idx = it*256 + tid, r = idx >> 4, slot = idx & 15;
        int colbase = slot*8;
        if (r < 3){
          uint4 v = *(uint4*)(Bs + r*128 + colbase);
          *(uint4*)(bt + (size_t)r*CONVD + colbase) = v;
        } else {
          if (r >= 61){
            uint4 v = *(uint4*)(Bs + r*128 + colbase);
            *(uint4*)(bt + (size_t)(r-58)*CONVD + colbase) = v;
          }
          U8 tp[4];
          #pragma unroll
          for (int k = 0; k < 4; ++k)
            tp[k].v = *(uint4*)(Bs + (r-3+k)*128 + colbase);
          U8 o;
          #pragma unroll
          for (int k2 = 0; k2 < 8; ++k2){
            int c = colbase + k2;
            float v = b2f(tp[0].h[k2])*cwsh[c][0] + b2f(tp[1].h[k2])*cwsh[c][1]
                    + b2f(tp[2].h[k2])*cwsh[c][2] + b2f(tp[3].h[k2])*cwsh[c][3] + cbsh[c];
            o.h[k2] = f2b(silu_f(v));
          }
          *(uint4*)(xdst + (size_t)r*CONVD + colbase) = o.v;
        }
      }
      __syncthreads();
    } else {
      #pragma unroll
      for (int i = 0; i < 2; ++i)
        #pragma unroll
        for (int jn = 0; jn < 4; ++jn)
          #pragma unroll
          for (int r = 0; r < 4; ++r){
            int m = wr*32 + i*16 + (l >> 4)*4 + r, n = wc*64 + jn*16 + (l & 15);
            if (n < 4){
              float v = acc[i][jn][r] + dt_bias[dj*4 + n];
              dtb[((size_t)dz*LSEQ + (size_t)mt*64 + m)*4 + n] = softplus_f(v);
            }
          }
    }
  }
}

// ---------------- chunk kernel 1: folded conv-fixup (rows 0..2); dt-scan; G, Y1, S^T ----------------
__global__ __launch_bounds__(256) void k_chunk1(u16* __restrict__ xact, const float* __restrict__ dtb,
    const float* __restrict__ A_log, const float* __restrict__ Dskip,
    const u16* __restrict__ bnd, const float* __restrict__ conv_w, const float* __restrict__ conv_b,
    u16* __restrict__ E, u16* __restrict__ y1, float* __restrict__ ltot, int d_base, int j){
  __shared__ __align__(16) u16 sB[4096], sC[4096], sM[4096], sXt[4096], sBw[4096];
  __shared__ float sLl[4][64], sdt[4][64];
  __shared__ float wexp[64];
  int c = blockIdx.x, dz = blockIdx.y, tid = threadIdx.x;
  int dj = (d_base+dz)*2 + j;
  int l = tid & 63, w = tid >> 6, wr = w >> 1, wc = w & 1;
  int mb = wr*32, nb = wc*32;
  int row0 = c*64;
  const u16* xa = xact + ((size_t)dz*LSEQ + row0)*CONVD;
  // per-wave dt scan: wave w = head w
  {
    float4 d4 = *(const float4*)(dtb + ((size_t)dz*LSEQ + row0 + l)*4);
    float dt = (w==0)?d4.x:((w==1)?d4.y:((w==2)?d4.z:d4.w));
    float A = -__expf(A_log[dj*4 + w]);
    float v = dt * A;
    #pragma unroll
    for (int o = 1; o < 64; o <<= 1){ float pv = __shfl_up(v, o); if (l >= o) v += pv; }
    sdt[w][l] = dt; sLl[w][l] = v;
    if (l == 63) ltot[((size_t)(dz*NCHUNK + c))*NH + w] = v;
  }
  // stage B (cols 256..319) and C (cols 320..383), rows 3..63 only (rows 0..2 come from the fix)
  #pragma unroll
  for (int it = 0; it < 2; ++it){
    int idx = it*256 + tid, t = idx >> 3, slot = idx & 7;
    if (t >= 3){
      uint4 vB = *(const uint4*)(xa + (size_t)t*CONVD + 256 + slot*8);
      uint4 vC = *(const uint4*)(xa + (size_t)t*CONVD + 320 + slot*8);
      *(uint4*)((char*)sB + SWZ(t, slot*16)) = vB;
      *(uint4*)((char*)sC + SWZ(t, slot*16)) = vC;
    }
  }
  // folded conv fixup: rows 0..2 of this tile from boundary buffer (same math as old k_convfix)
  U8 fixo; int fr = 0, fcg = 0;
  bool isfix = (tid < 144);
  if (isfix){
    fr = tid / 48; fcg = tid % 48;
    int col = fcg*8;
    const u16* bcur  = bnd + ((size_t)(dz*NCHUNK + c)*6)*CONVD;
    const u16* bprev = bnd + ((size_t)(dz*NCHUNK + c - 1)*6)*CONVD;
    U8 tp[4];
    #pragma unroll
    for (int k = 0; k < 4; ++k){
      int grow = fr - 3 + k;
      if (grow >= 0) tp[k].v = *(const uint4*)(bcur + (size_t)grow*CONVD + col);
      else if (c > 0) tp[k].v = *(const uint4*)(bprev + (size_t)(6 + grow)*CONVD + col);
      else tp[k].v = make_uint4(0,0,0,0);
    }
    #pragma unroll
    for (int k2 = 0; k2 < 8; ++k2){
      int cc = col + k2;
      const float* wp = conv_w + ((size_t)dj*CONVD + cc)*4;
      float v = b2f(tp[0].h[k2])*wp[0] + b2f(tp[1].h[k2])*wp[1]
              + b2f(tp[2].h[k2])*wp[2] + b2f(tp[3].h[k2])*wp[3] + conv_b[(size_t)dj*CONVD + cc];
      fixo.h[k2] = f2b(silu_f(v));
    }
    if (fcg >= 40){
      // C cols: patch LDS for this block + global store for k_chunk2
      *(uint4*)(xact + ((size_t)dz*LSEQ + row0 + fr)*CONVD + col) = fixo.v;
      *(uint4*)((char*)sC + SWZ(fr, (col - 320)*2)) = fixo.v;
    } else if (fcg >= 32){
      *(uint4*)((char*)sB + SWZ(fr, (col - 256)*2)) = fixo.v;
    }
    // fcg < 32 (X cols): kept in registers, patched per-head below
  }
  __syncthreads();
  // G[t][s] = sum_n C[t][n]*B[s][n]
  f32x4 g[2][2] = {};
  #pragma unroll
  for (int ks = 0; ks < 64; ks += 32){
    bf16x8 a[2], b[2];
    int cb = (ks + (l >> 4)*8)*2;
    #pragma unroll
    for (int i = 0; i < 2; ++i){
      a[i] = *(bf16x8*)((char*)sC + SWZ(mb + i*16 + (l & 15), cb));
      b[i] = *(bf16x8*)((char*)sB + SWZ(nb + i*16 + (l & 15), cb));
    }
    #pragma unroll
    for (int i = 0; i < 2; ++i)
      #pragma unroll
      for (int jn = 0; jn < 2; ++jn)
        g[i][jn] = __builtin_amdgcn_mfma_f32_16x16x32_bf16(a[i], b[jn], g[i][jn], 0, 0, 0);
  }
  for (int h = 0; h < NH; ++h){
    __syncthreads();
    if (tid < 64) wexp[tid] = __expf(sLl[h][63] - sLl[h][tid]) * sdt[h][tid];
    // stage X row-major into sC (rows 3..63 from global; rows 0..2 patched from fix registers)
    #pragma unroll
    for (int it = 0; it < 2; ++it){
      int idx = it*256 + tid, s = idx >> 3, slot = idx & 7;
      if (s >= 3){
        uint4 xv = *(const uint4*)(xa + (size_t)s*CONVD + h*64 + slot*8);
        *(uint4*)((char*)sC + SWZ(s, slot*16)) = xv;
      }
    }
    if (isfix && fcg < 32 && (fcg >> 3) == h)
      *(uint4*)((char*)sC + SWZ(fr, (fcg & 7)*16)) = fixo.v;
    // build M[t][s]
    #pragma unroll
    for (int i = 0; i < 2; ++i)
      #pragma unroll
      for (int jn = 0; jn < 2; ++jn)
        #pragma unroll
        for (int r = 0; r < 4; ++r){
          int t = mb + i*16 + (l >> 4)*4 + r;
          int s = nb + jn*16 + (l & 15);
          float v = (s <= t) ? g[i][jn][r]*__expf(sLl[h][t]-sLl[h][s])*sdt[h][s] : 0.f;
          *(u16*)((char*)sM + SWZ(t, s*2)) = f2b(v);
        }
    __syncthreads();
    // two-stage transpose: Xt[n][s] = X[s][n]; Bw[n][s] = B[s][n]*wexp[s]
    #pragma unroll
    for (int it = 0; it < 2; ++it){
      int idx = it*256 + tid, n = idx & 63, so = idx >> 6;
      U8 xo, bo;
      #pragma unroll
      for (int k = 0; k < 8; ++k){
        int s = so*8 + k;
        u16 xv = *(u16*)((char*)sC + SWZ(s, n*2));
        u16 bv = *(u16*)((char*)sB + SWZ(s, n*2));
        xo.h[k] = xv;
        bo.h[k] = f2b(b2f(bv) * wexp[s]);
      }
      *(uint4*)((char*)sXt + SWZ(n, so*16)) = xo.v;
      *(uint4*)((char*)sBw + SWZ(n, so*16)) = bo.v;
    }
    __syncthreads();
    // Y1 = M x Xt ; S^T = Xt x Bw
    f32x4 y1a[2][2] = {}, ssa[2][2] = {};
    #pragma unroll
    for (int ks = 0; ks < 64; ks += 32){
      int cb = (ks + (l >> 4)*8)*2;
      bf16x8 am[2], ax[2], bx[2], bw2[2];
      #pragma unroll
      for (int i = 0; i < 2; ++i){
        am[i]  = *(bf16x8*)((char*)sM  + SWZ(mb + i*16 + (l & 15), cb));
        ax[i]  = *(bf16x8*)((char*)sXt + SWZ(mb + i*16 + (l & 15), cb));
        bx[i]  = *(bf16x8*)((char*)sXt + SWZ(nb + i*16 + (l & 15), cb));
        bw2[i] = *(bf16x8*)((char*)sBw + SWZ(nb + i*16 + (l & 15), cb));
      }
      #pragma unroll
      for (int i = 0; i < 2; ++i)
        #pragma unroll
        for (int jn = 0; jn < 2; ++jn){
          y1a[i][jn] = __builtin_amdgcn_mfma_f32_16x16x32_bf16(am[i], bx[jn], y1a[i][jn], 0, 0, 0);
          ssa[i][jn] = __builtin_amdgcn_mfma_f32_16x16x32_bf16(ax[i], bw2[jn], ssa[i][jn], 0, 0, 0);
        }
    }
    __syncthreads();   // all waves done reading sM/sBw
    float dsk = Dskip[dj*NH + h];
    #pragma unroll
    for (int i = 0; i < 2; ++i)
      #pragma unroll
      for (int jn = 0; jn < 2; ++jn)
        #pragma unroll
        for (int r = 0; r < 4; ++r){
          int m = mb + i*16 + (l >> 4)*4 + r, n = nb + jn*16 + (l & 15);
          float xsv = b2f(*(u16*)((char*)sXt + SWZ(n, m*2)));
          *(u16*)((char*)sM  + SWZ(m, n*2)) = f2b(y1a[i][jn][r] + dsk * xsv);
          *(u16*)((char*)sBw + SWZ(m, n*2)) = f2b(ssa[i][jn][r]);
        }
    __syncthreads();
    u16* yr = y1 + ((size_t)dz*LSEQ + row0)*DI + h*64;
    u16* Ep = E + ((size_t)(dz*NCHUNK + c)*NH + h)*4096;
    #pragma unroll
    for (int it = 0; it < 2; ++it){
      int idx = it*256 + tid, r = idx >> 3, slot = idx & 7;
      uint4 vy = *(uint4*)((char*)sM  + SWZ(r, slot*16));
      uint4 ve = *(uint4*)((char*)sBw + SWZ(r, slot*16));
      *(uint4*)(yr + (size_t)r*DI + slot*8) = vy;
      *(uint4*)(Ep + r*64 + slot*8) = ve;
    }
  }
}

// ---------------- sequential carry over chunks, in-place on bf16 E, depth-16 prefetch ----------------
__global__ __launch_bounds__(256) void k_seq(u16* __restrict__ E, const float* __restrict__ ltot, int nd){
  int i = blockIdx.x*256 + threadIdx.x;
  if (i >= nd*16384) return;
  int dz = i >> 14, h = (i >> 12) & 3, np = i & 4095;
  const int stride = 16384;
  size_t base = (size_t)dz*NCHUNK*stride + (size_t)h*4096 + np;
  const float* lt = ltot + (size_t)dz*NCHUNK*NH + h;
  u16 eb[16]; float pb[16];
  #pragma unroll
  for (int q = 0; q < 16; ++q){ eb[q] = E[base + (size_t)q*stride]; pb[q] = lt[q*NH]; }
  float carry = 0.f;
  for (int cc = 0; cc < 256; cc += 16){
    u16 e2[16]; float p2[16];
    if (cc + 16 < 256){
      #pragma unroll
      for (int q = 0; q < 16; ++q){
        e2[q] = E[base + (size_t)(cc+16+q)*stride];
        p2[q] = lt[(cc+16+q)*NH];
      }
    }
    #pragma unroll
    for (int q = 0; q < 16; ++q){
      u16 cv = f2b(carry);
      carry = fmaf(__expf(pb[q]), carry, b2f(eb[q]));
      E[base + (size_t)(cc+q)*stride] = cv;
    }
    #pragma unroll
    for (int q = 0; q < 16; ++q){ eb[q] = e2[q]; pb[q] = p2[q]; }
  }
}

// ---------------- chunk kernel 2: Y2 MFMA; gate+RMS in LDS; fused out_proj (+residual/scatter) ----------------
__global__ __launch_bounds__(256) void k_chunk2(const u16* __restrict__ xact, const float* __restrict__ dtb,
    const float* __restrict__ A_log, const u16* __restrict__ zbuf, const u16* __restrict__ y1,
    const u16* __restrict__ E, const float* __restrict__ norm_w, const u16* __restrict__ wo,
    float* __restrict__ x, const int* __restrict__ sidx, u16* __restrict__ multi,
    int d_base, int j){
  __shared__ __align__(16) u16 SH[24576];   // 48KB: sC(8K) sHt(8K) Ylds(32K); Bs reuses sC+sHt
  u16* sC   = SH;
  u16* sHt  = SH + 4096;
  u16* Ylds = SH + 8192;
  u16* Bs   = SH;             // phase C weight tile / scatter staging (16KB)
  __shared__ float sLl[4][64];
  __shared__ float nws[256];
  int c = blockIdx.x, dz = blockIdx.y, tid = threadIdx.x;
  int dj = (d_base+dz)*2 + j;
  int l = tid & 63, w = tid >> 6, wr = w >> 1, wc = w & 1;
  int mb = wr*32, nb = wc*32;
  int row0 = c*64;
  const u16* xa = xact + ((size_t)dz*LSEQ + row0)*CONVD;
  if (tid < 64) ((float4*)nws)[tid] = ((const float4*)(norm_w + (size_t)dj*DI))[tid];
  // dt scan
  {
    float4 d4 = *(const float4*)(dtb + ((size_t)dz*LSEQ + row0 + l)*4);
    float dt = (w==0)?d4.x:((w==1)?d4.y:((w==2)?d4.z:d4.w));
    float A = -__expf(A_log[dj*4 + w]);
    float v = dt * A;
    #pragma unroll
    for (int o = 1; o < 64; o <<= 1){ float pv = __shfl_up(v, o); if (l >= o) v += pv; }
    sLl[w][l] = v;
  }
  // stage C (cols 320..383)
  #pragma unroll
  for (int it = 0; it < 2; ++it){
    int idx = it*256 + tid, t = idx >> 3, slot = idx & 7;
    uint4 vC = *(const uint4*)(xa + (size_t)t*CONVD + 320 + slot*8);
    *(uint4*)((char*)sC + SWZ(t, slot*16)) = vC;
  }
  // phase A: per-head MFMA, scaled Y2 into Ylds
  for (int h = 0; h < NH; ++h){
    __syncthreads();
    const u16* Hp = E + ((size_t)(dz*NCHUNK + c)*NH + h)*4096;
    #pragma unroll
    for (int it = 0; it < 2; ++it){
      int idx = it*256 + tid, p = idx >> 3, ng = idx & 7;
      uint4 v = *(const uint4*)(Hp + (size_t)p*64 + ng*8);
      *(uint4*)((char*)sHt + SWZ(p, ng*16)) = v;
    }
    __syncthreads();
    f32x4 acc[2][2] = {};
    #pragma unroll
    for (int ks = 0; ks < 64; ks += 32){
      int cb = (ks + (l >> 4)*8)*2;
      bf16x8 a[2], b[2];
      #pragma unroll
      for (int i = 0; i < 2; ++i){
        a[i] = *(bf16x8*)((char*)sC  + SWZ(mb + i*16 + (l & 15), cb));
        b[i] = *(bf16x8*)((char*)sHt + SWZ(nb + i*16 + (l & 15), cb));
      }
      #pragma unroll
      for (int i = 0; i < 2; ++i)
        #pragma unroll
        for (int jn = 0; jn < 2; ++jn)
          acc[i][jn] = __builtin_amdgcn_mfma_f32_16x16x32_bf16(a[i], b[jn], acc[i][jn], 0, 0, 0);
    }
    #pragma unroll
    for (int i = 0; i < 2; ++i)
      #pragma unroll
      for (int jn = 0; jn < 2; ++jn)
        #pragma unroll
        for (int r = 0; r < 4; ++r){
          int m = mb + i*16 + (l >> 4)*4 + r, n = nb + jn*16 + (l & 15);
          float e = __expf(sLl[h][m]);
          *(u16*)((char*)Ylds + SWZ4(m, (h*64 + n)*2)) = f2b(e * acc[i][jn][r]);
        }
  }
  __syncthreads();
  // phase B: row-parallel gate + RMSNorm, in-place normalized yn into Ylds
  {
    int r = tid >> 2, q = tid & 3;
    size_t rowbase = ((size_t)dz*LSEQ + row0 + r)*DI + q*64;
    float ssq = 0.f;
    U8 gs[8];
    #pragma unroll
    for (int v = 0; v < 8; ++v){
      U8 y2u; y2u.v = *(uint4*)((char*)Ylds + SWZ4(r, (q*64 + v*8)*2));
      U8 y1u; y1u.v = *(const uint4*)(y1 + rowbase + v*8);
      U8 zu;  zu.v  = *(const uint4*)(zbuf + rowbase + v*8);
      #pragma unroll
      for (int k = 0; k < 8; ++k){
        float gv = (b2f(y1u.h[k]) + b2f(y2u.h[k])) * silu_f(b2f(zu.h[k]));
        ssq += gv*gv;
        gs[v].h[k] = f2b(gv);
      }
    }
    ssq += __shfl_xor(ssq, 1);
    ssq += __shfl_xor(ssq, 2);
    float rr = rsqrtf(ssq * (1.f/256.f) + 1e-5f);
    #pragma unroll
    for (int v = 0; v < 8; ++v){
      U8 o;
      #pragma unroll
      for (int k = 0; k < 8; ++k)
        o.h[k] = f2b(b2f(gs[v].h[k]) * rr * nws[q*64 + v*8 + k]);
      *(uint4*)((char*)Ylds + SWZ4(r, (q*64 + v*8)*2)) = o.v;
    }
  }
  __syncthreads();
  // phase C: out_proj GEMM  yn[64x256] @ wo[dj][128x256]^T
  const u16* Bg = wo + (size_t)dj*DM*DI;
  f32x4 acc2[2][4] = {};
  for (int kt = 0; kt < 4; ++kt){
    #pragma unroll
    for (int it = 0; it < 4; ++it){
      int idx = it*256 + tid, r = idx >> 3, slot = idx & 7;
      uint4 vb = *(const uint4*)(Bg + (size_t)r*DI + kt*64 + slot*8);
      *(uint4*)((char*)Bs + SWZ(r, slot*16)) = vb;
    }
    __syncthreads();
    #pragma unroll
    for (int ks = 0; ks < 64; ks += 32){
      bf16x8 a[2], b[4];
      int cb = (ks + (l >> 4)*8)*2;
      int kcol = kt*64 + ks + (l >> 4)*8;
      #pragma unroll
      for (int i = 0; i < 2; ++i)
        a[i] = *(bf16x8*)((char*)Ylds + SWZ4(wr*32 + i*16 + (l & 15), kcol*2));
      #pragma unroll
      for (int i = 0; i < 4; ++i)
        b[i] = *(bf16x8*)((char*)Bs + SWZ(wc*64 + i*16 + (l & 15), cb));
      #pragma unroll
      for (int i = 0; i < 2; ++i)
        #pragma unroll
        for (int jn = 0; jn < 4; ++jn)
          acc2[i][jn] = __builtin_amdgcn_mfma_f32_16x16x32_bf16(a[i], b[jn], acc2[i][jn], 0, 0, 0);
    }
    __syncthreads();
  }
  float* xr = x + ((size_t)dz*LSEQ + row0)*DM;
  if (j == 0){
    #pragma unroll
    for (int i = 0; i < 2; ++i)
      #pragma unroll
      for (int jn = 0; jn < 4; ++jn)
        #pragma unroll
        for (int r = 0; r < 4; ++r){
          int m = wr*32 + i*16 + (l >> 4)*4 + r, n = wc*64 + jn*16 + (l & 15);
          xr[(size_t)m*DM + n] += acc2[i][jn][r];
        }
  } else {
    // residual + convert -> Bs (64x128), then row-scatter into multi
    #pragma unroll
    for (int i = 0; i < 2; ++i)
      #pragma unroll
      for (int jn = 0; jn < 4; ++jn)
        #pragma unroll
        for (int r = 0; r < 4; ++r){
          int m = wr*32 + i*16 + (l >> 4)*4 + r, n = wc*64 + jn*16 + (l & 15);
          float res = xr[(size_t)m*DM + n] + acc2[i][jn][r];
          Bs[m*128 + n] = f2b(res);
        }
    __syncthreads();
    const int* ip = sidx + (size_t)(d_base+dz)*LSEQ + row0;
    #pragma unroll
    for (int it = 0; it < 4; ++it){
      int e = it*256 + tid, r = e >> 4, slot = e & 15;
      int orig = ip[r];
      uint4 v = *(uint4*)(Bs + r*128 + slot*8);
      *(uint4*)(multi + (size_t)orig*768 + (size_t)(d_base+dz)*128 + slot*8) = v;
    }
  }
}

// ---------------- fuse: fused LN(768) + GEMM + bias + exact gelu; N-split x2 ----------------
__global__ __launch_bounds__(256) void k_fuse(const u16* __restrict__ multi, const u16* __restrict__ wbf,
                                              const float* __restrict__ lnw, const float* __restrict__ lnb,
                                              const float* __restrict__ fb, float* __restrict__ out){
  __shared__ __align__(16) u16 As[64*64];    // 8KB
  __shared__ __align__(16) u16 Bs[64*64];    // 8KB
  __shared__ float swn[768], sbn[768], smu[64], sinv[64];
  int nh = blockIdx.x, mt = blockIdx.y, tid = threadIdx.x;
  int l = tid & 63, w = tid >> 6, wr = w >> 1, wc = w & 1;
  for (int e = tid; e < 192; e += 256){
    ((float4*)swn)[e] = ((const float4*)lnw)[e];
    ((float4*)sbn)[e] = ((const float4*)lnb)[e];
  }
  {
    int r = tid >> 2, q = tid & 3;
    const u16* row = multi + ((size_t)(mt*64 + r))*768 + q*192;
    float s = 0.f, ss = 0.f;
    #pragma unroll
    for (int v = 0; v < 24; ++v){
      U8 u; u.v = *(const uint4*)(row + v*8);
      #pragma unroll
      for (int k = 0; k < 8; ++k){ float f = b2f(u.h[k]); s += f; ss += f*f; }
    }
    s += __shfl_xor(s, 1); s += __shfl_xor(s, 2);
    ss += __shfl_xor(ss, 1); ss += __shfl_xor(ss, 2);
    if (q == 0){
      float mu = s * (1.f/768.f);
      smu[r] = mu;
      sinv[r] = rsqrtf(ss * (1.f/768.f) - mu*mu + 1e-5f);
    }
  }
  __syncthreads();
  const u16* Ag = multi + (size_t)mt*64*768;
  const u16* Wg = wbf + (size_t)nh*64*768;
  f32x4 acc[2][2] = {};
  for (int kt = 0; kt < 12; ++kt){
    #pragma unroll
    for (int it = 0; it < 2; ++it){
      int e = it*256 + tid, r = e >> 3, slot = e & 7;
      U8 u; u.v = *(const uint4*)(Ag + (size_t)r*768 + kt*64 + slot*8);
      float mu = smu[r], inv = sinv[r];
      U8 o;
      #pragma unroll
      for (int k = 0; k < 8; ++k){
        int col = kt*64 + slot*8 + k;
        o.h[k] = f2b((b2f(u.h[k]) - mu)*inv*swn[col] + sbn[col]);
      }
      *(uint4*)((char*)As + SWZ(r, slot*16)) = o.v;
    }
    #pragma unroll
    for (int it = 0; it < 2; ++it){
      int e = it*256 + tid, r = e >> 3, slot = e & 7;
      uint4 vb = *(const uint4*)(Wg + (size_t)r*768 + kt*64 + slot*8);
      *(uint4*)((char*)Bs + SWZ(r, slot*16)) = vb;
    }
    __syncthreads();
    #pragma unroll
    for (int ks = 0; ks < 64; ks += 32){
      bf16x8 a[2], b[2];
      int cb = (ks + (l >> 4)*8)*2;
      #pragma unroll
      for (int i = 0; i < 2; ++i)
        a[i] = *(bf16x8*)((char*)As + SWZ(wr*32 + i*16 + (l & 15), cb));
      #pragma unroll
      for (int i = 0; i < 2; ++i)
        b[i] = *(bf16x8*)((char*)Bs + SWZ(wc*32 + i*16 + (l & 15), cb));
      #pragma unroll
      for (int i = 0; i < 2; ++i)
        #pragma unroll
        for (int jn = 0; jn < 2; ++jn)
          acc[i][jn] = __builtin_amdgcn_mfma_f32_16x16x32_bf16(a[i], b[jn], acc[i][jn], 0, 0, 0);
    }
    __syncthreads();
  }
  #pragma unroll
  for (int i = 0; i < 2; ++i)
    #pragma unroll
    for (int jn = 0; jn < 2; ++jn)
      #pragma unroll
      for (int r = 0; r < 4; ++r){
        int m = wr*32 + i*16 + (l >> 4)*4 + r;
        int n = nh*64 + wc*32 + jn*16 + (l & 15);
        float v = acc[i][jn][r] + fb[n];
        float gl = 0.5f * v * (1.f + erff(v * 0.70710678118654752f));
        out[(size_t)(mt*64 + m)*DM + n] = gl;
      }
}

extern "C" void kernel_launch(void* const* d_in, const int* in_sizes, int n_in,
                              void* d_out, int out_size, void* d_ws, size_t ws_size,
                              hipStream_t stream){
  (void)in_sizes; (void)n_in; (void)out_size;
  const float* vectors  = (const float*)d_in[0];
  const int*   coords   = (const int*)d_in[1];
  const float* ln_w     = (const float*)d_in[2];
  const float* ln_b     = (const float*)d_in[3];
  const float* in_w     = (const float*)d_in[4];
  const float* conv_w   = (const float*)d_in[5];
  const float* conv_b   = (const float*)d_in[6];
  const float* dt_bias  = (const float*)d_in[7];
  const float* A_log    = (const float*)d_in[8];
  const float* D_skip   = (const float*)d_in[9];
  const float* norm_w   = (const float*)d_in[10];
  const float* out_w    = (const float*)d_in[11];
  const float* fuse_lw  = (const float*)d_in[12];
  const float* fuse_lb  = (const float*)d_in[13];
  const float* fuse_w   = (const float*)d_in[14];
  const float* fuse_b   = (const float*)d_in[15];
  float* out = (float*)d_out;

  char* p = (char*)d_ws;
  auto carve = [&](size_t bytes)->char*{
    char* r = p; p += (bytes + 255) & ~(size_t)255; return r;
  };
  int* idxb = (int*)carve((size_t)NDIR*LSEQ*4);
  unsigned long long* skey  = (unsigned long long*)carve((size_t)NDIR*LSEQ*8);
  unsigned long long* skey2 = (unsigned long long*)carve((size_t)NDIR*LSEQ*8);
  int* starts = (int*)carve((size_t)NDIR*1025*4);
  int* cursor = (int*)carve((size_t)NDIR*1024*4);
  u16* multi = (u16*)carve((size_t)LSEQ*768*2);
  u16* wbf_in   = (u16*)carve((size_t)NW0*2);
  u16* wbf_out  = (u16*)carve((size_t)NW1*2);
  u16* wbf_fuse = (u16*)carve((size_t)NW2*2);

  size_t fixed = (size_t)(p - (char*)d_ws);
  auto need = [&](int nd)->size_t{
    size_t s = 0; auto a = [&](size_t b){ s += (b + 255) & ~(size_t)255; };
    a((size_t)nd*LSEQ*DM*4);      // xbuf (f32 residual)
    a((size_t)nd*LSEQ*DI*2);      // zbuf (bf16)
    a((size_t)nd*LSEQ*CONVD*2);   // xact (bf16, conv'd)
    a((size_t)nd*NCHUNK*6*CONVD*2); // bnd (boundary rows)
    a((size_t)nd*LSEQ*NH*4);      // dtb (f32)
    a((size_t)nd*NCHUNK*NH*4);    // ltot (f32)
    a((size_t)nd*LSEQ*DI*2);      // y1 (bf16)
    a((size_t)nd*NCHUNK*NH*DSTATE*HD*2); // E (bf16, in-place scan)
    return s;
  };
  // adaptive batching: largest nd in {6,3,2,1} that fits the workspace
  int nd = 1;
  {
    const int cands[3] = {6, 3, 2};
    for (int ci = 0; ci < 3; ++ci){
      if (fixed + need(cands[ci]) <= ws_size){ nd = cands[ci]; break; }
    }
  }
  if (fixed + need(nd) > ws_size) return;  // insufficient workspace: no-op

  float* xbuf = (float*)carve((size_t)nd*LSEQ*DM*4);
  u16*   zbuf = (u16*)carve((size_t)nd*LSEQ*DI*2);
  u16*   xact = (u16*)carve((size_t)nd*LSEQ*CONVD*2);
  u16*   bnd  = (u16*)carve((size_t)nd*NCHUNK*6*CONVD*2);
  float* dtb  = (float*)carve((size_t)nd*LSEQ*NH*4);
  float* ltot = (float*)carve((size_t)nd*NCHUNK*NH*4);
  u16*   y1b  = (u16*)carve((size_t)nd*LSEQ*DI*2);
  u16*   Ebuf = (u16*)carve((size_t)nd*NCHUNK*NH*DSTATE*HD*2);

  k_cvt         <<<(NW0+NW1+NW2+255)/256, 256, 0, stream>>>(in_w, out_w, fuse_w, wbf_in, wbf_out, wbf_fuse, cursor);
  k_sort1       <<<(NDIR*LSEQ + 255)/256, 256, 0, stream>>>(coords, skey, cursor);
  k_sort_scan   <<<NDIR, 1024, 0, stream>>>(cursor, starts);
  k_sort_scatter<<<(NDIR*LSEQ + 255)/256, 256, 0, stream>>>(skey, skey2, cursor);
  k_sort_rank   <<<(NDIR*LSEQ + 255)/256, 256, 0, stream>>>(skey2, starts, idxb);

  for (int d_base = 0; d_base < NDIR; d_base += nd){
    k_gather<<<nd*2048, 256, 0, stream>>>(vectors, idxb, xbuf, d_base, nd);
    for (int j = 0; j < 2; ++j){
      k_inproj<<<dim3(3, LSEQ/64, nd), 256, 0, stream>>>(xbuf, ln_w, ln_b, wbf_in, dt_bias,
                                                         conv_w, conv_b, zbuf, xact, bnd, dtb, d_base, j);
      k_chunk1<<<dim3(NCHUNK, nd), 256, 0, stream>>>(xact, dtb, A_log, D_skip, bnd, conv_w, conv_b,
                                                     Ebuf, y1b, ltot, d_base, j);
      k_seq   <<<(nd*16384 + 255)/256, 256, 0, stream>>>(Ebuf, ltot, nd);
      k_chunk2<<<dim3(NCHUNK, nd), 256, 0, stream>>>(xact, dtb, A_log, zbuf, y1b, Ebuf,
                                                     norm_w, wbf_out, xbuf, idxb, multi, d_base, j);
    }
  }
  k_fuse <<<dim3(2, LSEQ/64), 256, 0, stream>>>(multi, wbf_fuse, fuse_lw, fuse_lb, fuse_b, out);
}

// Round 22
// 715.956 us; speedup vs baseline: 1.0478x; 1.0248x over previous
//
#include <hip/hip_runtime.h>
#include <math.h>

#define LSEQ   16384
#define DM     128
#define DI     256
#define DSTATE 64
#define NH     4
#define HD     64
#define CONVD  384
#define DPROJ  644
#define NDIR   6
#define NCHUNK 256      // LSEQ/64

typedef unsigned short u16;
typedef __attribute__((ext_vector_type(8))) __bf16 bf16x8;
typedef __attribute__((ext_vector_type(4))) float f32x4;

union U8 { uint4 v; u16 h[8]; };

__device__ __constant__ int ORD[6][3] = {{0,1,2},{0,2,1},{1,0,2},{1,2,0},{2,0,1},{2,1,0}};

__device__ __forceinline__ float softplus_f(float x){
  float ax = fabsf(x);
  return fmaxf(x, 0.f) + log1pf(__expf(-ax));
}
__device__ __forceinline__ float silu_f(float x){
  return x / (1.f + __expf(-x));
}
__device__ __forceinline__ u16 f2b(float f){
  unsigned u = __float_as_uint(f);
  unsigned r = (u + 0x7fffu + ((u >> 16) & 1u)) >> 16;
  return (u16)r;
}
__device__ __forceinline__ float b2f(u16 h){
  return __uint_as_float(((unsigned)h) << 16);
}
// XOR swizzle for [rows][128B] bf16 LDS tiles: conflict-free ds_read_b128 (T2)
__device__ __forceinline__ int SWZ(int r, int cb){
  return r*128 + (cb ^ ((r & 7) << 4));
}
// swizzle for 256B-row LDS tiles (inproj As)
__device__ __forceinline__ int SWZ2(int r, int cb){
  return r*256 + (cb ^ ((r & 7) << 4));
}
// swizzle for 512B-row LDS tiles (chunk2 Ylds)
__device__ __forceinline__ int SWZ4(int r, int cb){
  return r*512 + (cb ^ ((r & 7) << 4));
}

// ---------------- weight convert to bf16 (+ cursor zeroing) ----------------
#define NW0 (12*768*128)
#define NW1 (12*128*256)
#define NW2 (128*768)
__global__ __launch_bounds__(256) void k_cvt(const float* __restrict__ in_w,
                                             const float* __restrict__ out_w,
                                             const float* __restrict__ fuse_w,
                                             u16* __restrict__ wi, u16* __restrict__ wo,
                                             u16* __restrict__ wf, int* __restrict__ cursor){
  int i = blockIdx.x*256 + threadIdx.x;
  if (i < NDIR*1024) cursor[i] = 0;
  if (i < NW0){
    int dj = i / (768*128), rem = i % (768*128), r = rem >> 7, c = rem & 127;
    float v = (r < DPROJ) ? in_w[((size_t)dj*DPROJ + r)*128 + c] : 0.f;
    wi[i] = f2b(v);
  } else if (i < NW0 + NW1){
    int k = i - NW0;
    wo[k] = f2b(out_w[k]);
  } else if (i < NW0 + NW1 + NW2){
    int k = i - NW0 - NW1;
    wf[k] = f2b(fuse_w[k]);
  }
}

// ---------------- sort ----------------
__global__ __launch_bounds__(256) void k_sort1(const int* __restrict__ coords,
                                               unsigned long long* __restrict__ skey,
                                               int* __restrict__ cursor){
  int i = blockIdx.x*256 + threadIdx.x;
  if (i >= NDIR*LSEQ) return;
  int d = i >> 14, t = i & 16383;
  unsigned k = ((unsigned)coords[t*4 + ORD[d][0]] << 20)
             | ((unsigned)coords[t*4 + ORD[d][1]] << 10)
             |  (unsigned)coords[t*4 + ORD[d][2]];
  skey[i] = ((unsigned long long)k << 14) | (unsigned long long)t;
  atomicAdd(&cursor[(d << 10) + (k >> 20)], 1);
}

__global__ void k_sort_scan(int* __restrict__ cursor, int* __restrict__ starts){
  __shared__ int sh[1024];
  int d = blockIdx.x, t = threadIdx.x;
  int v = cursor[d*1024 + t];
  sh[t] = v; __syncthreads();
  for (int off = 1; off < 1024; off <<= 1){
    int a = (t >= off) ? sh[t-off] : 0;
    __syncthreads();
    sh[t] += a;
    __syncthreads();
  }
  int incl = sh[t], excl = incl - v;
  starts[d*1025 + t] = excl;
  cursor[d*1024 + t] = excl;
  if (t == 1023) starts[d*1025 + 1024] = incl;
}

__global__ __launch_bounds__(256) void k_sort_scatter(const unsigned long long* __restrict__ skey,
                                                      unsigned long long* __restrict__ skey2,
                                                      int* __restrict__ cursor){
  int i = blockIdx.x*256 + threadIdx.x;
  if (i >= NDIR*LSEQ) return;
  int d = i >> 14;
  unsigned long long v = skey[i];
  int b = (int)(v >> 34);
  int pos = atomicAdd(&cursor[(d << 10) + b], 1);
  skey2[(size_t)d*LSEQ + pos] = v;
}

__global__ __launch_bounds__(256) void k_sort_rank(const unsigned long long* __restrict__ skey2,
                                                   const int* __restrict__ starts,
                                                   int* __restrict__ idx){
  int i = blockIdx.x*256 + threadIdx.x;
  if (i >= NDIR*LSEQ) return;
  int d = i >> 14;
  unsigned long long v = skey2[i];
  int b = (int)(v >> 34);
  int s = starts[d*1025 + b], e = starts[d*1025 + b + 1];
  int r = s;
  for (int q = s; q < e; ++q) r += (skey2[(size_t)d*LSEQ + q] < v);
  int orig = (int)(v & 16383ULL);
  idx[(size_t)d*LSEQ + r] = orig;
}

// ---------------- in_proj: 64-row tiles; fused LN (j==0 gathers from vectors); conv+silu fused ----------------
__global__ __launch_bounds__(256) void k_inproj(const float* __restrict__ xres,
    const float* __restrict__ vecs, const int* __restrict__ sidx,
    const float* __restrict__ lnw, const float* __restrict__ lnb,
    const u16* __restrict__ wbf, const float* __restrict__ dt_bias,
    const float* __restrict__ conv_w, const float* __restrict__ conv_b,
    u16* __restrict__ zbuf, u16* __restrict__ xact, u16* __restrict__ bnd,
    float* __restrict__ dtb, int d_base, int j){
  __shared__ __align__(16) u16 As[64*128];   // 16KB (row stride 256B, swizzled)
  __shared__ __align__(16) u16 Bs[128*64];   // 16KB (weights; reused as 64x128 epilogue buf)
  __shared__ float cwsh[128][4];
  __shared__ float cbsh[128];
  int bpair = blockIdx.x, mt = blockIdx.y, dz = blockIdx.z, tid = threadIdx.x;
  int dj = (d_base+dz)*2 + j;
  int l = tid & 63, w = tid >> 6, wr = w >> 1, wc = w & 1;
  // ---- parallel LN: 2 threads per row (r15 summation order); j==0 gathers rows from vectors ----
  if (tid < 128){
    int r = tid >> 1, half = tid & 1;
    const float4* xr;
    if (j == 0){
      int src = sidx[(size_t)(d_base+dz)*LSEQ + (size_t)mt*64 + r];
      xr = (const float4*)(vecs + (size_t)src*DM) + half*16;
    } else {
      xr = (const float4*)(xres + ((size_t)dz*LSEQ + (size_t)mt*64 + r)*DM) + half*16;
    }
    float4 v[16];
    #pragma unroll
    for (int q = 0; q < 16; ++q) v[q] = xr[q];
    float s = 0.f, ss2 = 0.f;
    #pragma unroll
    for (int q = 0; q < 16; ++q){
      s   += v[q].x + v[q].y + v[q].z + v[q].w;
      ss2 += v[q].x*v[q].x + v[q].y*v[q].y + v[q].z*v[q].z + v[q].w*v[q].w;
    }
    s += __shfl_xor(s, 1); ss2 += __shfl_xor(ss2, 1);
    float mu = s*(1.f/128.f);
    float var = ss2*(1.f/128.f) - mu*mu;
    float inv = rsqrtf(var + 1e-5f);
    const float4* w4 = (const float4*)(lnw + (size_t)dj*DM) + half*16;
    const float4* b4 = (const float4*)(lnb + (size_t)dj*DM) + half*16;
    #pragma unroll
    for (int g = 0; g < 8; ++g){
      float4 a = v[2*g], b = v[2*g+1];
      float4 wa = w4[2*g], wb = w4[2*g+1];
      float4 ba = b4[2*g], bb = b4[2*g+1];
      U8 pk;
      pk.h[0] = f2b((a.x-mu)*inv*wa.x + ba.x);
      pk.h[1] = f2b((a.y-mu)*inv*wa.y + ba.y);
      pk.h[2] = f2b((a.z-mu)*inv*wa.z + ba.z);
      pk.h[3] = f2b((a.w-mu)*inv*wa.w + ba.w);
      pk.h[4] = f2b((b.x-mu)*inv*wb.x + bb.x);
      pk.h[5] = f2b((b.y-mu)*inv*wb.y + bb.y);
      pk.h[6] = f2b((b.z-mu)*inv*wb.z + bb.z);
      pk.h[7] = f2b((b.w-mu)*inv*wb.w + bb.w);
      int c0 = half*64 + g*8;
      *(uint4*)((char*)As + SWZ2(r, c0*2)) = pk.v;
    }
  }
  __syncthreads();
  for (int ib = 0; ib < 2; ++ib){
    int bn = bpair*2 + ib;
    const u16* Wd = wbf + (size_t)dj*768*DM + (size_t)bn*128*DM;
    f32x4 acc[2][4] = {};
    for (int kt = 0; kt < 2; ++kt){
      #pragma unroll
      for (int it = 0; it < 4; ++it){
        int idx = it*256 + tid, r = idx >> 3, slot = idx & 7;
        uint4 vb = *(const uint4*)(Wd + (size_t)r*DM + kt*64 + slot*8);
        *(uint4*)((char*)Bs + SWZ(r, slot*16)) = vb;
      }
      __syncthreads();
      #pragma unroll
      for (int ks = 0; ks < 64; ks += 32){
        bf16x8 a[2], b[4];
        int cbb = (ks + (l >> 4)*8)*2;
        int kea = kt*64 + ks + (l >> 4)*8;
        #pragma unroll
        for (int i = 0; i < 2; ++i){
          int ra = wr*32 + i*16 + (l & 15);
          a[i] = *(bf16x8*)((char*)As + SWZ2(ra, kea*2));
        }
        #pragma unroll
        for (int i = 0; i < 4; ++i)
          b[i] = *(bf16x8*)((char*)Bs + SWZ(wc*64 + i*16 + (l & 15), cbb));
        #pragma unroll
        for (int i = 0; i < 2; ++i)
          #pragma unroll
          for (int jn = 0; jn < 4; ++jn)
            acc[i][jn] = __builtin_amdgcn_mfma_f32_16x16x32_bf16(a[i], b[jn], acc[i][jn], 0, 0, 0);
      }
      __syncthreads();
    }
    if (bn < 2){
      // z columns: stage 64x128 tile into Bs (linear), 16B coalesced writes
      #pragma unroll
      for (int i = 0; i < 2; ++i)
        #pragma unroll
        for (int jn = 0; jn < 4; ++jn)
          #pragma unroll
          for (int r = 0; r < 4; ++r){
            int m = wr*32 + i*16 + (l >> 4)*4 + r, n = wc*64 + jn*16 + (l & 15);
            Bs[m*128 + n] = f2b(acc[i][jn][r]);
          }
      __syncthreads();
      u16* dst = zbuf + ((size_t)dz*LSEQ + (size_t)mt*64)*DI + bn*128;
      #pragma unroll
      for (int it = 0; it < 4; ++it){
        int idx = it*256 + tid, r = idx >> 4, slot = idx & 15;
        uint4 v = *(uint4*)(Bs + r*128 + slot*8);
        *(uint4*)(dst + (size_t)r*DI + slot*8) = v;
      }
      __syncthreads();
    } else if (bn < 5){
      // xBC columns: stage raw tile, load conv weights, then fused conv+silu (rows>=3) + boundary store
      int xco0 = bn*128 - 256;
      #pragma unroll
      for (int i = 0; i < 2; ++i)
        #pragma unroll
        for (int jn = 0; jn < 4; ++jn)
          #pragma unroll
          for (int r = 0; r < 4; ++r){
            int m = wr*32 + i*16 + (l >> 4)*4 + r, n = wc*64 + jn*16 + (l & 15);
            Bs[m*128 + n] = f2b(acc[i][jn][r]);
          }
      if (tid < 128){
        const float* wp = conv_w + ((size_t)dj*CONVD + xco0 + tid)*4;
        cwsh[tid][0]=wp[0]; cwsh[tid][1]=wp[1]; cwsh[tid][2]=wp[2]; cwsh[tid][3]=wp[3];
        cbsh[tid] = conv_b[(size_t)dj*CONVD + xco0 + tid];
      }
      __syncthreads();
      u16* bt = bnd + ((size_t)(dz*NCHUNK + mt)*6)*CONVD + xco0;
      u16* xdst = xact + ((size_t)dz*LSEQ + (size_t)mt*64)*CONVD + xco0;
      #pragma unroll
      for (int it = 0; it < 4; ++it){
        int idx = it*256 + tid, r = idx >> 4, slot = idx & 15;
        int colbase = slot*8;
        if (r < 3){
          uint4 v = *(uint4*)(Bs + r*128 + colbase);
          *(uint4*)(bt + (size_t)r*CONVD + colbase) = v;
        } else {
          if (r >= 61){
            uint4 v = *(uint4*)(Bs + r*128 + colbase);
            *(uint4*)(bt + (size_t)(r-58)*CONVD + colbase) = v;
          }
          U8 tp[4];
          #pragma unroll
          for (int k = 0; k < 4; ++k)
            tp[k].v = *(uint4*)(Bs + (r-3+k)*128 + colbase);
          U8 o;
          #pragma unroll
          for (int k2 = 0; k2 < 8; ++k2){
            int c = colbase + k2;
            float v = b2f(tp[0].h[k2])*cwsh[c][0] + b2f(tp[1].h[k2])*cwsh[c][1]
                    + b2f(tp[2].h[k2])*cwsh[c][2] + b2f(tp[3].h[k2])*cwsh[c][3] + cbsh[c];
            o.h[k2] = f2b(silu_f(v));
          }
          *(uint4*)(xdst + (size_t)r*CONVD + colbase) = o.v;
        }
      }
      __syncthreads();
    } else {
      #pragma unroll
      for (int i = 0; i < 2; ++i)
        #pragma unroll
        for (int jn = 0; jn < 4; ++jn)
          #pragma unroll
          for (int r = 0; r < 4; ++r){
            int m = wr*32 + i*16 + (l >> 4)*4 + r, n = wc*64 + jn*16 + (l & 15);
            if (n < 4){
              float v = acc[i][jn][r] + dt_bias[dj*4 + n];
              dtb[((size_t)dz*LSEQ + (size_t)mt*64 + m)*4 + n] = softplus_f(v);
            }
          }
    }
  }
}

// ---------------- conv fixup: rows 0..2 of each 64-row tile from boundary buffer ----------------
__global__ __launch_bounds__(256) void k_convfix(const u16* __restrict__ bnd,
    const float* __restrict__ conv_w, const float* __restrict__ conv_b,
    u16* __restrict__ xact, int d_base, int j){
  int mt = blockIdx.x, dz = blockIdx.y, tid = threadIdx.x;
  int dj = (d_base+dz)*2 + j;
  if (tid >= 144) return;
  int r = tid / 48, cg = tid % 48;
  int col = cg*8;
  const u16* bcur  = bnd + ((size_t)(dz*NCHUNK + mt)*6)*CONVD;
  const u16* bprev = bnd + ((size_t)(dz*NCHUNK + mt - 1)*6)*CONVD;
  U8 tp[4];
  #pragma unroll
  for (int k = 0; k < 4; ++k){
    int grow = r - 3 + k;
    if (grow >= 0) tp[k].v = *(const uint4*)(bcur + (size_t)grow*CONVD + col);
    else if (mt > 0) tp[k].v = *(const uint4*)(bprev + (size_t)(6 + grow)*CONVD + col);
    else tp[k].v = make_uint4(0,0,0,0);
  }
  U8 o;
  #pragma unroll
  for (int k2 = 0; k2 < 8; ++k2){
    int c = col + k2;
    const float* wp = conv_w + ((size_t)dj*CONVD + c)*4;
    float v = b2f(tp[0].h[k2])*wp[0] + b2f(tp[1].h[k2])*wp[1]
            + b2f(tp[2].h[k2])*wp[2] + b2f(tp[3].h[k2])*wp[3] + conv_b[(size_t)dj*CONVD + c];
    o.h[k2] = f2b(silu_f(v));
  }
  *(uint4*)(xact + ((size_t)dz*LSEQ + (size_t)mt*64 + r)*CONVD + col) = o.v;
}

// ---------------- chunk kernel 1: dt-scan fused; two-stage transpose; G, Y1, S^T ----------------
__global__ __launch_bounds__(256) void k_chunk1(const u16* __restrict__ xact, const float* __restrict__ dtb,
    const float* __restrict__ A_log, const float* __restrict__ Dskip,
    u16* __restrict__ E, u16* __restrict__ y1, float* __restrict__ ltot, int d_base, int j){
  __shared__ __align__(16) u16 sB[4096], sC[4096], sM[4096], sXt[4096], sBw[4096];
  __shared__ float sLl[4][64], sdt[4][64];
  __shared__ float wexp[64];
  int c = blockIdx.x, dz = blockIdx.y, tid = threadIdx.x;
  int dj = (d_base+dz)*2 + j;
  int l = tid & 63, w = tid >> 6, wr = w >> 1, wc = w & 1;
  int mb = wr*32, nb = wc*32;
  int row0 = c*64;
  const u16* xa = xact + ((size_t)dz*LSEQ + row0)*CONVD;
  // per-wave dt scan: wave w = head w
  {
    float4 d4 = *(const float4*)(dtb + ((size_t)dz*LSEQ + row0 + l)*4);
    float dt = (w==0)?d4.x:((w==1)?d4.y:((w==2)?d4.z:d4.w));
    float A = -__expf(A_log[dj*4 + w]);
    float v = dt * A;
    #pragma unroll
    for (int o = 1; o < 64; o <<= 1){ float pv = __shfl_up(v, o); if (l >= o) v += pv; }
    sdt[w][l] = dt; sLl[w][l] = v;
    if (l == 63) ltot[((size_t)(dz*NCHUNK + c))*NH + w] = v;
  }
  // stage B (cols 256..319) and C (cols 320..383)
  #pragma unroll
  for (int it = 0; it < 2; ++it){
    int idx = it*256 + tid, t = idx >> 3, slot = idx & 7;
    uint4 vB = *(const uint4*)(xa + (size_t)t*CONVD + 256 + slot*8);
    uint4 vC = *(const uint4*)(xa + (size_t)t*CONVD + 320 + slot*8);
    *(uint4*)((char*)sB + SWZ(t, slot*16)) = vB;
    *(uint4*)((char*)sC + SWZ(t, slot*16)) = vC;
  }
  __syncthreads();
  // G[t][s] = sum_n C[t][n]*B[s][n]
  f32x4 g[2][2] = {};
  #pragma unroll
  for (int ks = 0; ks < 64; ks += 32){
    bf16x8 a[2], b[2];
    int cb = (ks + (l >> 4)*8)*2;
    #pragma unroll
    for (int i = 0; i < 2; ++i){
      a[i] = *(bf16x8*)((char*)sC + SWZ(mb + i*16 + (l & 15), cb));
      b[i] = *(bf16x8*)((char*)sB + SWZ(nb + i*16 + (l & 15), cb));
    }
    #pragma unroll
    for (int i = 0; i < 2; ++i)
      #pragma unroll
      for (int jn = 0; jn < 2; ++jn)
        g[i][jn] = __builtin_amdgcn_mfma_f32_16x16x32_bf16(a[i], b[jn], g[i][jn], 0, 0, 0);
  }
  for (int h = 0; h < NH; ++h){
    __syncthreads();
    if (tid < 64) wexp[tid] = __expf(sLl[h][63] - sLl[h][tid]) * sdt[h][tid];
    // stage X row-major into sC (vectorized)
    #pragma unroll
    for (int it = 0; it < 2; ++it){
      int idx = it*256 + tid, s = idx >> 3, slot = idx & 7;
      uint4 xv = *(const uint4*)(xa + (size_t)s*CONVD + h*64 + slot*8);
      *(uint4*)((char*)sC + SWZ(s, slot*16)) = xv;
    }
    // build M[t][s]
    #pragma unroll
    for (int i = 0; i < 2; ++i)
      #pragma unroll
      for (int jn = 0; jn < 2; ++jn)
        #pragma unroll
        for (int r = 0; r < 4; ++r){
          int t = mb + i*16 + (l >> 4)*4 + r;
          int s = nb + jn*16 + (l & 15);
          float v = (s <= t) ? g[i][jn][r]*__expf(sLl[h][t]-sLl[h][s])*sdt[h][s] : 0.f;
          *(u16*)((char*)sM + SWZ(t, s*2)) = f2b(v);
        }
    __syncthreads();
    // two-stage transpose: Xt[n][s] = X[s][n]; Bw[n][s] = B[s][n]*wexp[s]
    #pragma unroll
    for (int it = 0; it < 2; ++it){
      int idx = it*256 + tid, n = idx & 63, so = idx >> 6;
      U8 xo, bo;
      #pragma unroll
      for (int k = 0; k < 8; ++k){
        int s = so*8 + k;
        u16 xv = *(u16*)((char*)sC + SWZ(s, n*2));
        u16 bv = *(u16*)((char*)sB + SWZ(s, n*2));
        xo.h[k] = xv;
        bo.h[k] = f2b(b2f(bv) * wexp[s]);
      }
      *(uint4*)((char*)sXt + SWZ(n, so*16)) = xo.v;
      *(uint4*)((char*)sBw + SWZ(n, so*16)) = bo.v;
    }
    __syncthreads();
    // Y1 = M x Xt ; S^T = Xt x Bw
    f32x4 y1a[2][2] = {}, ssa[2][2] = {};
    #pragma unroll
    for (int ks = 0; ks < 64; ks += 32){
      int cb = (ks + (l >> 4)*8)*2;
      bf16x8 am[2], ax[2], bx[2], bw2[2];
      #pragma unroll
      for (int i = 0; i < 2; ++i){
        am[i]  = *(bf16x8*)((char*)sM  + SWZ(mb + i*16 + (l & 15), cb));
        ax[i]  = *(bf16x8*)((char*)sXt + SWZ(mb + i*16 + (l & 15), cb));
        bx[i]  = *(bf16x8*)((char*)sXt + SWZ(nb + i*16 + (l & 15), cb));
        bw2[i] = *(bf16x8*)((char*)sBw + SWZ(nb + i*16 + (l & 15), cb));
      }
      #pragma unroll
      for (int i = 0; i < 2; ++i)
        #pragma unroll
        for (int jn = 0; jn < 2; ++jn){
          y1a[i][jn] = __builtin_amdgcn_mfma_f32_16x16x32_bf16(am[i], bx[jn], y1a[i][jn], 0, 0, 0);
          ssa[i][jn] = __builtin_amdgcn_mfma_f32_16x16x32_bf16(ax[i], bw2[jn], ssa[i][jn], 0, 0, 0);
        }
    }
    __syncthreads();   // all waves done reading sM/sBw
    float dsk = Dskip[dj*NH + h];
    #pragma unroll
    for (int i = 0; i < 2; ++i)
      #pragma unroll
      for (int jn = 0; jn < 2; ++jn)
        #pragma unroll
        for (int r = 0; r < 4; ++r){
          int m = mb + i*16 + (l >> 4)*4 + r, n = nb + jn*16 + (l & 15);
          float xsv = b2f(*(u16*)((char*)sXt + SWZ(n, m*2)));
          *(u16*)((char*)sM  + SWZ(m, n*2)) = f2b(y1a[i][jn][r] + dsk * xsv);
          *(u16*)((char*)sBw + SWZ(m, n*2)) = f2b(ssa[i][jn][r]);
        }
    __syncthreads();
    u16* yr = y1 + ((size_t)dz*LSEQ + row0)*DI + h*64;
    u16* Ep = E + ((size_t)(dz*NCHUNK + c)*NH + h)*4096;
    #pragma unroll
    for (int it = 0; it < 2; ++it){
      int idx = it*256 + tid, r = idx >> 3, slot = idx & 7;
      uint4 vy = *(uint4*)((char*)sM  + SWZ(r, slot*16));
      uint4 ve = *(uint4*)((char*)sBw + SWZ(r, slot*16));
      *(uint4*)(yr + (size_t)r*DI + slot*8) = vy;
      *(uint4*)(Ep + r*64 + slot*8) = ve;
    }
  }
}

// ---------------- sequential carry over chunks, in-place on bf16 E, depth-16 prefetch ----------------
__global__ __launch_bounds__(256) void k_seq(u16* __restrict__ E, const float* __restrict__ ltot, int nd){
  int i = blockIdx.x*256 + threadIdx.x;
  if (i >= nd*16384) return;
  int dz = i >> 14, h = (i >> 12) & 3, np = i & 4095;
  const int stride = 16384;
  size_t base = (size_t)dz*NCHUNK*stride + (size_t)h*4096 + np;
  const float* lt = ltot + (size_t)dz*NCHUNK*NH + h;
  u16 eb[16]; float pb[16];
  #pragma unroll
  for (int q = 0; q < 16; ++q){ eb[q] = E[base + (size_t)q*stride]; pb[q] = lt[q*NH]; }
  float carry = 0.f;
  for (int cc = 0; cc < 256; cc += 16){
    u16 e2[16]; float p2[16];
    if (cc + 16 < 256){
      #pragma unroll
      for (int q = 0; q < 16; ++q){
        e2[q] = E[base + (size_t)(cc+16+q)*stride];
        p2[q] = lt[(cc+16+q)*NH];
      }
    }
    #pragma unroll
    for (int q = 0; q < 16; ++q){
      u16 cv = f2b(carry);
      carry = fmaf(__expf(pb[q]), carry, b2f(eb[q]));
      E[base + (size_t)(cc+q)*stride] = cv;
    }
    #pragma unroll
    for (int q = 0; q < 16; ++q){ eb[q] = e2[q]; pb[q] = p2[q]; }
  }
}

// ---------------- chunk kernel 2: Y2 MFMA; gate+RMS in LDS; fused out_proj (+residual/scatter) ----------------
__global__ __launch_bounds__(256) void k_chunk2(const u16* __restrict__ xact, const float* __restrict__ dtb,
    const float* __restrict__ A_log, const u16* __restrict__ zbuf, const u16* __restrict__ y1,
    const u16* __restrict__ E, const float* __restrict__ norm_w, const u16* __restrict__ wo,
    float* __restrict__ x, const float* __restrict__ vecs, const int* __restrict__ sidx,
    u16* __restrict__ multi, int d_base, int j){
  __shared__ __align__(16) u16 SH[24576];   // 48KB: sC(8K) sHt(8K) Ylds(32K); Bs reuses sC+sHt
  u16* sC   = SH;
  u16* sHt  = SH + 4096;
  u16* Ylds = SH + 8192;
  u16* Bs   = SH;             // phase C weight tile / scatter staging (16KB)
  __shared__ float sLl[4][64];
  __shared__ float nws[256];
  int c = blockIdx.x, dz = blockIdx.y, tid = threadIdx.x;
  int dj = (d_base+dz)*2 + j;
  int l = tid & 63, w = tid >> 6, wr = w >> 1, wc = w & 1;
  int mb = wr*32, nb = wc*32;
  int row0 = c*64;
  const u16* xa = xact + ((size_t)dz*LSEQ + row0)*CONVD;
  if (tid < 64) ((float4*)nws)[tid] = ((const float4*)(norm_w + (size_t)dj*DI))[tid];
  // dt scan
  {
    float4 d4 = *(const float4*)(dtb + ((size_t)dz*LSEQ + row0 + l)*4);
    float dt = (w==0)?d4.x:((w==1)?d4.y:((w==2)?d4.z:d4.w));
    float A = -__expf(A_log[dj*4 + w]);
    float v = dt * A;
    #pragma unroll
    for (int o = 1; o < 64; o <<= 1){ float pv = __shfl_up(v, o); if (l >= o) v += pv; }
    sLl[w][l] = v;
  }
  // stage C (cols 320..383)
  #pragma unroll
  for (int it = 0; it < 2; ++it){
    int idx = it*256 + tid, t = idx >> 3, slot = idx & 7;
    uint4 vC = *(const uint4*)(xa + (size_t)t*CONVD + 320 + slot*8);
    *(uint4*)((char*)sC + SWZ(t, slot*16)) = vC;
  }
  // phase A: per-head MFMA, scaled Y2 into Ylds
  for (int h = 0; h < NH; ++h){
    __syncthreads();
    const u16* Hp = E + ((size_t)(dz*NCHUNK + c)*NH + h)*4096;
    #pragma unroll
    for (int it = 0; it < 2; ++it){
      int idx = it*256 + tid, p = idx >> 3, ng = idx & 7;
      uint4 v = *(const uint4*)(Hp + (size_t)p*64 + ng*8);
      *(uint4*)((char*)sHt + SWZ(p, ng*16)) = v;
    }
    __syncthreads();
    f32x4 acc[2][2] = {};
    #pragma unroll
    for (int ks = 0; ks < 64; ks += 32){
      int cb = (ks + (l >> 4)*8)*2;
      bf16x8 a[2], b[2];
      #pragma unroll
      for (int i = 0; i < 2; ++i){
        a[i] = *(bf16x8*)((char*)sC  + SWZ(mb + i*16 + (l & 15), cb));
        b[i] = *(bf16x8*)((char*)sHt + SWZ(nb + i*16 + (l & 15), cb));
      }
      #pragma unroll
      for (int i = 0; i < 2; ++i)
        #pragma unroll
        for (int jn = 0; jn < 2; ++jn)
          acc[i][jn] = __builtin_amdgcn_mfma_f32_16x16x32_bf16(a[i], b[jn], acc[i][jn], 0, 0, 0);
    }
    #pragma unroll
    for (int i = 0; i < 2; ++i)
      #pragma unroll
      for (int jn = 0; jn < 2; ++jn)
        #pragma unroll
        for (int r = 0; r < 4; ++r){
          int m = mb + i*16 + (l >> 4)*4 + r, n = nb + jn*16 + (l & 15);
          float e = __expf(sLl[h][m]);
          *(u16*)((char*)Ylds + SWZ4(m, (h*64 + n)*2)) = f2b(e * acc[i][jn][r]);
        }
  }
  __syncthreads();
  // phase B: row-parallel gate + RMSNorm, in-place normalized yn into Ylds
  {
    int r = tid >> 2, q = tid & 3;
    size_t rowbase = ((size_t)dz*LSEQ + row0 + r)*DI + q*64;
    float ssq = 0.f;
    U8 gs[8];
    #pragma unroll
    for (int v = 0; v < 8; ++v){
      U8 y2u; y2u.v = *(uint4*)((char*)Ylds + SWZ4(r, (q*64 + v*8)*2));
      U8 y1u; y1u.v = *(const uint4*)(y1 + rowbase + v*8);
      U8 zu;  zu.v  = *(const uint4*)(zbuf + rowbase + v*8);
      #pragma unroll
      for (int k = 0; k < 8; ++k){
        float gv = (b2f(y1u.h[k]) + b2f(y2u.h[k])) * silu_f(b2f(zu.h[k]));
        ssq += gv*gv;
        gs[v].h[k] = f2b(gv);
      }
    }
    ssq += __shfl_xor(ssq, 1);
    ssq += __shfl_xor(ssq, 2);
    float rr = rsqrtf(ssq * (1.f/256.f) + 1e-5f);
    #pragma unroll
    for (int v = 0; v < 8; ++v){
      U8 o;
      #pragma unroll
      for (int k = 0; k < 8; ++k)
        o.h[k] = f2b(b2f(gs[v].h[k]) * rr * nws[q*64 + v*8 + k]);
      *(uint4*)((char*)Ylds + SWZ4(r, (q*64 + v*8)*2)) = o.v;
    }
  }
  __syncthreads();
  // phase C: out_proj GEMM  yn[64x256] @ wo[dj][128x256]^T
  const u16* Bg = wo + (size_t)dj*DM*DI;
  f32x4 acc2[2][4] = {};
  for (int kt = 0; kt < 4; ++kt){
    #pragma unroll
    for (int it = 0; it < 4; ++it){
      int idx = it*256 + tid, r = idx >> 3, slot = idx & 7;
      uint4 vb = *(const uint4*)(Bg + (size_t)r*DI + kt*64 + slot*8);
      *(uint4*)((char*)Bs + SWZ(r, slot*16)) = vb;
    }
    __syncthreads();
    #pragma unroll
    for (int ks = 0; ks < 64; ks += 32){
      bf16x8 a[2], b[4];
      int cb = (ks + (l >> 4)*8)*2;
      int kcol = kt*64 + ks + (l >> 4)*8;
      #pragma unroll
      for (int i = 0; i < 2; ++i)
        a[i] = *(bf16x8*)((char*)Ylds + SWZ4(wr*32 + i*16 + (l & 15), kcol*2));
      #pragma unroll
      for (int i = 0; i < 4; ++i)
        b[i] = *(bf16x8*)((char*)Bs + SWZ(wc*64 + i*16 + (l & 15), cb));
      #pragma unroll
      for (int i = 0; i < 2; ++i)
        #pragma unroll
        for (int jn = 0; jn < 4; ++jn)
          acc2[i][jn] = __builtin_amdgcn_mfma_f32_16x16x32_bf16(a[i], b[jn], acc2[i][jn], 0, 0, 0);
    }
    __syncthreads();
  }
  float* xr = x + ((size_t)dz*LSEQ + row0)*DM;
  if (j == 0){
    // residual base gathered directly from vectors (xbuf never pre-initialized)
    const int* ip = sidx + (size_t)(d_base+dz)*LSEQ + row0;
    #pragma unroll
    for (int i = 0; i < 2; ++i)
      #pragma unroll
      for (int r = 0; r < 4; ++r){
        int m = wr*32 + i*16 + (l >> 4)*4 + r;
        int src = ip[m];
        #pragma unroll
        for (int jn = 0; jn < 4; ++jn){
          int n = wc*64 + jn*16 + (l & 15);
          xr[(size_t)m*DM + n] = vecs[(size_t)src*DM + n] + acc2[i][jn][r];
        }
      }
  } else {
    // residual + convert -> Bs (64x128), then row-scatter into multi
    #pragma unroll
    for (int i = 0; i < 2; ++i)
      #pragma unroll
      for (int jn = 0; jn < 4; ++jn)
        #pragma unroll
        for (int r = 0; r < 4; ++r){
          int m = wr*32 + i*16 + (l >> 4)*4 + r, n = wc*64 + jn*16 + (l & 15);
          float res = xr[(size_t)m*DM + n] + acc2[i][jn][r];
          Bs[m*128 + n] = f2b(res);
        }
    __syncthreads();
    const int* ip = sidx + (size_t)(d_base+dz)*LSEQ + row0;
    #pragma unroll
    for (int it = 0; it < 4; ++it){
      int e = it*256 + tid, r = e >> 4, slot = e & 15;
      int orig = ip[r];
      uint4 v = *(uint4*)(Bs + r*128 + slot*8);
      *(uint4*)(multi + (size_t)orig*768 + (size_t)(d_base+dz)*128 + slot*8) = v;
    }
  }
}

// ---------------- fuse: fused LN(768) + GEMM + bias + exact gelu; N-split x2 ----------------
__global__ __launch_bounds__(256) void k_fuse(const u16* __restrict__ multi, const u16* __restrict__ wbf,
                                              const float* __restrict__ lnw, const float* __restrict__ lnb,
                                              const float* __restrict__ fb, float* __restrict__ out){
  __shared__ __align__(16) u16 As[64*64];    // 8KB
  __shared__ __align__(16) u16 Bs[64*64];    // 8KB
  __shared__ float swn[768], sbn[768], smu[64], sinv[64];
  int nh = blockIdx.x, mt = blockIdx.y, tid = threadIdx.x;
  int l = tid & 63, w = tid >> 6, wr = w >> 1, wc = w & 1;
  for (int e = tid; e < 192; e += 256){
    ((float4*)swn)[e] = ((const float4*)lnw)[e];
    ((float4*)sbn)[e] = ((const float4*)lnb)[e];
  }
  {
    int r = tid >> 2, q = tid & 3;
    const u16* row = multi + ((size_t)(mt*64 + r))*768 + q*192;
    float s = 0.f, ss = 0.f;
    #pragma unroll
    for (int v = 0; v < 24; ++v){
      U8 u; u.v = *(const uint4*)(row + v*8);
      #pragma unroll
      for (int k = 0; k < 8; ++k){ float f = b2f(u.h[k]); s += f; ss += f*f; }
    }
    s += __shfl_xor(s, 1); s += __shfl_xor(s, 2);
    ss += __shfl_xor(ss, 1); ss += __shfl_xor(ss, 2);
    if (q == 0){
      float mu = s * (1.f/768.f);
      smu[r] = mu;
      sinv[r] = rsqrtf(ss * (1.f/768.f) - mu*mu + 1e-5f);
    }
  }
  __syncthreads();
  const u16* Ag = multi + (size_t)mt*64*768;
  const u16* Wg = wbf + (size_t)nh*64*768;
  f32x4 acc[2][2] = {};
  for (int kt = 0; kt < 12; ++kt){
    #pragma unroll
    for (int it = 0; it < 2; ++it){
      int e = it*256 + tid, r = e >> 3, slot = e & 7;
      U8 u; u.v = *(const uint4*)(Ag + (size_t)r*768 + kt*64 + slot*8);
      float mu = smu[r], inv = sinv[r];
      U8 o;
      #pragma unroll
      for (int k = 0; k < 8; ++k){
        int col = kt*64 + slot*8 + k;
        o.h[k] = f2b((b2f(u.h[k]) - mu)*inv*swn[col] + sbn[col]);
      }
      *(uint4*)((char*)As + SWZ(r, slot*16)) = o.v;
    }
    #pragma unroll
    for (int it = 0; it < 2; ++it){
      int e = it*256 + tid, r = e >> 3, slot = e & 7;
      uint4 vb = *(const uint4*)(Wg + (size_t)r*768 + kt*64 + slot*8);
      *(uint4*)((char*)Bs + SWZ(r, slot*16)) = vb;
    }
    __syncthreads();
    #pragma unroll
    for (int ks = 0; ks < 64; ks += 32){
      bf16x8 a[2], b[2];
      int cb = (ks + (l >> 4)*8)*2;
      #pragma unroll
      for (int i = 0; i < 2; ++i)
        a[i] = *(bf16x8*)((char*)As + SWZ(wr*32 + i*16 + (l & 15), cb));
      #pragma unroll
      for (int i = 0; i < 2; ++i)
        b[i] = *(bf16x8*)((char*)Bs + SWZ(wc*32 + i*16 + (l & 15), cb));
      #pragma unroll
      for (int i = 0; i < 2; ++i)
        #pragma unroll
        for (int jn = 0; jn < 2; ++jn)
          acc[i][jn] = __builtin_amdgcn_mfma_f32_16x16x32_bf16(a[i], b[jn], acc[i][jn], 0, 0, 0);
    }
    __syncthreads();
  }
  #pragma unroll
  for (int i = 0; i < 2; ++i)
    #pragma unroll
    for (int jn = 0; jn < 2; ++jn)
      #pragma unroll
      for (int r = 0; r < 4; ++r){
        int m = wr*32 + i*16 + (l >> 4)*4 + r;
        int n = nh*64 + wc*32 + jn*16 + (l & 15);
        float v = acc[i][jn][r] + fb[n];
        float gl = 0.5f * v * (1.f + erff(v * 0.70710678118654752f));
        out[(size_t)(mt*64 + m)*DM + n] = gl;
      }
}

extern "C" void kernel_launch(void* const* d_in, const int* in_sizes, int n_in,
                              void* d_out, int out_size, void* d_ws, size_t ws_size,
                              hipStream_t stream){
  (void)in_sizes; (void)n_in; (void)out_size;
  const float* vectors  = (const float*)d_in[0];
  const int*   coords   = (const int*)d_in[1];
  const float* ln_w     = (const float*)d_in[2];
  const float* ln_b     = (const float*)d_in[3];
  const float* in_w     = (const float*)d_in[4];
  const float* conv_w   = (const float*)d_in[5];
  const float* conv_b   = (const float*)d_in[6];
  const float* dt_bias  = (const float*)d_in[7];
  const float* A_log    = (const float*)d_in[8];
  const float* D_skip   = (const float*)d_in[9];
  const float* norm_w   = (const float*)d_in[10];
  const float* out_w    = (const float*)d_in[11];
  const float* fuse_lw  = (const float*)d_in[12];
  const float* fuse_lb  = (const float*)d_in[13];
  const float* fuse_w   = (const float*)d_in[14];
  const float* fuse_b   = (const float*)d_in[15];
  float* out = (float*)d_out;

  char* p = (char*)d_ws;
  auto carve = [&](size_t bytes)->char*{
    char* r = p; p += (bytes + 255) & ~(size_t)255; return r;
  };
  int* idxb = (int*)carve((size_t)NDIR*LSEQ*4);
  unsigned long long* skey  = (unsigned long long*)carve((size_t)NDIR*LSEQ*8);
  unsigned long long* skey2 = (unsigned long long*)carve((size_t)NDIR*LSEQ*8);
  int* starts = (int*)carve((size_t)NDIR*1025*4);
  int* cursor = (int*)carve((size_t)NDIR*1024*4);
  u16* multi = (u16*)carve((size_t)LSEQ*768*2);
  u16* wbf_in   = (u16*)carve((size_t)NW0*2);
  u16* wbf_out  = (u16*)carve((size_t)NW1*2);
  u16* wbf_fuse = (u16*)carve((size_t)NW2*2);

  size_t fixed = (size_t)(p - (char*)d_ws);
  auto need = [&](int nd)->size_t{
    size_t s = 0; auto a = [&](size_t b){ s += (b + 255) & ~(size_t)255; };
    a((size_t)nd*LSEQ*DM*4);      // xbuf (f32 residual)
    a((size_t)nd*LSEQ*DI*2);      // zbuf (bf16)
    a((size_t)nd*LSEQ*CONVD*2);   // xact (bf16, conv'd)
    a((size_t)nd*NCHUNK*6*CONVD*2); // bnd (boundary rows)
    a((size_t)nd*LSEQ*NH*4);      // dtb (f32)
    a((size_t)nd*NCHUNK*NH*4);    // ltot (f32)
    a((size_t)nd*LSEQ*DI*2);      // y1 (bf16)
    a((size_t)nd*NCHUNK*NH*DSTATE*HD*2); // E (bf16, in-place scan)
    return s;
  };
  // adaptive batching: largest nd in {6,3,2,1} that fits the workspace
  int nd = 1;
  {
    const int cands[3] = {6, 3, 2};
    for (int ci = 0; ci < 3; ++ci){
      if (fixed + need(cands[ci]) <= ws_size){ nd = cands[ci]; break; }
    }
  }
  if (fixed + need(nd) > ws_size) return;  // insufficient workspace: no-op

  float* xbuf = (float*)carve((size_t)nd*LSEQ*DM*4);
  u16*   zbuf = (u16*)carve((size_t)nd*LSEQ*DI*2);
  u16*   xact = (u16*)carve((size_t)nd*LSEQ*CONVD*2);
  u16*   bnd  = (u16*)carve((size_t)nd*NCHUNK*6*CONVD*2);
  float* dtb  = (float*)carve((size_t)nd*LSEQ*NH*4);
  float* ltot = (float*)carve((size_t)nd*NCHUNK*NH*4);
  u16*   y1b  = (u16*)carve((size_t)nd*LSEQ*DI*2);
  u16*   Ebuf = (u16*)carve((size_t)nd*NCHUNK*NH*DSTATE*HD*2);

  k_cvt         <<<(NW0+NW1+NW2+255)/256, 256, 0, stream>>>(in_w, out_w, fuse_w, wbf_in, wbf_out, wbf_fuse, cursor);
  k_sort1       <<<(NDIR*LSEQ + 255)/256, 256, 0, stream>>>(coords, skey, cursor);
  k_sort_scan   <<<NDIR, 1024, 0, stream>>>(cursor, starts);
  k_sort_scatter<<<(NDIR*LSEQ + 255)/256, 256, 0, stream>>>(skey, skey2, cursor);
  k_sort_rank   <<<(NDIR*LSEQ + 255)/256, 256, 0, stream>>>(skey2, starts, idxb);

  for (int d_base = 0; d_base < NDIR; d_base += nd){
    for (int j = 0; j < 2; ++j){
      k_inproj<<<dim3(3, LSEQ/64, nd), 256, 0, stream>>>(xbuf, vectors, idxb, ln_w, ln_b, wbf_in, dt_bias,
                                                         conv_w, conv_b, zbuf, xact, bnd, dtb, d_base, j);
      k_convfix<<<dim3(NCHUNK, nd), 256, 0, stream>>>(bnd, conv_w, conv_b, xact, d_base, j);
      k_chunk1<<<dim3(NCHUNK, nd), 256, 0, stream>>>(xact, dtb, A_log, D_skip,
                                                     Ebuf, y1b, ltot, d_base, j);
      k_seq   <<<(nd*16384 + 255)/256, 256, 0, stream>>>(Ebuf, ltot, nd);
      k_chunk2<<<dim3(NCHUNK, nd), 256, 0, stream>>>(xact, dtb, A_log, zbuf, y1b, Ebuf,
                                                     norm_w, wbf_out, xbuf, vectors, idxb, multi, d_base, j);
    }
  }
  k_fuse <<<dim3(2, LSEQ/64), 256, 0, stream>>>(multi, wbf_fuse, fuse_lw, fuse_lb, fuse_b, out);
}

// Round 23
// 713.119 us; speedup vs baseline: 1.0519x; 1.0040x over previous
//
#include <hip/hip_runtime.h>
#include <math.h>

#define LSEQ   16384
#define DM     128
#define DI     256
#define DSTATE 64
#define NH     4
#define HD     64
#define CONVD  384
#define DPROJ  644
#define NDIR   6
#define NCHUNK 256      // LSEQ/64

typedef unsigned short u16;
typedef __attribute__((ext_vector_type(8))) __bf16 bf16x8;
typedef __attribute__((ext_vector_type(4))) float f32x4;

union U8 { uint4 v; u16 h[8]; };

__device__ __constant__ int ORD[6][3] = {{0,1,2},{0,2,1},{1,0,2},{1,2,0},{2,0,1},{2,1,0}};

__device__ __forceinline__ float softplus_f(float x){
  float ax = fabsf(x);
  return fmaxf(x, 0.f) + log1pf(__expf(-ax));
}
__device__ __forceinline__ float silu_f(float x){
  return x / (1.f + __expf(-x));
}
__device__ __forceinline__ u16 f2b(float f){
  unsigned u = __float_as_uint(f);
  unsigned r = (u + 0x7fffu + ((u >> 16) & 1u)) >> 16;
  return (u16)r;
}
__device__ __forceinline__ float b2f(u16 h){
  return __uint_as_float(((unsigned)h) << 16);
}
// XOR swizzle for [rows][128B] bf16 LDS tiles: conflict-free ds_read_b128 (T2)
__device__ __forceinline__ int SWZ(int r, int cb){
  return r*128 + (cb ^ ((r & 7) << 4));
}
// swizzle for 256B-row LDS tiles (inproj As)
__device__ __forceinline__ int SWZ2(int r, int cb){
  return r*256 + (cb ^ ((r & 7) << 4));
}
// swizzle for 512B-row LDS tiles (chunk2 Ylds)
__device__ __forceinline__ int SWZ4(int r, int cb){
  return r*512 + (cb ^ ((r & 7) << 4));
}

// async global->LDS staging of one 128x64-u16 tile into SWZ layout.
// LDS dest is LINEAR (wave-uniform base + lane*16); source column carries the
// inverse swizzle (XOR involution within each 128B row) so SWZ readers see
// the right bytes (rule #21: linear dest + inverse-swz source + swz read).
__device__ __forceinline__ void stage_tile_async(const u16* __restrict__ srcbase, size_t srcstride,
                                                 u16* lds, int w, int l){
  int cbl = (l & 7) * 16;                 // byte col within 128B LDS row
  int cbs = cbl ^ ((l >> 3) << 4);        // swizzled source byte col ((r&7)==(l>>3))
  #pragma unroll
  for (int it = 0; it < 4; ++it){
    int chunk = it*4 + w;                 // 0..15, wave-uniform
    int r = chunk*8 + (l >> 3);           // 0..127
    const u16* src = srcbase + (size_t)r*srcstride + (cbs >> 1);
    __builtin_amdgcn_global_load_lds(
        (const __attribute__((address_space(1))) void*)src,
        (__attribute__((address_space(3))) void*)((char*)lds + chunk*1024),
        16, 0, 0);
  }
}

// ---------------- weight convert to bf16 (+ cursor zeroing) ----------------
#define NW0 (12*768*128)
#define NW1 (12*128*256)
#define NW2 (128*768)
__global__ __launch_bounds__(256) void k_cvt(const float* __restrict__ in_w,
                                             const float* __restrict__ out_w,
                                             const float* __restrict__ fuse_w,
                                             u16* __restrict__ wi, u16* __restrict__ wo,
                                             u16* __restrict__ wf, int* __restrict__ cursor){
  int i = blockIdx.x*256 + threadIdx.x;
  if (i < NDIR*1024) cursor[i] = 0;
  if (i < NW0){
    int dj = i / (768*128), rem = i % (768*128), r = rem >> 7, c = rem & 127;
    float v = (r < DPROJ) ? in_w[((size_t)dj*DPROJ + r)*128 + c] : 0.f;
    wi[i] = f2b(v);
  } else if (i < NW0 + NW1){
    int k = i - NW0;
    wo[k] = f2b(out_w[k]);
  } else if (i < NW0 + NW1 + NW2){
    int k = i - NW0 - NW1;
    wf[k] = f2b(fuse_w[k]);
  }
}

// ---------------- sort ----------------
__global__ __launch_bounds__(256) void k_sort1(const int* __restrict__ coords,
                                               unsigned long long* __restrict__ skey,
                                               int* __restrict__ cursor){
  int i = blockIdx.x*256 + threadIdx.x;
  if (i >= NDIR*LSEQ) return;
  int d = i >> 14, t = i & 16383;
  unsigned k = ((unsigned)coords[t*4 + ORD[d][0]] << 20)
             | ((unsigned)coords[t*4 + ORD[d][1]] << 10)
             |  (unsigned)coords[t*4 + ORD[d][2]];
  skey[i] = ((unsigned long long)k << 14) | (unsigned long long)t;
  atomicAdd(&cursor[(d << 10) + (k >> 20)], 1);
}

__global__ void k_sort_scan(int* __restrict__ cursor, int* __restrict__ starts){
  __shared__ int sh[1024];
  int d = blockIdx.x, t = threadIdx.x;
  int v = cursor[d*1024 + t];
  sh[t] = v; __syncthreads();
  for (int off = 1; off < 1024; off <<= 1){
    int a = (t >= off) ? sh[t-off] : 0;
    __syncthreads();
    sh[t] += a;
    __syncthreads();
  }
  int incl = sh[t], excl = incl - v;
  starts[d*1025 + t] = excl;
  cursor[d*1024 + t] = excl;
  if (t == 1023) starts[d*1025 + 1024] = incl;
}

__global__ __launch_bounds__(256) void k_sort_scatter(const unsigned long long* __restrict__ skey,
                                                      unsigned long long* __restrict__ skey2,
                                                      int* __restrict__ cursor){
  int i = blockIdx.x*256 + threadIdx.x;
  if (i >= NDIR*LSEQ) return;
  int d = i >> 14;
  unsigned long long v = skey[i];
  int b = (int)(v >> 34);
  int pos = atomicAdd(&cursor[(d << 10) + b], 1);
  skey2[(size_t)d*LSEQ + pos] = v;
}

__global__ __launch_bounds__(256) void k_sort_rank(const unsigned long long* __restrict__ skey2,
                                                   const int* __restrict__ starts,
                                                   int* __restrict__ idx){
  int i = blockIdx.x*256 + threadIdx.x;
  if (i >= NDIR*LSEQ) return;
  int d = i >> 14;
  unsigned long long v = skey2[i];
  int b = (int)(v >> 34);
  int s = starts[d*1025 + b], e = starts[d*1025 + b + 1];
  int r = s;
  for (int q = s; q < e; ++q) r += (skey2[(size_t)d*LSEQ + q] < v);
  int orig = (int)(v & 16383ULL);
  idx[(size_t)d*LSEQ + r] = orig;
}

// ---------------- in_proj: 64-row tiles; fused LN (j==0 gathers from vectors); conv+silu fused ----------------
__global__ __launch_bounds__(256) void k_inproj(const float* __restrict__ xres,
    const float* __restrict__ vecs, const int* __restrict__ sidx,
    const float* __restrict__ lnw, const float* __restrict__ lnb,
    const u16* __restrict__ wbf, const float* __restrict__ dt_bias,
    const float* __restrict__ conv_w, const float* __restrict__ conv_b,
    u16* __restrict__ zbuf, u16* __restrict__ xact, u16* __restrict__ bnd,
    float* __restrict__ dtb, int d_base, int j){
  __shared__ __align__(16) u16 As[64*128];   // 16KB (row stride 256B, swizzled)
  __shared__ __align__(16) u16 Bs[128*64];   // 16KB (weights; reused as 64x128 epilogue buf)
  __shared__ float cwsh[128][4];
  __shared__ float cbsh[128];
  int bpair = blockIdx.x, mt = blockIdx.y, dz = blockIdx.z, tid = threadIdx.x;
  int dj = (d_base+dz)*2 + j;
  int l = tid & 63, w = tid >> 6, wr = w >> 1, wc = w & 1;
  // ---- parallel LN: 2 threads per row (r15 summation order); j==0 gathers rows from vectors ----
  if (tid < 128){
    int r = tid >> 1, half = tid & 1;
    const float4* xr;
    if (j == 0){
      int src = sidx[(size_t)(d_base+dz)*LSEQ + (size_t)mt*64 + r];
      xr = (const float4*)(vecs + (size_t)src*DM) + half*16;
    } else {
      xr = (const float4*)(xres + ((size_t)dz*LSEQ + (size_t)mt*64 + r)*DM) + half*16;
    }
    float4 v[16];
    #pragma unroll
    for (int q = 0; q < 16; ++q) v[q] = xr[q];
    float s = 0.f, ss2 = 0.f;
    #pragma unroll
    for (int q = 0; q < 16; ++q){
      s   += v[q].x + v[q].y + v[q].z + v[q].w;
      ss2 += v[q].x*v[q].x + v[q].y*v[q].y + v[q].z*v[q].z + v[q].w*v[q].w;
    }
    s += __shfl_xor(s, 1); ss2 += __shfl_xor(ss2, 1);
    float mu = s*(1.f/128.f);
    float var = ss2*(1.f/128.f) - mu*mu;
    float inv = rsqrtf(var + 1e-5f);
    const float4* w4 = (const float4*)(lnw + (size_t)dj*DM) + half*16;
    const float4* b4 = (const float4*)(lnb + (size_t)dj*DM) + half*16;
    #pragma unroll
    for (int g = 0; g < 8; ++g){
      float4 a = v[2*g], b = v[2*g+1];
      float4 wa = w4[2*g], wb = w4[2*g+1];
      float4 ba = b4[2*g], bb = b4[2*g+1];
      U8 pk;
      pk.h[0] = f2b((a.x-mu)*inv*wa.x + ba.x);
      pk.h[1] = f2b((a.y-mu)*inv*wa.y + ba.y);
      pk.h[2] = f2b((a.z-mu)*inv*wa.z + ba.z);
      pk.h[3] = f2b((a.w-mu)*inv*wa.w + ba.w);
      pk.h[4] = f2b((b.x-mu)*inv*wb.x + bb.x);
      pk.h[5] = f2b((b.y-mu)*inv*wb.y + bb.y);
      pk.h[6] = f2b((b.z-mu)*inv*wb.z + bb.z);
      pk.h[7] = f2b((b.w-mu)*inv*wb.w + bb.w);
      int c0 = half*64 + g*8;
      *(uint4*)((char*)As + SWZ2(r, c0*2)) = pk.v;
    }
  }
  __syncthreads();
  for (int ib = 0; ib < 2; ++ib){
    int bn = bpair*2 + ib;
    const u16* Wd = wbf + (size_t)dj*768*DM + (size_t)bn*128*DM;
    f32x4 acc[2][4] = {};
    for (int kt = 0; kt < 2; ++kt){
      // async staging: 16B global_load_lds per lane, linear dest + inverse-swz source
      stage_tile_async(Wd + kt*64, DM, Bs, w, l);
      __syncthreads();
      #pragma unroll
      for (int ks = 0; ks < 64; ks += 32){
        bf16x8 a[2], b[4];
        int cbb = (ks + (l >> 4)*8)*2;
        int kea = kt*64 + ks + (l >> 4)*8;
        #pragma unroll
        for (int i = 0; i < 2; ++i){
          int ra = wr*32 + i*16 + (l & 15);
          a[i] = *(bf16x8*)((char*)As + SWZ2(ra, kea*2));
        }
        #pragma unroll
        for (int i = 0; i < 4; ++i)
          b[i] = *(bf16x8*)((char*)Bs + SWZ(wc*64 + i*16 + (l & 15), cbb));
        #pragma unroll
        for (int i = 0; i < 2; ++i)
          #pragma unroll
          for (int jn = 0; jn < 4; ++jn)
            acc[i][jn] = __builtin_amdgcn_mfma_f32_16x16x32_bf16(a[i], b[jn], acc[i][jn], 0, 0, 0);
      }
      __syncthreads();
    }
    if (bn < 2){
      // z columns: stage 64x128 tile into Bs (linear), 16B coalesced writes
      #pragma unroll
      for (int i = 0; i < 2; ++i)
        #pragma unroll
        for (int jn = 0; jn < 4; ++jn)
          #pragma unroll
          for (int r = 0; r < 4; ++r){
            int m = wr*32 + i*16 + (l >> 4)*4 + r, n = wc*64 + jn*16 + (l & 15);
            Bs[m*128 + n] = f2b(acc[i][jn][r]);
          }
      __syncthreads();
      u16* dst = zbuf + ((size_t)dz*LSEQ + (size_t)mt*64)*DI + bn*128;
      #pragma unroll
      for (int it = 0; it < 4; ++it){
        int idx = it*256 + tid, r = idx >> 4, slot = idx & 15;
        uint4 v = *(uint4*)(Bs + r*128 + slot*8);
        *(uint4*)(dst + (size_t)r*DI + slot*8) = v;
      }
      __syncthreads();
    } else if (bn < 5){
      // xBC columns: stage raw tile, load conv weights, then fused conv+silu (rows>=3) + boundary store
      int xco0 = bn*128 - 256;
      #pragma unroll
      for (int i = 0; i < 2; ++i)
        #pragma unroll
        for (int jn = 0; jn < 4; ++jn)
          #pragma unroll
          for (int r = 0; r < 4; ++r){
            int m = wr*32 + i*16 + (l >> 4)*4 + r, n = wc*64 + jn*16 + (l & 15);
            Bs[m*128 + n] = f2b(acc[i][jn][r]);
          }
      if (tid < 128){
        const float* wp = conv_w + ((size_t)dj*CONVD + xco0 + tid)*4;
        cwsh[tid][0]=wp[0]; cwsh[tid][1]=wp[1]; cwsh[tid][2]=wp[2]; cwsh[tid][3]=wp[3];
        cbsh[tid] = conv_b[(size_t)dj*CONVD + xco0 + tid];
      }
      __syncthreads();
      u16* bt = bnd + ((size_t)(dz*NCHUNK + mt)*6)*CONVD + xco0;
      u16* xdst = xact + ((size_t)dz*LSEQ + (size_t)mt*64)*CONVD + xco0;
      #pragma unroll
      for (int it = 0; it < 4; ++it){
        int idx = it*256 + tid, r = idx >> 4, slot = idx & 15;
        int colbase = slot*8;
        if (r < 3){
          uint4 v = *(uint4*)(Bs + r*128 + colbase);
          *(uint4*)(bt + (size_t)r*CONVD + colbase) = v;
        } else {
          if (r >= 61){
            uint4 v = *(uint4*)(Bs + r*128 + colbase);
            *(uint4*)(bt + (size_t)(r-58)*CONVD + colbase) = v;
          }
          U8 tp[4];
          #pragma unroll
          for (int k = 0; k < 4; ++k)
            tp[k].v = *(uint4*)(Bs + (r-3+k)*128 + colbase);
          U8 o;
          #pragma unroll
          for (int k2 = 0; k2 < 8; ++k2){
            int c = colbase + k2;
            float v = b2f(tp[0].h[k2])*cwsh[c][0] + b2f(tp[1].h[k2])*cwsh[c][1]
                    + b2f(tp[2].h[k2])*cwsh[c][2] + b2f(tp[3].h[k2])*cwsh[c][3] + cbsh[c];
            o.h[k2] = f2b(silu_f(v));
          }
          *(uint4*)(xdst + (size_t)r*CONVD + colbase) = o.v;
        }
      }
      __syncthreads();
    } else {
      #pragma unroll
      for (int i = 0; i < 2; ++i)
        #pragma unroll
        for (int jn = 0; jn < 4; ++jn)
          #pragma unroll
          for (int r = 0; r < 4; ++r){
            int m = wr*32 + i*16 + (l >> 4)*4 + r, n = wc*64 + jn*16 + (l & 15);
            if (n < 4){
              float v = acc[i][jn][r] + dt_bias[dj*4 + n];
              dtb[((size_t)dz*LSEQ + (size_t)mt*64 + m)*4 + n] = softplus_f(v);
            }
          }
    }
  }
}

// ---------------- conv fixup: rows 0..2 of each 64-row tile from boundary buffer ----------------
__global__ __launch_bounds__(256) void k_convfix(const u16* __restrict__ bnd,
    const float* __restrict__ conv_w, const float* __restrict__ conv_b,
    u16* __restrict__ xact, int d_base, int j){
  int mt = blockIdx.x, dz = blockIdx.y, tid = threadIdx.x;
  int dj = (d_base+dz)*2 + j;
  if (tid >= 144) return;
  int r = tid / 48, cg = tid % 48;
  int col = cg*8;
  const u16* bcur  = bnd + ((size_t)(dz*NCHUNK + mt)*6)*CONVD;
  const u16* bprev = bnd + ((size_t)(dz*NCHUNK + mt - 1)*6)*CONVD;
  U8 tp[4];
  #pragma unroll
  for (int k = 0; k < 4; ++k){
    int grow = r - 3 + k;
    if (grow >= 0) tp[k].v = *(const uint4*)(bcur + (size_t)grow*CONVD + col);
    else if (mt > 0) tp[k].v = *(const uint4*)(bprev + (size_t)(6 + grow)*CONVD + col);
    else tp[k].v = make_uint4(0,0,0,0);
  }
  U8 o;
  #pragma unroll
  for (int k2 = 0; k2 < 8; ++k2){
    int c = col + k2;
    const float* wp = conv_w + ((size_t)dj*CONVD + c)*4;
    float v = b2f(tp[0].h[k2])*wp[0] + b2f(tp[1].h[k2])*wp[1]
            + b2f(tp[2].h[k2])*wp[2] + b2f(tp[3].h[k2])*wp[3] + conv_b[(size_t)dj*CONVD + c];
    o.h[k2] = f2b(silu_f(v));
  }
  *(uint4*)(xact + ((size_t)dz*LSEQ + (size_t)mt*64 + r)*CONVD + col) = o.v;
}

// ---------------- chunk kernel 1: dt-scan fused; two-stage transpose; G, Y1, S^T ----------------
__global__ __launch_bounds__(256) void k_chunk1(const u16* __restrict__ xact, const float* __restrict__ dtb,
    const float* __restrict__ A_log, const float* __restrict__ Dskip,
    u16* __restrict__ E, u16* __restrict__ y1, float* __restrict__ ltot, int d_base, int j){
  __shared__ __align__(16) u16 sB[4096], sC[4096], sM[4096], sXt[4096], sBw[4096];
  __shared__ float sLl[4][64], sdt[4][64];
  __shared__ float wexp[64];
  int c = blockIdx.x, dz = blockIdx.y, tid = threadIdx.x;
  int dj = (d_base+dz)*2 + j;
  int l = tid & 63, w = tid >> 6, wr = w >> 1, wc = w & 1;
  int mb = wr*32, nb = wc*32;
  int row0 = c*64;
  const u16* xa = xact + ((size_t)dz*LSEQ + row0)*CONVD;
  // per-wave dt scan: wave w = head w
  {
    float4 d4 = *(const float4*)(dtb + ((size_t)dz*LSEQ + row0 + l)*4);
    float dt = (w==0)?d4.x:((w==1)?d4.y:((w==2)?d4.z:d4.w));
    float A = -__expf(A_log[dj*4 + w]);
    float v = dt * A;
    #pragma unroll
    for (int o = 1; o < 64; o <<= 1){ float pv = __shfl_up(v, o); if (l >= o) v += pv; }
    sdt[w][l] = dt; sLl[w][l] = v;
    if (l == 63) ltot[((size_t)(dz*NCHUNK + c))*NH + w] = v;
  }
  // stage B (cols 256..319) and C (cols 320..383)
  #pragma unroll
  for (int it = 0; it < 2; ++it){
    int idx = it*256 + tid, t = idx >> 3, slot = idx & 7;
    uint4 vB = *(const uint4*)(xa + (size_t)t*CONVD + 256 + slot*8);
    uint4 vC = *(const uint4*)(xa + (size_t)t*CONVD + 320 + slot*8);
    *(uint4*)((char*)sB + SWZ(t, slot*16)) = vB;
    *(uint4*)((char*)sC + SWZ(t, slot*16)) = vC;
  }
  __syncthreads();
  // G[t][s] = sum_n C[t][n]*B[s][n]
  f32x4 g[2][2] = {};
  #pragma unroll
  for (int ks = 0; ks < 64; ks += 32){
    bf16x8 a[2], b[2];
    int cb = (ks + (l >> 4)*8)*2;
    #pragma unroll
    for (int i = 0; i < 2; ++i){
      a[i] = *(bf16x8*)((char*)sC + SWZ(mb + i*16 + (l & 15), cb));
      b[i] = *(bf16x8*)((char*)sB + SWZ(nb + i*16 + (l & 15), cb));
    }
    #pragma unroll
    for (int i = 0; i < 2; ++i)
      #pragma unroll
      for (int jn = 0; jn < 2; ++jn)
        g[i][jn] = __builtin_amdgcn_mfma_f32_16x16x32_bf16(a[i], b[jn], g[i][jn], 0, 0, 0);
  }
  for (int h = 0; h < NH; ++h){
    __syncthreads();
    if (tid < 64) wexp[tid] = __expf(sLl[h][63] - sLl[h][tid]) * sdt[h][tid];
    // stage X row-major into sC (vectorized)
    #pragma unroll
    for (int it = 0; it < 2; ++it){
      int idx = it*256 + tid, s = idx >> 3, slot = idx & 7;
      uint4 xv = *(const uint4*)(xa + (size_t)s*CONVD + h*64 + slot*8);
      *(uint4*)((char*)sC + SWZ(s, slot*16)) = xv;
    }
    // build M[t][s]
    #pragma unroll
    for (int i = 0; i < 2; ++i)
      #pragma unroll
      for (int jn = 0; jn < 2; ++jn)
        #pragma unroll
        for (int r = 0; r < 4; ++r){
          int t = mb + i*16 + (l >> 4)*4 + r;
          int s = nb + jn*16 + (l & 15);
          float v = (s <= t) ? g[i][jn][r]*__expf(sLl[h][t]-sLl[h][s])*sdt[h][s] : 0.f;
          *(u16*)((char*)sM + SWZ(t, s*2)) = f2b(v);
        }
    __syncthreads();
    // two-stage transpose: Xt[n][s] = X[s][n]; Bw[n][s] = B[s][n]*wexp[s]
    #pragma unroll
    for (int it = 0; it < 2; ++it){
      int idx = it*256 + tid, n = idx & 63, so = idx >> 6;
      U8 xo, bo;
      #pragma unroll
      for (int k = 0; k < 8; ++k){
        int s = so*8 + k;
        u16 xv = *(u16*)((char*)sC + SWZ(s, n*2));
        u16 bv = *(u16*)((char*)sB + SWZ(s, n*2));
        xo.h[k] = xv;
        bo.h[k] = f2b(b2f(bv) * wexp[s]);
      }
      *(uint4*)((char*)sXt + SWZ(n, so*16)) = xo.v;
      *(uint4*)((char*)sBw + SWZ(n, so*16)) = bo.v;
    }
    __syncthreads();
    // Y1 = M x Xt ; S^T = Xt x Bw
    f32x4 y1a[2][2] = {}, ssa[2][2] = {};
    #pragma unroll
    for (int ks = 0; ks < 64; ks += 32){
      int cb = (ks + (l >> 4)*8)*2;
      bf16x8 am[2], ax[2], bx[2], bw2[2];
      #pragma unroll
      for (int i = 0; i < 2; ++i){
        am[i]  = *(bf16x8*)((char*)sM  + SWZ(mb + i*16 + (l & 15), cb));
        ax[i]  = *(bf16x8*)((char*)sXt + SWZ(mb + i*16 + (l & 15), cb));
        bx[i]  = *(bf16x8*)((char*)sXt + SWZ(nb + i*16 + (l & 15), cb));
        bw2[i] = *(bf16x8*)((char*)sBw + SWZ(nb + i*16 + (l & 15), cb));
      }
      #pragma unroll
      for (int i = 0; i < 2; ++i)
        #pragma unroll
        for (int jn = 0; jn < 2; ++jn){
          y1a[i][jn] = __builtin_amdgcn_mfma_f32_16x16x32_bf16(am[i], bx[jn], y1a[i][jn], 0, 0, 0);
          ssa[i][jn] = __builtin_amdgcn_mfma_f32_16x16x32_bf16(ax[i], bw2[jn], ssa[i][jn], 0, 0, 0);
        }
    }
    __syncthreads();   // all waves done reading sM/sBw
    float dsk = Dskip[dj*NH + h];
    #pragma unroll
    for (int i = 0; i < 2; ++i)
      #pragma unroll
      for (int jn = 0; jn < 2; ++jn)
        #pragma unroll
        for (int r = 0; r < 4; ++r){
          int m = mb + i*16 + (l >> 4)*4 + r, n = nb + jn*16 + (l & 15);
          float xsv = b2f(*(u16*)((char*)sXt + SWZ(n, m*2)));
          *(u16*)((char*)sM  + SWZ(m, n*2)) = f2b(y1a[i][jn][r] + dsk * xsv);
          *(u16*)((char*)sBw + SWZ(m, n*2)) = f2b(ssa[i][jn][r]);
        }
    __syncthreads();
    u16* yr = y1 + ((size_t)dz*LSEQ + row0)*DI + h*64;
    u16* Ep = E + ((size_t)(dz*NCHUNK + c)*NH + h)*4096;
    #pragma unroll
    for (int it = 0; it < 2; ++it){
      int idx = it*256 + tid, r = idx >> 3, slot = idx & 7;
      uint4 vy = *(uint4*)((char*)sM  + SWZ(r, slot*16));
      uint4 ve = *(uint4*)((char*)sBw + SWZ(r, slot*16));
      *(uint4*)(yr + (size_t)r*DI + slot*8) = vy;
      *(uint4*)(Ep + r*64 + slot*8) = ve;
    }
  }
}

// ---------------- sequential carry over chunks, in-place on bf16 E, depth-16 prefetch ----------------
__global__ __launch_bounds__(256) void k_seq(u16* __restrict__ E, const float* __restrict__ ltot, int nd){
  int i = blockIdx.x*256 + threadIdx.x;
  if (i >= nd*16384) return;
  int dz = i >> 14, h = (i >> 12) & 3, np = i & 4095;
  const int stride = 16384;
  size_t base = (size_t)dz*NCHUNK*stride + (size_t)h*4096 + np;
  const float* lt = ltot + (size_t)dz*NCHUNK*NH + h;
  u16 eb[16]; float pb[16];
  #pragma unroll
  for (int q = 0; q < 16; ++q){ eb[q] = E[base + (size_t)q*stride]; pb[q] = lt[q*NH]; }
  float carry = 0.f;
  for (int cc = 0; cc < 256; cc += 16){
    u16 e2[16]; float p2[16];
    if (cc + 16 < 256){
      #pragma unroll
      for (int q = 0; q < 16; ++q){
        e2[q] = E[base + (size_t)(cc+16+q)*stride];
        p2[q] = lt[(cc+16+q)*NH];
      }
    }
    #pragma unroll
    for (int q = 0; q < 16; ++q){
      u16 cv = f2b(carry);
      carry = fmaf(__expf(pb[q]), carry, b2f(eb[q]));
      E[base + (size_t)(cc+q)*stride] = cv;
    }
    #pragma unroll
    for (int q = 0; q < 16; ++q){ eb[q] = e2[q]; pb[q] = p2[q]; }
  }
}

// ---------------- chunk kernel 2: Y2 MFMA; gate+RMS in LDS; fused out_proj (+residual/scatter) ----------------
__global__ __launch_bounds__(256) void k_chunk2(const u16* __restrict__ xact, const float* __restrict__ dtb,
    const float* __restrict__ A_log, const u16* __restrict__ zbuf, const u16* __restrict__ y1,
    const u16* __restrict__ E, const float* __restrict__ norm_w, const u16* __restrict__ wo,
    float* __restrict__ x, const float* __restrict__ vecs, const int* __restrict__ sidx,
    u16* __restrict__ multi, int d_base, int j){
  __shared__ __align__(16) u16 SH[24576];   // 48KB: sC(8K) sHt(8K) Ylds(32K); Bs reuses sC+sHt
  u16* sC   = SH;
  u16* sHt  = SH + 4096;
  u16* Ylds = SH + 8192;
  u16* Bs   = SH;             // phase C weight tile / scatter staging (16KB)
  __shared__ float sLl[4][64];
  __shared__ float nws[256];
  int c = blockIdx.x, dz = blockIdx.y, tid = threadIdx.x;
  int dj = (d_base+dz)*2 + j;
  int l = tid & 63, w = tid >> 6, wr = w >> 1, wc = w & 1;
  int mb = wr*32, nb = wc*32;
  int row0 = c*64;
  const u16* xa = xact + ((size_t)dz*LSEQ + row0)*CONVD;
  if (tid < 64) ((float4*)nws)[tid] = ((const float4*)(norm_w + (size_t)dj*DI))[tid];
  // dt scan
  {
    float4 d4 = *(const float4*)(dtb + ((size_t)dz*LSEQ + row0 + l)*4);
    float dt = (w==0)?d4.x:((w==1)?d4.y:((w==2)?d4.z:d4.w));
    float A = -__expf(A_log[dj*4 + w]);
    float v = dt * A;
    #pragma unroll
    for (int o = 1; o < 64; o <<= 1){ float pv = __shfl_up(v, o); if (l >= o) v += pv; }
    sLl[w][l] = v;
  }
  // stage C (cols 320..383)
  #pragma unroll
  for (int it = 0; it < 2; ++it){
    int idx = it*256 + tid, t = idx >> 3, slot = idx & 7;
    uint4 vC = *(const uint4*)(xa + (size_t)t*CONVD + 320 + slot*8);
    *(uint4*)((char*)sC + SWZ(t, slot*16)) = vC;
  }
  // phase A: per-head MFMA, scaled Y2 into Ylds
  for (int h = 0; h < NH; ++h){
    __syncthreads();
    const u16* Hp = E + ((size_t)(dz*NCHUNK + c)*NH + h)*4096;
    #pragma unroll
    for (int it = 0; it < 2; ++it){
      int idx = it*256 + tid, p = idx >> 3, ng = idx & 7;
      uint4 v = *(const uint4*)(Hp + (size_t)p*64 + ng*8);
      *(uint4*)((char*)sHt + SWZ(p, ng*16)) = v;
    }
    __syncthreads();
    f32x4 acc[2][2] = {};
    #pragma unroll
    for (int ks = 0; ks < 64; ks += 32){
      int cb = (ks + (l >> 4)*8)*2;
      bf16x8 a[2], b[2];
      #pragma unroll
      for (int i = 0; i < 2; ++i){
        a[i] = *(bf16x8*)((char*)sC  + SWZ(mb + i*16 + (l & 15), cb));
        b[i] = *(bf16x8*)((char*)sHt + SWZ(nb + i*16 + (l & 15), cb));
      }
      #pragma unroll
      for (int i = 0; i < 2; ++i)
        #pragma unroll
        for (int jn = 0; jn < 2; ++jn)
          acc[i][jn] = __builtin_amdgcn_mfma_f32_16x16x32_bf16(a[i], b[jn], acc[i][jn], 0, 0, 0);
    }
    #pragma unroll
    for (int i = 0; i < 2; ++i)
      #pragma unroll
      for (int jn = 0; jn < 2; ++jn)
        #pragma unroll
        for (int r = 0; r < 4; ++r){
          int m = mb + i*16 + (l >> 4)*4 + r, n = nb + jn*16 + (l & 15);
          float e = __expf(sLl[h][m]);
          *(u16*)((char*)Ylds + SWZ4(m, (h*64 + n)*2)) = f2b(e * acc[i][jn][r]);
        }
  }
  __syncthreads();
  // phase B: row-parallel gate + RMSNorm, in-place normalized yn into Ylds
  {
    int r = tid >> 2, q = tid & 3;
    size_t rowbase = ((size_t)dz*LSEQ + row0 + r)*DI + q*64;
    float ssq = 0.f;
    U8 gs[8];
    #pragma unroll
    for (int v = 0; v < 8; ++v){
      U8 y2u; y2u.v = *(uint4*)((char*)Ylds + SWZ4(r, (q*64 + v*8)*2));
      U8 y1u; y1u.v = *(const uint4*)(y1 + rowbase + v*8);
      U8 zu;  zu.v  = *(const uint4*)(zbuf + rowbase + v*8);
      #pragma unroll
      for (int k = 0; k < 8; ++k){
        float gv = (b2f(y1u.h[k]) + b2f(y2u.h[k])) * silu_f(b2f(zu.h[k]));
        ssq += gv*gv;
        gs[v].h[k] = f2b(gv);
      }
    }
    ssq += __shfl_xor(ssq, 1);
    ssq += __shfl_xor(ssq, 2);
    float rr = rsqrtf(ssq * (1.f/256.f) + 1e-5f);
    #pragma unroll
    for (int v = 0; v < 8; ++v){
      U8 o;
      #pragma unroll
      for (int k = 0; k < 8; ++k)
        o.h[k] = f2b(b2f(gs[v].h[k]) * rr * nws[q*64 + v*8 + k]);
      *(uint4*)((char*)Ylds + SWZ4(r, (q*64 + v*8)*2)) = o.v;
    }
  }
  __syncthreads();
  // phase C: out_proj GEMM  yn[64x256] @ wo[dj][128x256]^T
  const u16* Bg = wo + (size_t)dj*DM*DI;
  f32x4 acc2[2][4] = {};
  for (int kt = 0; kt < 4; ++kt){
    #pragma unroll
    for (int it = 0; it < 4; ++it){
      int idx = it*256 + tid, r = idx >> 3, slot = idx & 7;
      uint4 vb = *(const uint4*)(Bg + (size_t)r*DI + kt*64 + slot*8);
      *(uint4*)((char*)Bs + SWZ(r, slot*16)) = vb;
    }
    __syncthreads();
    #pragma unroll
    for (int ks = 0; ks < 64; ks += 32){
      bf16x8 a[2], b[4];
      int cb = (ks + (l >> 4)*8)*2;
      int kcol = kt*64 + ks + (l >> 4)*8;
      #pragma unroll
      for (int i = 0; i < 2; ++i)
        a[i] = *(bf16x8*)((char*)Ylds + SWZ4(wr*32 + i*16 + (l & 15), kcol*2));
      #pragma unroll
      for (int i = 0; i < 4; ++i)
        b[i] = *(bf16x8*)((char*)Bs + SWZ(wc*64 + i*16 + (l & 15), cb));
      #pragma unroll
      for (int i = 0; i < 2; ++i)
        #pragma unroll
        for (int jn = 0; jn < 4; ++jn)
          acc2[i][jn] = __builtin_amdgcn_mfma_f32_16x16x32_bf16(a[i], b[jn], acc2[i][jn], 0, 0, 0);
    }
    __syncthreads();
  }
  float* xr = x + ((size_t)dz*LSEQ + row0)*DM;
  if (j == 0){
    // residual base gathered directly from vectors (xbuf never pre-initialized)
    const int* ip = sidx + (size_t)(d_base+dz)*LSEQ + row0;
    #pragma unroll
    for (int i = 0; i < 2; ++i)
      #pragma unroll
      for (int r = 0; r < 4; ++r){
        int m = wr*32 + i*16 + (l >> 4)*4 + r;
        int src = ip[m];
        #pragma unroll
        for (int jn = 0; jn < 4; ++jn){
          int n = wc*64 + jn*16 + (l & 15);
          xr[(size_t)m*DM + n] = vecs[(size_t)src*DM + n] + acc2[i][jn][r];
        }
      }
  } else {
    // residual + convert -> Bs (64x128), then row-scatter into multi
    #pragma unroll
    for (int i = 0; i < 2; ++i)
      #pragma unroll
      for (int jn = 0; jn < 4; ++jn)
        #pragma unroll
        for (int r = 0; r < 4; ++r){
          int m = wr*32 + i*16 + (l >> 4)*4 + r, n = wc*64 + jn*16 + (l & 15);
          float res = xr[(size_t)m*DM + n] + acc2[i][jn][r];
          Bs[m*128 + n] = f2b(res);
        }
    __syncthreads();
    const int* ip = sidx + (size_t)(d_base+dz)*LSEQ + row0;
    #pragma unroll
    for (int it = 0; it < 4; ++it){
      int e = it*256 + tid, r = e >> 4, slot = e & 15;
      int orig = ip[r];
      uint4 v = *(uint4*)(Bs + r*128 + slot*8);
      *(uint4*)(multi + (size_t)orig*768 + (size_t)(d_base+dz)*128 + slot*8) = v;
    }
  }
}

// ---------------- fuse: fused LN(768) + GEMM + bias + exact gelu; N-split x2 ----------------
__global__ __launch_bounds__(256) void k_fuse(const u16* __restrict__ multi, const u16* __restrict__ wbf,
                                              const float* __restrict__ lnw, const float* __restrict__ lnb,
                                              const float* __restrict__ fb, float* __restrict__ out){
  __shared__ __align__(16) u16 As[64*64];    // 8KB
  __shared__ __align__(16) u16 Bs[64*64];    // 8KB
  __shared__ float swn[768], sbn[768], smu[64], sinv[64];
  int nh = blockIdx.x, mt = blockIdx.y, tid = threadIdx.x;
  int l = tid & 63, w = tid >> 6, wr = w >> 1, wc = w & 1;
  for (int e = tid; e < 192; e += 256){
    ((float4*)swn)[e] = ((const float4*)lnw)[e];
    ((float4*)sbn)[e] = ((const float4*)lnb)[e];
  }
  {
    int r = tid >> 2, q = tid & 3;
    const u16* row = multi + ((size_t)(mt*64 + r))*768 + q*192;
    float s = 0.f, ss = 0.f;
    #pragma unroll
    for (int v = 0; v < 24; ++v){
      U8 u; u.v = *(const uint4*)(row + v*8);
      #pragma unroll
      for (int k = 0; k < 8; ++k){ float f = b2f(u.h[k]); s += f; ss += f*f; }
    }
    s += __shfl_xor(s, 1); s += __shfl_xor(s, 2);
    ss += __shfl_xor(ss, 1); ss += __shfl_xor(ss, 2);
    if (q == 0){
      float mu = s * (1.f/768.f);
      smu[r] = mu;
      sinv[r] = rsqrtf(ss * (1.f/768.f) - mu*mu + 1e-5f);
    }
  }
  __syncthreads();
  const u16* Ag = multi + (size_t)mt*64*768;
  const u16* Wg = wbf + (size_t)nh*64*768;
  f32x4 acc[2][2] = {};
  for (int kt = 0; kt < 12; ++kt){
    #pragma unroll
    for (int it = 0; it < 2; ++it){
      int e = it*256 + tid, r = e >> 3, slot = e & 7;
      U8 u; u.v = *(const uint4*)(Ag + (size_t)r*768 + kt*64 + slot*8);
      float mu = smu[r], inv = sinv[r];
      U8 o;
      #pragma unroll
      for (int k = 0; k < 8; ++k){
        int col = kt*64 + slot*8 + k;
        o.h[k] = f2b((b2f(u.h[k]) - mu)*inv*swn[col] + sbn[col]);
      }
      *(uint4*)((char*)As + SWZ(r, slot*16)) = o.v;
    }
    #pragma unroll
    for (int it = 0; it < 2; ++it){
      int e = it*256 + tid, r = e >> 3, slot = e & 7;
      uint4 vb = *(const uint4*)(Wg + (size_t)r*768 + kt*64 + slot*8);
      *(uint4*)((char*)Bs + SWZ(r, slot*16)) = vb;
    }
    __syncthreads();
    #pragma unroll
    for (int ks = 0; ks < 64; ks += 32){
      bf16x8 a[2], b[2];
      int cb = (ks + (l >> 4)*8)*2;
      #pragma unroll
      for (int i = 0; i < 2; ++i)
        a[i] = *(bf16x8*)((char*)As + SWZ(wr*32 + i*16 + (l & 15), cb));
      #pragma unroll
      for (int i = 0; i < 2; ++i)
        b[i] = *(bf16x8*)((char*)Bs + SWZ(wc*32 + i*16 + (l & 15), cb));
      #pragma unroll
      for (int i = 0; i < 2; ++i)
        #pragma unroll
        for (int jn = 0; jn < 2; ++jn)
          acc[i][jn] = __builtin_amdgcn_mfma_f32_16x16x32_bf16(a[i], b[jn], acc[i][jn], 0, 0, 0);
    }
    __syncthreads();
  }
  #pragma unroll
  for (int i = 0; i < 2; ++i)
    #pragma unroll
    for (int jn = 0; jn < 2; ++jn)
      #pragma unroll
      for (int r = 0; r < 4; ++r){
        int m = wr*32 + i*16 + (l >> 4)*4 + r;
        int n = nh*64 + wc*32 + jn*16 + (l & 15);
        float v = acc[i][jn][r] + fb[n];
        float gl = 0.5f * v * (1.f + erff(v * 0.70710678118654752f));
        out[(size_t)(mt*64 + m)*DM + n] = gl;
      }
}

extern "C" void kernel_launch(void* const* d_in, const int* in_sizes, int n_in,
                              void* d_out, int out_size, void* d_ws, size_t ws_size,
                              hipStream_t stream){
  (void)in_sizes; (void)n_in; (void)out_size;
  const float* vectors  = (const float*)d_in[0];
  const int*   coords   = (const int*)d_in[1];
  const float* ln_w     = (const float*)d_in[2];
  const float* ln_b     = (const float*)d_in[3];
  const float* in_w     = (const float*)d_in[4];
  const float* conv_w   = (const float*)d_in[5];
  const float* conv_b   = (const float*)d_in[6];
  const float* dt_bias  = (const float*)d_in[7];
  const float* A_log    = (const float*)d_in[8];
  const float* D_skip   = (const float*)d_in[9];
  const float* norm_w   = (const float*)d_in[10];
  const float* out_w    = (const float*)d_in[11];
  const float* fuse_lw  = (const float*)d_in[12];
  const float* fuse_lb  = (const float*)d_in[13];
  const float* fuse_w   = (const float*)d_in[14];
  const float* fuse_b   = (const float*)d_in[15];
  float* out = (float*)d_out;

  char* p = (char*)d_ws;
  auto carve = [&](size_t bytes)->char*{
    char* r = p; p += (bytes + 255) & ~(size_t)255; return r;
  };
  int* idxb = (int*)carve((size_t)NDIR*LSEQ*4);
  unsigned long long* skey  = (unsigned long long*)carve((size_t)NDIR*LSEQ*8);
  unsigned long long* skey2 = (unsigned long long*)carve((size_t)NDIR*LSEQ*8);
  int* starts = (int*)carve((size_t)NDIR*1025*4);
  int* cursor = (int*)carve((size_t)NDIR*1024*4);
  u16* multi = (u16*)carve((size_t)LSEQ*768*2);
  u16* wbf_in   = (u16*)carve((size_t)NW0*2);
  u16* wbf_out  = (u16*)carve((size_t)NW1*2);
  u16* wbf_fuse = (u16*)carve((size_t)NW2*2);

  size_t fixed = (size_t)(p - (char*)d_ws);
  auto need = [&](int nd)->size_t{
    size_t s = 0; auto a = [&](size_t b){ s += (b + 255) & ~(size_t)255; };
    a((size_t)nd*LSEQ*DM*4);      // xbuf (f32 residual)
    a((size_t)nd*LSEQ*DI*2);      // zbuf (bf16)
    a((size_t)nd*LSEQ*CONVD*2);   // xact (bf16, conv'd)
    a((size_t)nd*NCHUNK*6*CONVD*2); // bnd (boundary rows)
    a((size_t)nd*LSEQ*NH*4);      // dtb (f32)
    a((size_t)nd*NCHUNK*NH*4);    // ltot (f32)
    a((size_t)nd*LSEQ*DI*2);      // y1 (bf16)
    a((size_t)nd*NCHUNK*NH*DSTATE*HD*2); // E (bf16, in-place scan)
    return s;
  };
  // adaptive batching: largest nd in {6,3,2,1} that fits the workspace
  int nd = 1;
  {
    const int cands[3] = {6, 3, 2};
    for (int ci = 0; ci < 3; ++ci){
      if (fixed + need(cands[ci]) <= ws_size){ nd = cands[ci]; break; }
    }
  }
  if (fixed + need(nd) > ws_size) return;  // insufficient workspace: no-op

  float* xbuf = (float*)carve((size_t)nd*LSEQ*DM*4);
  u16*   zbuf = (u16*)carve((size_t)nd*LSEQ*DI*2);
  u16*   xact = (u16*)carve((size_t)nd*LSEQ*CONVD*2);
  u16*   bnd  = (u16*)carve((size_t)nd*NCHUNK*6*CONVD*2);
  float* dtb  = (float*)carve((size_t)nd*LSEQ*NH*4);
  float* ltot = (float*)carve((size_t)nd*NCHUNK*NH*4);
  u16*   y1b  = (u16*)carve((size_t)nd*LSEQ*DI*2);
  u16*   Ebuf = (u16*)carve((size_t)nd*NCHUNK*NH*DSTATE*HD*2);

  k_cvt         <<<(NW0+NW1+NW2+255)/256, 256, 0, stream>>>(in_w, out_w, fuse_w, wbf_in, wbf_out, wbf_fuse, cursor);
  k_sort1       <<<(NDIR*LSEQ + 255)/256, 256, 0, stream>>>(coords, skey, cursor);
  k_sort_scan   <<<NDIR, 1024, 0, stream>>>(cursor, starts);
  k_sort_scatter<<<(NDIR*LSEQ + 255)/256, 256, 0, stream>>>(skey, skey2, cursor);
  k_sort_rank   <<<(NDIR*LSEQ + 255)/256, 256, 0, stream>>>(skey2, starts, idxb);

  for (int d_base = 0; d_base < NDIR; d_base += nd){
    for (int j = 0; j < 2; ++j){
      k_inproj<<<dim3(3, LSEQ/64, nd), 256, 0, stream>>>(xbuf, vectors, idxb, ln_w, ln_b, wbf_in, dt_bias,
                                                         conv_w, conv_b, zbuf, xact, bnd, dtb, d_base, j);
      k_convfix<<<dim3(NCHUNK, nd), 256, 0, stream>>>(bnd, conv_w, conv_b, xact, d_base, j);
      k_chunk1<<<dim3(NCHUNK, nd), 256, 0, stream>>>(xact, dtb, A_log, D_skip,
                                                     Ebuf, y1b, ltot, d_base, j);
      k_seq   <<<(nd*16384 + 255)/256, 256, 0, stream>>>(Ebuf, ltot, nd);
      k_chunk2<<<dim3(NCHUNK, nd), 256, 0, stream>>>(xact, dtb, A_log, zbuf, y1b, Ebuf,
                                                     norm_w, wbf_out, xbuf, vectors, idxb, multi, d_base, j);
    }
  }
  k_fuse <<<dim3(2, LSEQ/64), 256, 0, stream>>>(multi, wbf_fuse, fuse_lw, fuse_lb, fuse_b, out);
}

// Round 24
// 710.183 us; speedup vs baseline: 1.0563x; 1.0041x over previous
//
#include <hip/hip_runtime.h>
#include <math.h>

#define LSEQ   16384
#define DM     128
#define DI     256
#define DSTATE 64
#define NH     4
#define HD     64
#define CONVD  384
#define DPROJ  644
#define NDIR   6
#define NCHUNK 256      // LSEQ/64

typedef unsigned short u16;
typedef __attribute__((ext_vector_type(8))) __bf16 bf16x8;
typedef __attribute__((ext_vector_type(4))) float f32x4;

union U8 { uint4 v; u16 h[8]; };

__device__ __constant__ int ORD[6][3] = {{0,1,2},{0,2,1},{1,0,2},{1,2,0},{2,0,1},{2,1,0}};

__device__ __forceinline__ float softplus_f(float x){
  float ax = fabsf(x);
  return fmaxf(x, 0.f) + log1pf(__expf(-ax));
}
__device__ __forceinline__ float silu_f(float x){
  return x / (1.f + __expf(-x));
}
__device__ __forceinline__ u16 f2b(float f){
  unsigned u = __float_as_uint(f);
  unsigned r = (u + 0x7fffu + ((u >> 16) & 1u)) >> 16;
  return (u16)r;
}
__device__ __forceinline__ float b2f(u16 h){
  return __uint_as_float(((unsigned)h) << 16);
}
// XOR swizzle for [rows][128B] bf16 LDS tiles: conflict-free ds_read_b128 (T2)
__device__ __forceinline__ int SWZ(int r, int cb){
  return r*128 + (cb ^ ((r & 7) << 4));
}
// swizzle for 256B-row LDS tiles (inproj As)
__device__ __forceinline__ int SWZ2(int r, int cb){
  return r*256 + (cb ^ ((r & 7) << 4));
}
// swizzle for 512B-row LDS tiles (chunk2 Ylds)
__device__ __forceinline__ int SWZ4(int r, int cb){
  return r*512 + (cb ^ ((r & 7) << 4));
}

// async global->LDS staging of one 128x64-u16 tile into SWZ layout.
// LDS dest is LINEAR (wave-uniform base + lane*16); source column carries the
// inverse swizzle (XOR involution within each 128B row) so SWZ readers see
// the right bytes (rule #21: linear dest + inverse-swz source + swz read).
__device__ __forceinline__ void stage_tile_async(const u16* __restrict__ srcbase, size_t srcstride,
                                                 u16* lds, int w, int l){
  int cbl = (l & 7) * 16;                 // byte col within 128B LDS row
  int cbs = cbl ^ ((l >> 3) << 4);        // swizzled source byte col ((r&7)==(l>>3))
  #pragma unroll
  for (int it = 0; it < 4; ++it){
    int chunk = it*4 + w;                 // 0..15, wave-uniform
    int r = chunk*8 + (l >> 3);           // 0..127
    const u16* src = srcbase + (size_t)r*srcstride + (cbs >> 1);
    __builtin_amdgcn_global_load_lds(
        (const __attribute__((address_space(1))) void*)src,
        (__attribute__((address_space(3))) void*)((char*)lds + chunk*1024),
        16, 0, 0);
  }
}

// ---------------- weight convert to bf16 (+ cursor zeroing) ----------------
#define NW0 (12*768*128)
#define NW1 (12*128*256)
#define NW2 (128*768)
__global__ __launch_bounds__(256) void k_cvt(const float* __restrict__ in_w,
                                             const float* __restrict__ out_w,
                                             const float* __restrict__ fuse_w,
                                             u16* __restrict__ wi, u16* __restrict__ wo,
                                             u16* __restrict__ wf, int* __restrict__ cursor){
  int i = blockIdx.x*256 + threadIdx.x;
  if (i < NDIR*1024) cursor[i] = 0;
  if (i < NW0){
    int dj = i / (768*128), rem = i % (768*128), r = rem >> 7, c = rem & 127;
    float v = (r < DPROJ) ? in_w[((size_t)dj*DPROJ + r)*128 + c] : 0.f;
    wi[i] = f2b(v);
  } else if (i < NW0 + NW1){
    int k = i - NW0;
    wo[k] = f2b(out_w[k]);
  } else if (i < NW0 + NW1 + NW2){
    int k = i - NW0 - NW1;
    wf[k] = f2b(fuse_w[k]);
  }
}

// ---------------- sort ----------------
__global__ __launch_bounds__(256) void k_sort1(const int* __restrict__ coords,
                                               unsigned long long* __restrict__ skey,
                                               int* __restrict__ cursor){
  int i = blockIdx.x*256 + threadIdx.x;
  if (i >= NDIR*LSEQ) return;
  int d = i >> 14, t = i & 16383;
  unsigned k = ((unsigned)coords[t*4 + ORD[d][0]] << 20)
             | ((unsigned)coords[t*4 + ORD[d][1]] << 10)
             |  (unsigned)coords[t*4 + ORD[d][2]];
  skey[i] = ((unsigned long long)k << 14) | (unsigned long long)t;
  atomicAdd(&cursor[(d << 10) + (k >> 20)], 1);
}

__global__ void k_sort_scan(int* __restrict__ cursor, int* __restrict__ starts){
  __shared__ int sh[1024];
  int d = blockIdx.x, t = threadIdx.x;
  int v = cursor[d*1024 + t];
  sh[t] = v; __syncthreads();
  for (int off = 1; off < 1024; off <<= 1){
    int a = (t >= off) ? sh[t-off] : 0;
    __syncthreads();
    sh[t] += a;
    __syncthreads();
  }
  int incl = sh[t], excl = incl - v;
  starts[d*1025 + t] = excl;
  cursor[d*1024 + t] = excl;
  if (t == 1023) starts[d*1025 + 1024] = incl;
}

__global__ __launch_bounds__(256) void k_sort_scatter(const unsigned long long* __restrict__ skey,
                                                      unsigned long long* __restrict__ skey2,
                                                      int* __restrict__ cursor){
  int i = blockIdx.x*256 + threadIdx.x;
  if (i >= NDIR*LSEQ) return;
  int d = i >> 14;
  unsigned long long v = skey[i];
  int b = (int)(v >> 34);
  int pos = atomicAdd(&cursor[(d << 10) + b], 1);
  skey2[(size_t)d*LSEQ + pos] = v;
}

__global__ __launch_bounds__(256) void k_sort_rank(const unsigned long long* __restrict__ skey2,
                                                   const int* __restrict__ starts,
                                                   int* __restrict__ idx){
  int i = blockIdx.x*256 + threadIdx.x;
  if (i >= NDIR*LSEQ) return;
  int d = i >> 14;
  unsigned long long v = skey2[i];
  int b = (int)(v >> 34);
  int s = starts[d*1025 + b], e = starts[d*1025 + b + 1];
  int r = s;
  for (int q = s; q < e; ++q) r += (skey2[(size_t)d*LSEQ + q] < v);
  int orig = (int)(v & 16383ULL);
  idx[(size_t)d*LSEQ + r] = orig;
}

// ---------------- in_proj: 64-row tiles; fused LN; double-buffered pipelined weight staging ----------------
__global__ __launch_bounds__(256) void k_inproj(const float* __restrict__ xres,
    const float* __restrict__ vecs, const int* __restrict__ sidx,
    const float* __restrict__ lnw, const float* __restrict__ lnb,
    const u16* __restrict__ wbf, const float* __restrict__ dt_bias,
    const float* __restrict__ conv_w, const float* __restrict__ conv_b,
    u16* __restrict__ zbuf, u16* __restrict__ xact, u16* __restrict__ bnd,
    float* __restrict__ dtb, int d_base, int j){
  __shared__ __align__(16) u16 As[64*128];      // 16KB (row stride 256B, swizzled)
  __shared__ __align__(16) u16 Bsb[2][128*64];  // 32KB double-buffered weights / epilogue scratch
  __shared__ float cwsh[128][4];
  __shared__ float cbsh[128];
  int bpair = blockIdx.x, mt = blockIdx.y, dz = blockIdx.z, tid = threadIdx.x;
  int dj = (d_base+dz)*2 + j;
  int l = tid & 63, w = tid >> 6, wr = w >> 1, wc = w & 1;
  const u16* W0 = wbf + (size_t)dj*768*DM + (size_t)(bpair*2)*128*DM;
  const u16* W1 = W0 + (size_t)128*DM;
  // issue phase-0 staging (bn0, kt=0) before LN: latency hides under LN compute
  stage_tile_async(W0, DM, Bsb[0], w, l);
  // ---- parallel LN: 2 threads per row (r15 summation order); j==0 gathers rows from vectors ----
  if (tid < 128){
    int r = tid >> 1, half = tid & 1;
    const float4* xr;
    if (j == 0){
      int src = sidx[(size_t)(d_base+dz)*LSEQ + (size_t)mt*64 + r];
      xr = (const float4*)(vecs + (size_t)src*DM) + half*16;
    } else {
      xr = (const float4*)(xres + ((size_t)dz*LSEQ + (size_t)mt*64 + r)*DM) + half*16;
    }
    float4 v[16];
    #pragma unroll
    for (int q = 0; q < 16; ++q) v[q] = xr[q];
    float s = 0.f, ss2 = 0.f;
    #pragma unroll
    for (int q = 0; q < 16; ++q){
      s   += v[q].x + v[q].y + v[q].z + v[q].w;
      ss2 += v[q].x*v[q].x + v[q].y*v[q].y + v[q].z*v[q].z + v[q].w*v[q].w;
    }
    s += __shfl_xor(s, 1); ss2 += __shfl_xor(ss2, 1);
    float mu = s*(1.f/128.f);
    float var = ss2*(1.f/128.f) - mu*mu;
    float inv = rsqrtf(var + 1e-5f);
    const float4* w4 = (const float4*)(lnw + (size_t)dj*DM) + half*16;
    const float4* b4 = (const float4*)(lnb + (size_t)dj*DM) + half*16;
    #pragma unroll
    for (int g = 0; g < 8; ++g){
      float4 a = v[2*g], b = v[2*g+1];
      float4 wa = w4[2*g], wb = w4[2*g+1];
      float4 ba = b4[2*g], bb = b4[2*g+1];
      U8 pk;
      pk.h[0] = f2b((a.x-mu)*inv*wa.x + ba.x);
      pk.h[1] = f2b((a.y-mu)*inv*wa.y + ba.y);
      pk.h[2] = f2b((a.z-mu)*inv*wa.z + ba.z);
      pk.h[3] = f2b((a.w-mu)*inv*wa.w + ba.w);
      pk.h[4] = f2b((b.x-mu)*inv*wb.x + bb.x);
      pk.h[5] = f2b((b.y-mu)*inv*wb.y + bb.y);
      pk.h[6] = f2b((b.z-mu)*inv*wb.z + bb.z);
      pk.h[7] = f2b((b.w-mu)*inv*wb.w + bb.w);
      int c0 = half*64 + g*8;
      *(uint4*)((char*)As + SWZ2(r, c0*2)) = pk.v;
    }
  }
  __syncthreads();   // LN writes visible; phase-0 staging drained
  // ---- 4 pipelined MFMA phases (prefetch next tile into other buffer before compute) ----
  f32x4 accA[2][4] = {}, accB[2][4] = {};
  auto mfma_phase = [&](u16* bs, int kt, f32x4 (&acc)[2][4]){
    #pragma unroll
    for (int ks = 0; ks < 64; ks += 32){
      bf16x8 a[2], b[4];
      int cbb = (ks + (l >> 4)*8)*2;
      int kea = kt*64 + ks + (l >> 4)*8;
      #pragma unroll
      for (int i = 0; i < 2; ++i){
        int ra = wr*32 + i*16 + (l & 15);
        a[i] = *(bf16x8*)((char*)As + SWZ2(ra, kea*2));
      }
      #pragma unroll
      for (int i = 0; i < 4; ++i)
        b[i] = *(bf16x8*)((char*)bs + SWZ(wc*64 + i*16 + (l & 15), cbb));
      #pragma unroll
      for (int i = 0; i < 2; ++i)
        #pragma unroll
        for (int jn = 0; jn < 4; ++jn)
          acc[i][jn] = __builtin_amdgcn_mfma_f32_16x16x32_bf16(a[i], b[jn], acc[i][jn], 0, 0, 0);
    }
  };
  // phase 0: compute (bn0,kt0) from Bsb[0]; prefetch (bn0,kt1) -> Bsb[1]
  stage_tile_async(W0 + 64, DM, Bsb[1], w, l);
  mfma_phase(Bsb[0], 0, accA);
  __syncthreads();
  // phase 1: compute (bn0,kt1) from Bsb[1]; prefetch (bn1,kt0) -> Bsb[0]
  stage_tile_async(W1, DM, Bsb[0], w, l);
  mfma_phase(Bsb[1], 1, accA);
  __syncthreads();
  // phase 2: compute (bn1,kt0) from Bsb[0]; prefetch (bn1,kt1) -> Bsb[1]
  stage_tile_async(W1 + 64, DM, Bsb[1], w, l);
  mfma_phase(Bsb[0], 0, accB);
  __syncthreads();
  // phase 3: compute (bn1,kt1) from Bsb[1]
  mfma_phase(Bsb[1], 1, accB);
  __syncthreads();
  // ---- epilogues (scratch = Bsb[0]) ----
  u16* Bs = Bsb[0];
  #pragma unroll
  for (int ib = 0; ib < 2; ++ib){
    int bn = bpair*2 + ib;
    f32x4 (&acc)[2][4] = ib ? accB : accA;
    if (bn < 2){
      // z columns: stage 64x128 tile into Bs (linear), 16B coalesced writes
      #pragma unroll
      for (int i = 0; i < 2; ++i)
        #pragma unroll
        for (int jn = 0; jn < 4; ++jn)
          #pragma unroll
          for (int r = 0; r < 4; ++r){
            int m = wr*32 + i*16 + (l >> 4)*4 + r, n = wc*64 + jn*16 + (l & 15);
            Bs[m*128 + n] = f2b(acc[i][jn][r]);
          }
      __syncthreads();
      u16* dst = zbuf + ((size_t)dz*LSEQ + (size_t)mt*64)*DI + bn*128;
      #pragma unroll
      for (int it = 0; it < 4; ++it){
        int idx = it*256 + tid, r = idx >> 4, slot = idx & 15;
        uint4 v = *(uint4*)(Bs + r*128 + slot*8);
        *(uint4*)(dst + (size_t)r*DI + slot*8) = v;
      }
      __syncthreads();
    } else if (bn < 5){
      // xBC columns: stage raw tile, load conv weights, then fused conv+silu (rows>=3) + boundary store
      int xco0 = bn*128 - 256;
      #pragma unroll
      for (int i = 0; i < 2; ++i)
        #pragma unroll
        for (int jn = 0; jn < 4; ++jn)
          #pragma unroll
          for (int r = 0; r < 4; ++r){
            int m = wr*32 + i*16 + (l >> 4)*4 + r, n = wc*64 + jn*16 + (l & 15);
            Bs[m*128 + n] = f2b(acc[i][jn][r]);
          }
      if (tid < 128){
        const float* wp = conv_w + ((size_t)dj*CONVD + xco0 + tid)*4;
        cwsh[tid][0]=wp[0]; cwsh[tid][1]=wp[1]; cwsh[tid][2]=wp[2]; cwsh[tid][3]=wp[3];
        cbsh[tid] = conv_b[(size_t)dj*CONVD + xco0 + tid];
      }
      __syncthreads();
      u16* bt = bnd + ((size_t)(dz*NCHUNK + mt)*6)*CONVD + xco0;
      u16* xdst = xact + ((size_t)dz*LSEQ + (size_t)mt*64)*CONVD + xco0;
      #pragma unroll
      for (int it = 0; it < 4; ++it){
        int idx = it*256 + tid, r = idx >> 4, slot = idx & 15;
        int colbase = slot*8;
        if (r < 3){
          uint4 v = *(uint4*)(Bs + r*128 + colbase);
          *(uint4*)(bt + (size_t)r*CONVD + colbase) = v;
        } else {
          if (r >= 61){
            uint4 v = *(uint4*)(Bs + r*128 + colbase);
            *(uint4*)(bt + (size_t)(r-58)*CONVD + colbase) = v;
          }
          U8 tp[4];
          #pragma unroll
          for (int k = 0; k < 4; ++k)
            tp[k].v = *(uint4*)(Bs + (r-3+k)*128 + colbase);
          U8 o;
          #pragma unroll
          for (int k2 = 0; k2 < 8; ++k2){
            int c = colbase + k2;
            float v = b2f(tp[0].h[k2])*cwsh[c][0] + b2f(tp[1].h[k2])*cwsh[c][1]
                    + b2f(tp[2].h[k2])*cwsh[c][2] + b2f(tp[3].h[k2])*cwsh[c][3] + cbsh[c];
            o.h[k2] = f2b(silu_f(v));
          }
          *(uint4*)(xdst + (size_t)r*CONVD + colbase) = o.v;
        }
      }
      __syncthreads();
    } else {
      #pragma unroll
      for (int i = 0; i < 2; ++i)
        #pragma unroll
        for (int jn = 0; jn < 4; ++jn)
          #pragma unroll
          for (int r = 0; r < 4; ++r){
            int m = wr*32 + i*16 + (l >> 4)*4 + r, n = wc*64 + jn*16 + (l & 15);
            if (n < 4){
              float v = acc[i][jn][r] + dt_bias[dj*4 + n];
              dtb[((size_t)dz*LSEQ + (size_t)mt*64 + m)*4 + n] = softplus_f(v);
            }
          }
    }
  }
}

// ---------------- conv fixup: rows 0..2 of each 64-row tile from boundary buffer ----------------
__global__ __launch_bounds__(256) void k_convfix(const u16* __restrict__ bnd,
    const float* __restrict__ conv_w, const float* __restrict__ conv_b,
    u16* __restrict__ xact, int d_base, int j){
  int mt = blockIdx.x, dz = blockIdx.y, tid = threadIdx.x;
  int dj = (d_base+dz)*2 + j;
  if (tid >= 144) return;
  int r = tid / 48, cg = tid % 48;
  int col = cg*8;
  const u16* bcur  = bnd + ((size_t)(dz*NCHUNK + mt)*6)*CONVD;
  const u16* bprev = bnd + ((size_t)(dz*NCHUNK + mt - 1)*6)*CONVD;
  U8 tp[4];
  #pragma unroll
  for (int k = 0; k < 4; ++k){
    int grow = r - 3 + k;
    if (grow >= 0) tp[k].v = *(const uint4*)(bcur + (size_t)grow*CONVD + col);
    else if (mt > 0) tp[k].v = *(const uint4*)(bprev + (size_t)(6 + grow)*CONVD + col);
    else tp[k].v = make_uint4(0,0,0,0);
  }
  U8 o;
  #pragma unroll
  for (int k2 = 0; k2 < 8; ++k2){
    int c = col + k2;
    const float* wp = conv_w + ((size_t)dj*CONVD + c)*4;
    float v = b2f(tp[0].h[k2])*wp[0] + b2f(tp[1].h[k2])*wp[1]
            + b2f(tp[2].h[k2])*wp[2] + b2f(tp[3].h[k2])*wp[3] + conv_b[(size_t)dj*CONVD + c];
    o.h[k2] = f2b(silu_f(v));
  }
  *(uint4*)(xact + ((size_t)dz*LSEQ + (size_t)mt*64 + r)*CONVD + col) = o.v;
}

// ---------------- chunk kernel 1: dt-scan fused; two-stage transpose; G, Y1, S^T ----------------
__global__ __launch_bounds__(256) void k_chunk1(const u16* __restrict__ xact, const float* __restrict__ dtb,
    const float* __restrict__ A_log, const float* __restrict__ Dskip,
    u16* __restrict__ E, u16* __restrict__ y1, float* __restrict__ ltot, int d_base, int j){
  __shared__ __align__(16) u16 sB[4096], sC[4096], sM[4096], sXt[4096], sBw[4096];
  __shared__ float sLl[4][64], sdt[4][64];
  __shared__ float wexp[64];
  int c = blockIdx.x, dz = blockIdx.y, tid = threadIdx.x;
  int dj = (d_base+dz)*2 + j;
  int l = tid & 63, w = tid >> 6, wr = w >> 1, wc = w & 1;
  int mb = wr*32, nb = wc*32;
  int row0 = c*64;
  const u16* xa = xact + ((size_t)dz*LSEQ + row0)*CONVD;
  // per-wave dt scan: wave w = head w
  {
    float4 d4 = *(const float4*)(dtb + ((size_t)dz*LSEQ + row0 + l)*4);
    float dt = (w==0)?d4.x:((w==1)?d4.y:((w==2)?d4.z:d4.w));
    float A = -__expf(A_log[dj*4 + w]);
    float v = dt * A;
    #pragma unroll
    for (int o = 1; o < 64; o <<= 1){ float pv = __shfl_up(v, o); if (l >= o) v += pv; }
    sdt[w][l] = dt; sLl[w][l] = v;
    if (l == 63) ltot[((size_t)(dz*NCHUNK + c))*NH + w] = v;
  }
  // stage B (cols 256..319) and C (cols 320..383)
  #pragma unroll
  for (int it = 0; it < 2; ++it){
    int idx = it*256 + tid, t = idx >> 3, slot = idx & 7;
    uint4 vB = *(const uint4*)(xa + (size_t)t*CONVD + 256 + slot*8);
    uint4 vC = *(const uint4*)(xa + (size_t)t*CONVD + 320 + slot*8);
    *(uint4*)((char*)sB + SWZ(t, slot*16)) = vB;
    *(uint4*)((char*)sC + SWZ(t, slot*16)) = vC;
  }
  __syncthreads();
  // G[t][s] = sum_n C[t][n]*B[s][n]
  f32x4 g[2][2] = {};
  #pragma unroll
  for (int ks = 0; ks < 64; ks += 32){
    bf16x8 a[2], b[2];
    int cb = (ks + (l >> 4)*8)*2;
    #pragma unroll
    for (int i = 0; i < 2; ++i){
      a[i] = *(bf16x8*)((char*)sC + SWZ(mb + i*16 + (l & 15), cb));
      b[i] = *(bf16x8*)((char*)sB + SWZ(nb + i*16 + (l & 15), cb));
    }
    #pragma unroll
    for (int i = 0; i < 2; ++i)
      #pragma unroll
      for (int jn = 0; jn < 2; ++jn)
        g[i][jn] = __builtin_amdgcn_mfma_f32_16x16x32_bf16(a[i], b[jn], g[i][jn], 0, 0, 0);
  }
  for (int h = 0; h < NH; ++h){
    __syncthreads();
    if (tid < 64) wexp[tid] = __expf(sLl[h][63] - sLl[h][tid]) * sdt[h][tid];
    // stage X row-major into sC (vectorized)
    #pragma unroll
    for (int it = 0; it < 2; ++it){
      int idx = it*256 + tid, s = idx >> 3, slot = idx & 7;
      uint4 xv = *(const uint4*)(xa + (size_t)s*CONVD + h*64 + slot*8);
      *(uint4*)((char*)sC + SWZ(s, slot*16)) = xv;
    }
    // build M[t][s]
    #pragma unroll
    for (int i = 0; i < 2; ++i)
      #pragma unroll
      for (int jn = 0; jn < 2; ++jn)
        #pragma unroll
        for (int r = 0; r < 4; ++r){
          int t = mb + i*16 + (l >> 4)*4 + r;
          int s = nb + jn*16 + (l & 15);
          float v = (s <= t) ? g[i][jn][r]*__expf(sLl[h][t]-sLl[h][s])*sdt[h][s] : 0.f;
          *(u16*)((char*)sM + SWZ(t, s*2)) = f2b(v);
        }
    __syncthreads();
    // two-stage transpose: Xt[n][s] = X[s][n]; Bw[n][s] = B[s][n]*wexp[s]
    #pragma unroll
    for (int it = 0; it < 2; ++it){
      int idx = it*256 + tid, n = idx & 63, so = idx >> 6;
      U8 xo, bo;
      #pragma unroll
      for (int k = 0; k < 8; ++k){
        int s = so*8 + k;
        u16 xv = *(u16*)((char*)sC + SWZ(s, n*2));
        u16 bv = *(u16*)((char*)sB + SWZ(s, n*2));
        xo.h[k] = xv;
        bo.h[k] = f2b(b2f(bv) * wexp[s]);
      }
      *(uint4*)((char*)sXt + SWZ(n, so*16)) = xo.v;
      *(uint4*)((char*)sBw + SWZ(n, so*16)) = bo.v;
    }
    __syncthreads();
    // Y1 = M x Xt ; S^T = Xt x Bw
    f32x4 y1a[2][2] = {}, ssa[2][2] = {};
    #pragma unroll
    for (int ks = 0; ks < 64; ks += 32){
      int cb = (ks + (l >> 4)*8)*2;
      bf16x8 am[2], ax[2], bx[2], bw2[2];
      #pragma unroll
      for (int i = 0; i < 2; ++i){
        am[i]  = *(bf16x8*)((char*)sM  + SWZ(mb + i*16 + (l & 15), cb));
        ax[i]  = *(bf16x8*)((char*)sXt + SWZ(mb + i*16 + (l & 15), cb));
        bx[i]  = *(bf16x8*)((char*)sXt + SWZ(nb + i*16 + (l & 15), cb));
        bw2[i] = *(bf16x8*)((char*)sBw + SWZ(nb + i*16 + (l & 15), cb));
      }
      #pragma unroll
      for (int i = 0; i < 2; ++i)
        #pragma unroll
        for (int jn = 0; jn < 2; ++jn){
          y1a[i][jn] = __builtin_amdgcn_mfma_f32_16x16x32_bf16(am[i], bx[jn], y1a[i][jn], 0, 0, 0);
          ssa[i][jn] = __builtin_amdgcn_mfma_f32_16x16x32_bf16(ax[i], bw2[jn], ssa[i][jn], 0, 0, 0);
        }
    }
    __syncthreads();   // all waves done reading sM/sBw
    float dsk = Dskip[dj*NH + h];
    #pragma unroll
    for (int i = 0; i < 2; ++i)
      #pragma unroll
      for (int jn = 0; jn < 2; ++jn)
        #pragma unroll
        for (int r = 0; r < 4; ++r){
          int m = mb + i*16 + (l >> 4)*4 + r, n = nb + jn*16 + (l & 15);
          float xsv = b2f(*(u16*)((char*)sXt + SWZ(n, m*2)));
          *(u16*)((char*)sM  + SWZ(m, n*2)) = f2b(y1a[i][jn][r] + dsk * xsv);
          *(u16*)((char*)sBw + SWZ(m, n*2)) = f2b(ssa[i][jn][r]);
        }
    __syncthreads();
    u16* yr = y1 + ((size_t)dz*LSEQ + row0)*DI + h*64;
    u16* Ep = E + ((size_t)(dz*NCHUNK + c)*NH + h)*4096;
    #pragma unroll
    for (int it = 0; it < 2; ++it){
      int idx = it*256 + tid, r = idx >> 3, slot = idx & 7;
      uint4 vy = *(uint4*)((char*)sM  + SWZ(r, slot*16));
      uint4 ve = *(uint4*)((char*)sBw + SWZ(r, slot*16));
      *(uint4*)(yr + (size_t)r*DI + slot*8) = vy;
      *(uint4*)(Ep + r*64 + slot*8) = ve;
    }
  }
}

// ---------------- sequential carry over chunks, in-place on bf16 E, depth-16 prefetch ----------------
__global__ __launch_bounds__(256) void k_seq(u16* __restrict__ E, const float* __restrict__ ltot, int nd){
  int i = blockIdx.x*256 + threadIdx.x;
  if (i >= nd*16384) return;
  int dz = i >> 14, h = (i >> 12) & 3, np = i & 4095;
  const int stride = 16384;
  size_t base = (size_t)dz*NCHUNK*stride + (size_t)h*4096 + np;
  const float* lt = ltot + (size_t)dz*NCHUNK*NH + h;
  u16 eb[16]; float pb[16];
  #pragma unroll
  for (int q = 0; q < 16; ++q){ eb[q] = E[base + (size_t)q*stride]; pb[q] = lt[q*NH]; }
  float carry = 0.f;
  for (int cc = 0; cc < 256; cc += 16){
    u16 e2[16]; float p2[16];
    if (cc + 16 < 256){
      #pragma unroll
      for (int q = 0; q < 16; ++q){
        e2[q] = E[base + (size_t)(cc+16+q)*stride];
        p2[q] = lt[(cc+16+q)*NH];
      }
    }
    #pragma unroll
    for (int q = 0; q < 16; ++q){
      u16 cv = f2b(carry);
      carry = fmaf(__expf(pb[q]), carry, b2f(eb[q]));
      E[base + (size_t)(cc+q)*stride] = cv;
    }
    #pragma unroll
    for (int q = 0; q < 16; ++q){ eb[q] = e2[q]; pb[q] = p2[q]; }
  }
}

// ---------------- chunk kernel 2: Y2 MFMA; gate+RMS in LDS; fused out_proj (+residual/scatter) ----------------
__global__ __launch_bounds__(256) void k_chunk2(const u16* __restrict__ xact, const float* __restrict__ dtb,
    const float* __restrict__ A_log, const u16* __restrict__ zbuf, const u16* __restrict__ y1,
    const u16* __restrict__ E, const float* __restrict__ norm_w, const u16* __restrict__ wo,
    float* __restrict__ x, const float* __restrict__ vecs, const int* __restrict__ sidx,
    u16* __restrict__ multi, int d_base, int j){
  __shared__ __align__(16) u16 SH[24576];   // 48KB: sC(8K) sHt(8K) Ylds(32K); Bs reuses sC+sHt
  u16* sC   = SH;
  u16* sHt  = SH + 4096;
  u16* Ylds = SH + 8192;
  u16* Bs   = SH;             // phase C weight tile / scatter staging (16KB)
  __shared__ float sLl[4][64];
  __shared__ float nws[256];
  int c = blockIdx.x, dz = blockIdx.y, tid = threadIdx.x;
  int dj = (d_base+dz)*2 + j;
  int l = tid & 63, w = tid >> 6, wr = w >> 1, wc = w & 1;
  int mb = wr*32, nb = wc*32;
  int row0 = c*64;
  const u16* xa = xact + ((size_t)dz*LSEQ + row0)*CONVD;
  if (tid < 64) ((float4*)nws)[tid] = ((const float4*)(norm_w + (size_t)dj*DI))[tid];
  // dt scan
  {
    float4 d4 = *(const float4*)(dtb + ((size_t)dz*LSEQ + row0 + l)*4);
    float dt = (w==0)?d4.x:((w==1)?d4.y:((w==2)?d4.z:d4.w));
    float A = -__expf(A_log[dj*4 + w]);
    float v = dt * A;
    #pragma unroll
    for (int o = 1; o < 64; o <<= 1){ float pv = __shfl_up(v, o); if (l >= o) v += pv; }
    sLl[w][l] = v;
  }
  // stage C (cols 320..383)
  #pragma unroll
  for (int it = 0; it < 2; ++it){
    int idx = it*256 + tid, t = idx >> 3, slot = idx & 7;
    uint4 vC = *(const uint4*)(xa + (size_t)t*CONVD + 320 + slot*8);
    *(uint4*)((char*)sC + SWZ(t, slot*16)) = vC;
  }
  // phase A: per-head MFMA, scaled Y2 into Ylds
  for (int h = 0; h < NH; ++h){
    __syncthreads();
    const u16* Hp = E + ((size_t)(dz*NCHUNK + c)*NH + h)*4096;
    #pragma unroll
    for (int it = 0; it < 2; ++it){
      int idx = it*256 + tid, p = idx >> 3, ng = idx & 7;
      uint4 v = *(const uint4*)(Hp + (size_t)p*64 + ng*8);
      *(uint4*)((char*)sHt + SWZ(p, ng*16)) = v;
    }
    __syncthreads();
    f32x4 acc[2][2] = {};
    #pragma unroll
    for (int ks = 0; ks < 64; ks += 32){
      int cb = (ks + (l >> 4)*8)*2;
      bf16x8 a[2], b[2];
      #pragma unroll
      for (int i = 0; i < 2; ++i){
        a[i] = *(bf16x8*)((char*)sC  + SWZ(mb + i*16 + (l & 15), cb));
        b[i] = *(bf16x8*)((char*)sHt + SWZ(nb + i*16 + (l & 15), cb));
      }
      #pragma unroll
      for (int i = 0; i < 2; ++i)
        #pragma unroll
        for (int jn = 0; jn < 2; ++jn)
          acc[i][jn] = __builtin_amdgcn_mfma_f32_16x16x32_bf16(a[i], b[jn], acc[i][jn], 0, 0, 0);
    }
    #pragma unroll
    for (int i = 0; i < 2; ++i)
      #pragma unroll
      for (int jn = 0; jn < 2; ++jn)
        #pragma unroll
        for (int r = 0; r < 4; ++r){
          int m = mb + i*16 + (l >> 4)*4 + r, n = nb + jn*16 + (l & 15);
          float e = __expf(sLl[h][m]);
          *(u16*)((char*)Ylds + SWZ4(m, (h*64 + n)*2)) = f2b(e * acc[i][jn][r]);
        }
  }
  __syncthreads();
  // phase B: row-parallel gate + RMSNorm, in-place normalized yn into Ylds
  {
    int r = tid >> 2, q = tid & 3;
    size_t rowbase = ((size_t)dz*LSEQ + row0 + r)*DI + q*64;
    float ssq = 0.f;
    U8 gs[8];
    #pragma unroll
    for (int v = 0; v < 8; ++v){
      U8 y2u; y2u.v = *(uint4*)((char*)Ylds + SWZ4(r, (q*64 + v*8)*2));
      U8 y1u; y1u.v = *(const uint4*)(y1 + rowbase + v*8);
      U8 zu;  zu.v  = *(const uint4*)(zbuf + rowbase + v*8);
      #pragma unroll
      for (int k = 0; k < 8; ++k){
        float gv = (b2f(y1u.h[k]) + b2f(y2u.h[k])) * silu_f(b2f(zu.h[k]));
        ssq += gv*gv;
        gs[v].h[k] = f2b(gv);
      }
    }
    ssq += __shfl_xor(ssq, 1);
    ssq += __shfl_xor(ssq, 2);
    float rr = rsqrtf(ssq * (1.f/256.f) + 1e-5f);
    #pragma unroll
    for (int v = 0; v < 8; ++v){
      U8 o;
      #pragma unroll
      for (int k = 0; k < 8; ++k)
        o.h[k] = f2b(b2f(gs[v].h[k]) * rr * nws[q*64 + v*8 + k]);
      *(uint4*)((char*)Ylds + SWZ4(r, (q*64 + v*8)*2)) = o.v;
    }
  }
  __syncthreads();
  // phase C: out_proj GEMM  yn[64x256] @ wo[dj][128x256]^T
  const u16* Bg = wo + (size_t)dj*DM*DI;
  f32x4 acc2[2][4] = {};
  for (int kt = 0; kt < 4; ++kt){
    #pragma unroll
    for (int it = 0; it < 4; ++it){
      int idx = it*256 + tid, r = idx >> 3, slot = idx & 7;
      uint4 vb = *(const uint4*)(Bg + (size_t)r*DI + kt*64 + slot*8);
      *(uint4*)((char*)Bs + SWZ(r, slot*16)) = vb;
    }
    __syncthreads();
    #pragma unroll
    for (int ks = 0; ks < 64; ks += 32){
      bf16x8 a[2], b[4];
      int cb = (ks + (l >> 4)*8)*2;
      int kcol = kt*64 + ks + (l >> 4)*8;
      #pragma unroll
      for (int i = 0; i < 2; ++i)
        a[i] = *(bf16x8*)((char*)Ylds + SWZ4(wr*32 + i*16 + (l & 15), kcol*2));
      #pragma unroll
      for (int i = 0; i < 4; ++i)
        b[i] = *(bf16x8*)((char*)Bs + SWZ(wc*64 + i*16 + (l & 15), cb));
      #pragma unroll
      for (int i = 0; i < 2; ++i)
        #pragma unroll
        for (int jn = 0; jn < 4; ++jn)
          acc2[i][jn] = __builtin_amdgcn_mfma_f32_16x16x32_bf16(a[i], b[jn], acc2[i][jn], 0, 0, 0);
    }
    __syncthreads();
  }
  float* xr = x + ((size_t)dz*LSEQ + row0)*DM;
  if (j == 0){
    // residual base gathered directly from vectors (xbuf never pre-initialized)
    const int* ip = sidx + (size_t)(d_base+dz)*LSEQ + row0;
    #pragma unroll
    for (int i = 0; i < 2; ++i)
      #pragma unroll
      for (int r = 0; r < 4; ++r){
        int m = wr*32 + i*16 + (l >> 4)*4 + r;
        int src = ip[m];
        #pragma unroll
        for (int jn = 0; jn < 4; ++jn){
          int n = wc*64 + jn*16 + (l & 15);
          xr[(size_t)m*DM + n] = vecs[(size_t)src*DM + n] + acc2[i][jn][r];
        }
      }
  } else {
    // residual + convert -> Bs (64x128), then row-scatter into multi
    #pragma unroll
    for (int i = 0; i < 2; ++i)
      #pragma unroll
      for (int jn = 0; jn < 4; ++jn)
        #pragma unroll
        for (int r = 0; r < 4; ++r){
          int m = wr*32 + i*16 + (l >> 4)*4 + r, n = wc*64 + jn*16 + (l & 15);
          float res = xr[(size_t)m*DM + n] + acc2[i][jn][r];
          Bs[m*128 + n] = f2b(res);
        }
    __syncthreads();
    const int* ip = sidx + (size_t)(d_base+dz)*LSEQ + row0;
    #pragma unroll
    for (int it = 0; it < 4; ++it){
      int e = it*256 + tid, r = e >> 4, slot = e & 15;
      int orig = ip[r];
      uint4 v = *(uint4*)(Bs + r*128 + slot*8);
      *(uint4*)(multi + (size_t)orig*768 + (size_t)(d_base+dz)*128 + slot*8) = v;
    }
  }
}

// ---------------- fuse: fused LN(768) + GEMM + bias + exact gelu; N-split x2 ----------------
__global__ __launch_bounds__(256) void k_fuse(const u16* __restrict__ multi, const u16* __restrict__ wbf,
                                              const float* __restrict__ lnw, const float* __restrict__ lnb,
                                              const float* __restrict__ fb, float* __restrict__ out){
  __shared__ __align__(16) u16 As[64*64];    // 8KB
  __shared__ __align__(16) u16 Bs[64*64];    // 8KB
  __shared__ float swn[768], sbn[768], smu[64], sinv[64];
  int nh = blockIdx.x, mt = blockIdx.y, tid = threadIdx.x;
  int l = tid & 63, w = tid >> 6, wr = w >> 1, wc = w & 1;
  for (int e = tid; e < 192; e += 256){
    ((float4*)swn)[e] = ((const float4*)lnw)[e];
    ((float4*)sbn)[e] = ((const float4*)lnb)[e];
  }
  {
    int r = tid >> 2, q = tid & 3;
    const u16* row = multi + ((size_t)(mt*64 + r))*768 + q*192;
    float s = 0.f, ss = 0.f;
    #pragma unroll
    for (int v = 0; v < 24; ++v){
      U8 u; u.v = *(const uint4*)(row + v*8);
      #pragma unroll
      for (int k = 0; k < 8; ++k){ float f = b2f(u.h[k]); s += f; ss += f*f; }
    }
    s += __shfl_xor(s, 1); s += __shfl_xor(s, 2);
    ss += __shfl_xor(ss, 1); ss += __shfl_xor(ss, 2);
    if (q == 0){
      float mu = s * (1.f/768.f);
      smu[r] = mu;
      sinv[r] = rsqrtf(ss * (1.f/768.f) - mu*mu + 1e-5f);
    }
  }
  __syncthreads();
  const u16* Ag = multi + (size_t)mt*64*768;
  const u16* Wg = wbf + (size_t)nh*64*768;
  f32x4 acc[2][2] = {};
  for (int kt = 0; kt < 12; ++kt){
    #pragma unroll
    for (int it = 0; it < 2; ++it){
      int e = it*256 + tid, r = e >> 3, slot = e & 7;
      U8 u; u.v = *(const uint4*)(Ag + (size_t)r*768 + kt*64 + slot*8);
      float mu = smu[r], inv = sinv[r];
      U8 o;
      #pragma unroll
      for (int k = 0; k < 8; ++k){
        int col = kt*64 + slot*8 + k;
        o.h[k] = f2b((b2f(u.h[k]) - mu)*inv*swn[col] + sbn[col]);
      }
      *(uint4*)((char*)As + SWZ(r, slot*16)) = o.v;
    }
    #pragma unroll
    for (int it = 0; it < 2; ++it){
      int e = it*256 + tid, r = e >> 3, slot = e & 7;
      uint4 vb = *(const uint4*)(Wg + (size_t)r*768 + kt*64 + slot*8);
      *(uint4*)((char*)Bs + SWZ(r, slot*16)) = vb;
    }
    __syncthreads();
    #pragma unroll
    for (int ks = 0; ks < 64; ks += 32){
      bf16x8 a[2], b[2];
      int cb = (ks + (l >> 4)*8)*2;
      #pragma unroll
      for (int i = 0; i < 2; ++i)
        a[i] = *(bf16x8*)((char*)As + SWZ(wr*32 + i*16 + (l & 15), cb));
      #pragma unroll
      for (int i = 0; i < 2; ++i)
        b[i] = *(bf16x8*)((char*)Bs + SWZ(wc*32 + i*16 + (l & 15), cb));
      #pragma unroll
      for (int i = 0; i < 2; ++i)
        #pragma unroll
        for (int jn = 0; jn < 2; ++jn)
          acc[i][jn] = __builtin_amdgcn_mfma_f32_16x16x32_bf16(a[i], b[jn], acc[i][jn], 0, 0, 0);
    }
    __syncthreads();
  }
  #pragma unroll
  for (int i = 0; i < 2; ++i)
    #pragma unroll
    for (int jn = 0; jn < 2; ++jn)
      #pragma unroll
      for (int r = 0; r < 4; ++r){
        int m = wr*32 + i*16 + (l >> 4)*4 + r;
        int n = nh*64 + wc*32 + jn*16 + (l & 15);
        float v = acc[i][jn][r] + fb[n];
        float gl = 0.5f * v * (1.f + erff(v * 0.70710678118654752f));
        out[(size_t)(mt*64 + m)*DM + n] = gl;
      }
}

extern "C" void kernel_launch(void* const* d_in, const int* in_sizes, int n_in,
                              void* d_out, int out_size, void* d_ws, size_t ws_size,
                              hipStream_t stream){
  (void)in_sizes; (void)n_in; (void)out_size;
  const float* vectors  = (const float*)d_in[0];
  const int*   coords   = (const int*)d_in[1];
  const float* ln_w     = (const float*)d_in[2];
  const float* ln_b     = (const float*)d_in[3];
  const float* in_w     = (const float*)d_in[4];
  const float* conv_w   = (const float*)d_in[5];
  const float* conv_b   = (const float*)d_in[6];
  const float* dt_bias  = (const float*)d_in[7];
  const float* A_log    = (const float*)d_in[8];
  const float* D_skip   = (const float*)d_in[9];
  const float* norm_w   = (const float*)d_in[10];
  const float* out_w    = (const float*)d_in[11];
  const float* fuse_lw  = (const float*)d_in[12];
  const float* fuse_lb  = (const float*)d_in[13];
  const float* fuse_w   = (const float*)d_in[14];
  const float* fuse_b   = (const float*)d_in[15];
  float* out = (float*)d_out;

  char* p = (char*)d_ws;
  auto carve = [&](size_t bytes)->char*{
    char* r = p; p += (bytes + 255) & ~(size_t)255; return r;
  };
  int* idxb = (int*)carve((size_t)NDIR*LSEQ*4);
  unsigned long long* skey  = (unsigned long long*)carve((size_t)NDIR*LSEQ*8);
  unsigned long long* skey2 = (unsigned long long*)carve((size_t)NDIR*LSEQ*8);
  int* starts = (int*)carve((size_t)NDIR*1025*4);
  int* cursor = (int*)carve((size_t)NDIR*1024*4);
  u16* multi = (u16*)carve((size_t)LSEQ*768*2);
  u16* wbf_in   = (u16*)carve((size_t)NW0*2);
  u16* wbf_out  = (u16*)carve((size_t)NW1*2);
  u16* wbf_fuse = (u16*)carve((size_t)NW2*2);

  size_t fixed = (size_t)(p - (char*)d_ws);
  auto need = [&](int nd)->size_t{
    size_t s = 0; auto a = [&](size_t b){ s += (b + 255) & ~(size_t)255; };
    a((size_t)nd*LSEQ*DM*4);      // xbuf (f32 residual)
    a((size_t)nd*LSEQ*DI*2);      // zbuf (bf16)
    a((size_t)nd*LSEQ*CONVD*2);   // xact (bf16, conv'd)
    a((size_t)nd*NCHUNK*6*CONVD*2); // bnd (boundary rows)
    a((size_t)nd*LSEQ*NH*4);      // dtb (f32)
    a((size_t)nd*NCHUNK*NH*4);    // ltot (f32)
    a((size_t)nd*LSEQ*DI*2);      // y1 (bf16)
    a((size_t)nd*NCHUNK*NH*DSTATE*HD*2); // E (bf16, in-place scan)
    return s;
  };
  // adaptive batching: largest nd in {6,3,2,1} that fits the workspace
  int nd = 1;
  {
    const int cands[3] = {6, 3, 2};
    for (int ci = 0; ci < 3; ++ci){
      if (fixed + need(cands[ci]) <= ws_size){ nd = cands[ci]; break; }
    }
  }
  if (fixed + need(nd) > ws_size) return;  // insufficient workspace: no-op

  float* xbuf = (float*)carve((size_t)nd*LSEQ*DM*4);
  u16*   zbuf = (u16*)carve((size_t)nd*LSEQ*DI*2);
  u16*   xact = (u16*)carve((size_t)nd*LSEQ*CONVD*2);
  u16*   bnd  = (u16*)carve((size_t)nd*NCHUNK*6*CONVD*2);
  float* dtb  = (float*)carve((size_t)nd*LSEQ*NH*4);
  float* ltot = (float*)carve((size_t)nd*NCHUNK*NH*4);
  u16*   y1b  = (u16*)carve((size_t)nd*LSEQ*DI*2);
  u16*   Ebuf = (u16*)carve((size_t)nd*NCHUNK*NH*DSTATE*HD*2);

  k_cvt         <<<(NW0+NW1+NW2+255)/256, 256, 0, stream>>>(in_w, out_w, fuse_w, wbf_in, wbf_out, wbf_fuse, cursor);
  k_sort1       <<<(NDIR*LSEQ + 255)/256, 256, 0, stream>>>(coords, skey, cursor);
  k_sort_scan   <<<NDIR, 1024, 0, stream>>>(cursor, starts);
  k_sort_scatter<<<(NDIR*LSEQ + 255)/256, 256, 0, stream>>>(skey, skey2, cursor);
  k_sort_rank   <<<(NDIR*LSEQ + 255)/256, 256, 0, stream>>>(skey2, starts, idxb);

  for (int d_base = 0; d_base < NDIR; d_base += nd){
    for (int j = 0; j < 2; ++j){
      k_inproj<<<dim3(3, LSEQ/64, nd), 256, 0, stream>>>(xbuf, vectors, idxb, ln_w, ln_b, wbf_in, dt_bias,
                                                         conv_w, conv_b, zbuf, xact, bnd, dtb, d_base, j);
      k_convfix<<<dim3(NCHUNK, nd), 256, 0, stream>>>(bnd, conv_w, conv_b, xact, d_base, j);
      k_chunk1<<<dim3(NCHUNK, nd), 256, 0, stream>>>(xact, dtb, A_log, D_skip,
                                                     Ebuf, y1b, ltot, d_base, j);
      k_seq   <<<(nd*16384 + 255)/256, 256, 0, stream>>>(Ebuf, ltot, nd);
      k_chunk2<<<dim3(NCHUNK, nd), 256, 0, stream>>>(xact, dtb, A_log, zbuf, y1b, Ebuf,
                                                     norm_w, wbf_out, xbuf, vectors, idxb, multi, d_base, j);
    }
  }
  k_fuse <<<dim3(2, LSEQ/64), 256, 0, stream>>>(multi, wbf_fuse, fuse_lw, fuse_lb, fuse_b, out);
}

// Round 25
// 702.623 us; speedup vs baseline: 1.0676x; 1.0108x over previous
//
#include <hip/hip_runtime.h>
#include <math.h>

#define LSEQ   16384
#define DM     128
#define DI     256
#define DSTATE 64
#define NH     4
#define HD     64
#define CONVD  384
#define DPROJ  644
#define NDIR   6
#define NCHUNK 256      // LSEQ/64

typedef unsigned short u16;
typedef __attribute__((ext_vector_type(8))) __bf16 bf16x8;
typedef __attribute__((ext_vector_type(4))) float f32x4;

union U8 { uint4 v; u16 h[8]; };

__device__ __constant__ int ORD[6][3] = {{0,1,2},{0,2,1},{1,0,2},{1,2,0},{2,0,1},{2,1,0}};

__device__ __forceinline__ float softplus_f(float x){
  float ax = fabsf(x);
  return fmaxf(x, 0.f) + log1pf(__expf(-ax));
}
__device__ __forceinline__ float silu_f(float x){
  return x / (1.f + __expf(-x));
}
__device__ __forceinline__ u16 f2b(float f){
  unsigned u = __float_as_uint(f);
  unsigned r = (u + 0x7fffu + ((u >> 16) & 1u)) >> 16;
  return (u16)r;
}
__device__ __forceinline__ float b2f(u16 h){
  return __uint_as_float(((unsigned)h) << 16);
}
// XOR swizzle for [rows][128B] bf16 LDS tiles: conflict-free ds_read_b128 (T2)
__device__ __forceinline__ int SWZ(int r, int cb){
  return r*128 + (cb ^ ((r & 7) << 4));
}
// swizzle for 256B-row LDS tiles (inproj As)
__device__ __forceinline__ int SWZ2(int r, int cb){
  return r*256 + (cb ^ ((r & 7) << 4));
}
// swizzle for 512B-row LDS tiles (chunk2 Ylds)
__device__ __forceinline__ int SWZ4(int r, int cb){
  return r*512 + (cb ^ ((r & 7) << 4));
}
// XCD-chunked block remap (T1): total must be %8==0 (holds for nd in {1,2,3,6})
__device__ __forceinline__ int xcd_work(int lin, int total){
  return (lin & 7)*(total >> 3) + (lin >> 3);
}

// async global->LDS staging of one 128x64-u16 tile into SWZ layout.
// LDS dest is LINEAR (wave-uniform base + lane*16); source column carries the
// inverse swizzle (XOR involution within each 128B row) so SWZ readers see
// the right bytes (rule #21: linear dest + inverse-swz source + swz read).
__device__ __forceinline__ void stage_tile_async(const u16* __restrict__ srcbase, size_t srcstride,
                                                 u16* lds, int w, int l){
  int cbl = (l & 7) * 16;                 // byte col within 128B LDS row
  int cbs = cbl ^ ((l >> 3) << 4);        // swizzled source byte col ((r&7)==(l>>3))
  #pragma unroll
  for (int it = 0; it < 4; ++it){
    int chunk = it*4 + w;                 // 0..15, wave-uniform
    int r = chunk*8 + (l >> 3);           // 0..127
    const u16* src = srcbase + (size_t)r*srcstride + (cbs >> 1);
    __builtin_amdgcn_global_load_lds(
        (const __attribute__((address_space(1))) void*)src,
        (__attribute__((address_space(3))) void*)((char*)lds + chunk*1024),
        16, 0, 0);
  }
}

// ---------------- weight convert to bf16 (+ cursor zeroing) ----------------
#define NW0 (12*768*128)
#define NW1 (12*128*256)
#define NW2 (128*768)
__global__ __launch_bounds__(256) void k_cvt(const float* __restrict__ in_w,
                                             const float* __restrict__ out_w,
                                             const float* __restrict__ fuse_w,
                                             u16* __restrict__ wi, u16* __restrict__ wo,
                                             u16* __restrict__ wf, int* __restrict__ cursor){
  int i = blockIdx.x*256 + threadIdx.x;
  if (i < NDIR*1024) cursor[i] = 0;
  if (i < NW0){
    int dj = i / (768*128), rem = i % (768*128), r = rem >> 7, c = rem & 127;
    float v = (r < DPROJ) ? in_w[((size_t)dj*DPROJ + r)*128 + c] : 0.f;
    wi[i] = f2b(v);
  } else if (i < NW0 + NW1){
    int k = i - NW0;
    wo[k] = f2b(out_w[k]);
  } else if (i < NW0 + NW1 + NW2){
    int k = i - NW0 - NW1;
    wf[k] = f2b(fuse_w[k]);
  }
}

// ---------------- sort ----------------
__global__ __launch_bounds__(256) void k_sort1(const int* __restrict__ coords,
                                               unsigned long long* __restrict__ skey,
                                               int* __restrict__ cursor){
  int i = blockIdx.x*256 + threadIdx.x;
  if (i >= NDIR*LSEQ) return;
  int d = i >> 14, t = i & 16383;
  unsigned k = ((unsigned)coords[t*4 + ORD[d][0]] << 20)
             | ((unsigned)coords[t*4 + ORD[d][1]] << 10)
             |  (unsigned)coords[t*4 + ORD[d][2]];
  skey[i] = ((unsigned long long)k << 14) | (unsigned long long)t;
  atomicAdd(&cursor[(d << 10) + (k >> 20)], 1);
}

__global__ void k_sort_scan(int* __restrict__ cursor, int* __restrict__ starts){
  __shared__ int sh[1024];
  int d = blockIdx.x, t = threadIdx.x;
  int v = cursor[d*1024 + t];
  sh[t] = v; __syncthreads();
  for (int off = 1; off < 1024; off <<= 1){
    int a = (t >= off) ? sh[t-off] : 0;
    __syncthreads();
    sh[t] += a;
    __syncthreads();
  }
  int incl = sh[t], excl = incl - v;
  starts[d*1025 + t] = excl;
  cursor[d*1024 + t] = excl;
  if (t == 1023) starts[d*1025 + 1024] = incl;
}

__global__ __launch_bounds__(256) void k_sort_scatter(const unsigned long long* __restrict__ skey,
                                                      unsigned long long* __restrict__ skey2,
                                                      int* __restrict__ cursor){
  int i = blockIdx.x*256 + threadIdx.x;
  if (i >= NDIR*LSEQ) return;
  int d = i >> 14;
  unsigned long long v = skey[i];
  int b = (int)(v >> 34);
  int pos = atomicAdd(&cursor[(d << 10) + b], 1);
  skey2[(size_t)d*LSEQ + pos] = v;
}

__global__ __launch_bounds__(256) void k_sort_rank(const unsigned long long* __restrict__ skey2,
                                                   const int* __restrict__ starts,
                                                   int* __restrict__ idx){
  int i = blockIdx.x*256 + threadIdx.x;
  if (i >= NDIR*LSEQ) return;
  int d = i >> 14;
  unsigned long long v = skey2[i];
  int b = (int)(v >> 34);
  int s = starts[d*1025 + b], e = starts[d*1025 + b + 1];
  int r = s;
  for (int q = s; q < e; ++q) r += (skey2[(size_t)d*LSEQ + q] < v);
  int orig = (int)(v & 16383ULL);
  idx[(size_t)d*LSEQ + r] = orig;
}

// ---------------- in_proj: 64-row tiles; fused LN; dbuf pipelined staging; XCD swizzle ----------------
__global__ __launch_bounds__(256) void k_inproj(const float* __restrict__ xres,
    const float* __restrict__ vecs, const int* __restrict__ sidx,
    const float* __restrict__ lnw, const float* __restrict__ lnb,
    const u16* __restrict__ wbf, const float* __restrict__ dt_bias,
    const float* __restrict__ conv_w, const float* __restrict__ conv_b,
    u16* __restrict__ zbuf, u16* __restrict__ xact, u16* __restrict__ bnd,
    float* __restrict__ dtb, int d_base, int j, int nd){
  __shared__ __align__(16) u16 As[64*128];      // 16KB (row stride 256B, swizzled)
  __shared__ __align__(16) u16 Bsb[2][128*64];  // 32KB double-buffered weights / epilogue scratch
  __shared__ float cwsh[128][4];
  __shared__ float cbsh[128];
  int lin = blockIdx.x + 3*(blockIdx.y + 256*blockIdx.z);
  int work = xcd_work(lin, 768*nd);
  int bpair = work % 3, mt = (work/3) & 255, dz = work/768;
  int tid = threadIdx.x;
  int dj = (d_base+dz)*2 + j;
  int l = tid & 63, w = tid >> 6, wr = w >> 1, wc = w & 1;
  const u16* W0 = wbf + (size_t)dj*768*DM + (size_t)(bpair*2)*128*DM;
  const u16* W1 = W0 + (size_t)128*DM;
  // issue phase-0 staging (bn0, kt=0) before LN: latency hides under LN compute
  stage_tile_async(W0, DM, Bsb[0], w, l);
  // ---- parallel LN: 2 threads per row (r15 summation order); j==0 gathers rows from vectors ----
  if (tid < 128){
    int r = tid >> 1, half = tid & 1;
    const float4* xr;
    if (j == 0){
      int src = sidx[(size_t)(d_base+dz)*LSEQ + (size_t)mt*64 + r];
      xr = (const float4*)(vecs + (size_t)src*DM) + half*16;
    } else {
      xr = (const float4*)(xres + ((size_t)dz*LSEQ + (size_t)mt*64 + r)*DM) + half*16;
    }
    float4 v[16];
    #pragma unroll
    for (int q = 0; q < 16; ++q) v[q] = xr[q];
    float s = 0.f, ss2 = 0.f;
    #pragma unroll
    for (int q = 0; q < 16; ++q){
      s   += v[q].x + v[q].y + v[q].z + v[q].w;
      ss2 += v[q].x*v[q].x + v[q].y*v[q].y + v[q].z*v[q].z + v[q].w*v[q].w;
    }
    s += __shfl_xor(s, 1); ss2 += __shfl_xor(ss2, 1);
    float mu = s*(1.f/128.f);
    float var = ss2*(1.f/128.f) - mu*mu;
    float inv = rsqrtf(var + 1e-5f);
    const float4* w4 = (const float4*)(lnw + (size_t)dj*DM) + half*16;
    const float4* b4 = (const float4*)(lnb + (size_t)dj*DM) + half*16;
    #pragma unroll
    for (int g = 0; g < 8; ++g){
      float4 a = v[2*g], b = v[2*g+1];
      float4 wa = w4[2*g], wb = w4[2*g+1];
      float4 ba = b4[2*g], bb = b4[2*g+1];
      U8 pk;
      pk.h[0] = f2b((a.x-mu)*inv*wa.x + ba.x);
      pk.h[1] = f2b((a.y-mu)*inv*wa.y + ba.y);
      pk.h[2] = f2b((a.z-mu)*inv*wa.z + ba.z);
      pk.h[3] = f2b((a.w-mu)*inv*wa.w + ba.w);
      pk.h[4] = f2b((b.x-mu)*inv*wb.x + bb.x);
      pk.h[5] = f2b((b.y-mu)*inv*wb.y + bb.y);
      pk.h[6] = f2b((b.z-mu)*inv*wb.z + bb.z);
      pk.h[7] = f2b((b.w-mu)*inv*wb.w + bb.w);
      int c0 = half*64 + g*8;
      *(uint4*)((char*)As + SWZ2(r, c0*2)) = pk.v;
    }
  }
  __syncthreads();   // LN writes visible; phase-0 staging drained
  // ---- 4 pipelined MFMA phases (prefetch next tile into other buffer before compute) ----
  f32x4 accA[2][4] = {}, accB[2][4] = {};
  auto mfma_phase = [&](u16* bs, int kt, f32x4 (&acc)[2][4]){
    #pragma unroll
    for (int ks = 0; ks < 64; ks += 32){
      bf16x8 a[2], b[4];
      int cbb = (ks + (l >> 4)*8)*2;
      int kea = kt*64 + ks + (l >> 4)*8;
      #pragma unroll
      for (int i = 0; i < 2; ++i){
        int ra = wr*32 + i*16 + (l & 15);
        a[i] = *(bf16x8*)((char*)As + SWZ2(ra, kea*2));
      }
      #pragma unroll
      for (int i = 0; i < 4; ++i)
        b[i] = *(bf16x8*)((char*)bs + SWZ(wc*64 + i*16 + (l & 15), cbb));
      #pragma unroll
      for (int i = 0; i < 2; ++i)
        #pragma unroll
        for (int jn = 0; jn < 4; ++jn)
          acc[i][jn] = __builtin_amdgcn_mfma_f32_16x16x32_bf16(a[i], b[jn], acc[i][jn], 0, 0, 0);
    }
  };
  // phase 0: compute (bn0,kt0) from Bsb[0]; prefetch (bn0,kt1) -> Bsb[1]
  stage_tile_async(W0 + 64, DM, Bsb[1], w, l);
  mfma_phase(Bsb[0], 0, accA);
  __syncthreads();
  // phase 1: compute (bn0,kt1) from Bsb[1]; prefetch (bn1,kt0) -> Bsb[0]
  stage_tile_async(W1, DM, Bsb[0], w, l);
  mfma_phase(Bsb[1], 1, accA);
  __syncthreads();
  // phase 2: compute (bn1,kt0) from Bsb[0]; prefetch (bn1,kt1) -> Bsb[1]
  stage_tile_async(W1 + 64, DM, Bsb[1], w, l);
  mfma_phase(Bsb[0], 0, accB);
  __syncthreads();
  // phase 3: compute (bn1,kt1) from Bsb[1]
  mfma_phase(Bsb[1], 1, accB);
  __syncthreads();
  // ---- epilogues (scratch = Bsb[0]) ----
  u16* Bs = Bsb[0];
  #pragma unroll
  for (int ib = 0; ib < 2; ++ib){
    int bn = bpair*2 + ib;
    f32x4 (&acc)[2][4] = ib ? accB : accA;
    if (bn < 2){
      // z columns: stage 64x128 tile into Bs (linear), 16B coalesced writes
      #pragma unroll
      for (int i = 0; i < 2; ++i)
        #pragma unroll
        for (int jn = 0; jn < 4; ++jn)
          #pragma unroll
          for (int r = 0; r < 4; ++r){
            int m = wr*32 + i*16 + (l >> 4)*4 + r, n = wc*64 + jn*16 + (l & 15);
            Bs[m*128 + n] = f2b(acc[i][jn][r]);
          }
      __syncthreads();
      u16* dst = zbuf + ((size_t)dz*LSEQ + (size_t)mt*64)*DI + bn*128;
      #pragma unroll
      for (int it = 0; it < 4; ++it){
        int idx = it*256 + tid, r = idx >> 4, slot = idx & 15;
        uint4 v = *(uint4*)(Bs + r*128 + slot*8);
        *(uint4*)(dst + (size_t)r*DI + slot*8) = v;
      }
      __syncthreads();
    } else if (bn < 5){
      // xBC columns: stage raw tile, load conv weights, then fused conv+silu (rows>=3) + boundary store
      int xco0 = bn*128 - 256;
      #pragma unroll
      for (int i = 0; i < 2; ++i)
        #pragma unroll
        for (int jn = 0; jn < 4; ++jn)
          #pragma unroll
          for (int r = 0; r < 4; ++r){
            int m = wr*32 + i*16 + (l >> 4)*4 + r, n = wc*64 + jn*16 + (l & 15);
            Bs[m*128 + n] = f2b(acc[i][jn][r]);
          }
      if (tid < 128){
        const float* wp = conv_w + ((size_t)dj*CONVD + xco0 + tid)*4;
        cwsh[tid][0]=wp[0]; cwsh[tid][1]=wp[1]; cwsh[tid][2]=wp[2]; cwsh[tid][3]=wp[3];
        cbsh[tid] = conv_b[(size_t)dj*CONVD + xco0 + tid];
      }
      __syncthreads();
      u16* bt = bnd + ((size_t)(dz*NCHUNK + mt)*6)*CONVD + xco0;
      u16* xdst = xact + ((size_t)dz*LSEQ + (size_t)mt*64)*CONVD + xco0;
      #pragma unroll
      for (int it = 0; it < 4; ++it){
        int idx = it*256 + tid, r = idx >> 4, slot = idx & 15;
        int colbase = slot*8;
        if (r < 3){
          uint4 v = *(uint4*)(Bs + r*128 + colbase);
          *(uint4*)(bt + (size_t)r*CONVD + colbase) = v;
        } else {
          if (r >= 61){
            uint4 v = *(uint4*)(Bs + r*128 + colbase);
            *(uint4*)(bt + (size_t)(r-58)*CONVD + colbase) = v;
          }
          U8 tp[4];
          #pragma unroll
          for (int k = 0; k < 4; ++k)
            tp[k].v = *(uint4*)(Bs + (r-3+k)*128 + colbase);
          U8 o;
          #pragma unroll
          for (int k2 = 0; k2 < 8; ++k2){
            int c = colbase + k2;
            float v = b2f(tp[0].h[k2])*cwsh[c][0] + b2f(tp[1].h[k2])*cwsh[c][1]
                    + b2f(tp[2].h[k2])*cwsh[c][2] + b2f(tp[3].h[k2])*cwsh[c][3] + cbsh[c];
            o.h[k2] = f2b(silu_f(v));
          }
          *(uint4*)(xdst + (size_t)r*CONVD + colbase) = o.v;
        }
      }
      __syncthreads();
    } else {
      #pragma unroll
      for (int i = 0; i < 2; ++i)
        #pragma unroll
        for (int jn = 0; jn < 4; ++jn)
          #pragma unroll
          for (int r = 0; r < 4; ++r){
            int m = wr*32 + i*16 + (l >> 4)*4 + r, n = wc*64 + jn*16 + (l & 15);
            if (n < 4){
              float v = acc[i][jn][r] + dt_bias[dj*4 + n];
              dtb[((size_t)dz*LSEQ + (size_t)mt*64 + m)*4 + n] = softplus_f(v);
            }
          }
    }
  }
}

// ---------------- conv fixup: rows 0..2 of each 64-row tile from boundary buffer ----------------
__global__ __launch_bounds__(256) void k_convfix(const u16* __restrict__ bnd,
    const float* __restrict__ conv_w, const float* __restrict__ conv_b,
    u16* __restrict__ xact, int d_base, int j){
  int mt = blockIdx.x, dz = blockIdx.y, tid = threadIdx.x;
  int dj = (d_base+dz)*2 + j;
  if (tid >= 144) return;
  int r = tid / 48, cg = tid % 48;
  int col = cg*8;
  const u16* bcur  = bnd + ((size_t)(dz*NCHUNK + mt)*6)*CONVD;
  const u16* bprev = bnd + ((size_t)(dz*NCHUNK + mt - 1)*6)*CONVD;
  U8 tp[4];
  #pragma unroll
  for (int k = 0; k < 4; ++k){
    int grow = r - 3 + k;
    if (grow >= 0) tp[k].v = *(const uint4*)(bcur + (size_t)grow*CONVD + col);
    else if (mt > 0) tp[k].v = *(const uint4*)(bprev + (size_t)(6 + grow)*CONVD + col);
    else tp[k].v = make_uint4(0,0,0,0);
  }
  U8 o;
  #pragma unroll
  for (int k2 = 0; k2 < 8; ++k2){
    int c = col + k2;
    const float* wp = conv_w + ((size_t)dj*CONVD + c)*4;
    float v = b2f(tp[0].h[k2])*wp[0] + b2f(tp[1].h[k2])*wp[1]
            + b2f(tp[2].h[k2])*wp[2] + b2f(tp[3].h[k2])*wp[3] + conv_b[(size_t)dj*CONVD + c];
    o.h[k2] = f2b(silu_f(v));
  }
  *(uint4*)(xact + ((size_t)dz*LSEQ + (size_t)mt*64 + r)*CONVD + col) = o.v;
}

// ---------------- chunk kernel 1: dt-scan fused; two-stage transpose; G, Y1, S^T; XCD swizzle ----------------
__global__ __launch_bounds__(256) void k_chunk1(const u16* __restrict__ xact, const float* __restrict__ dtb,
    const float* __restrict__ A_log, const float* __restrict__ Dskip,
    u16* __restrict__ E, u16* __restrict__ y1, float* __restrict__ ltot, int d_base, int j, int nd){
  __shared__ __align__(16) u16 sB[4096], sC[4096], sM[4096], sXt[4096], sBw[4096];
  __shared__ float sLl[4][64], sdt[4][64];
  __shared__ float wexp[64];
  int lin = blockIdx.x + 256*blockIdx.y;
  int work = xcd_work(lin, 256*nd);
  int c = work & 255, dz = work >> 8;
  int tid = threadIdx.x;
  int dj = (d_base+dz)*2 + j;
  int l = tid & 63, w = tid >> 6, wr = w >> 1, wc = w & 1;
  int mb = wr*32, nb = wc*32;
  int row0 = c*64;
  const u16* xa = xact + ((size_t)dz*LSEQ + row0)*CONVD;
  // per-wave dt scan: wave w = head w
  {
    float4 d4 = *(const float4*)(dtb + ((size_t)dz*LSEQ + row0 + l)*4);
    float dt = (w==0)?d4.x:((w==1)?d4.y:((w==2)?d4.z:d4.w));
    float A = -__expf(A_log[dj*4 + w]);
    float v = dt * A;
    #pragma unroll
    for (int o = 1; o < 64; o <<= 1){ float pv = __shfl_up(v, o); if (l >= o) v += pv; }
    sdt[w][l] = dt; sLl[w][l] = v;
    if (l == 63) ltot[((size_t)(dz*NCHUNK + c))*NH + w] = v;
  }
  // stage B (cols 256..319) and C (cols 320..383)
  #pragma unroll
  for (int it = 0; it < 2; ++it){
    int idx = it*256 + tid, t = idx >> 3, slot = idx & 7;
    uint4 vB = *(const uint4*)(xa + (size_t)t*CONVD + 256 + slot*8);
    uint4 vC = *(const uint4*)(xa + (size_t)t*CONVD + 320 + slot*8);
    *(uint4*)((char*)sB + SWZ(t, slot*16)) = vB;
    *(uint4*)((char*)sC + SWZ(t, slot*16)) = vC;
  }
  __syncthreads();
  // G[t][s] = sum_n C[t][n]*B[s][n]
  f32x4 g[2][2] = {};
  #pragma unroll
  for (int ks = 0; ks < 64; ks += 32){
    bf16x8 a[2], b[2];
    int cb = (ks + (l >> 4)*8)*2;
    #pragma unroll
    for (int i = 0; i < 2; ++i){
      a[i] = *(bf16x8*)((char*)sC + SWZ(mb + i*16 + (l & 15), cb));
      b[i] = *(bf16x8*)((char*)sB + SWZ(nb + i*16 + (l & 15), cb));
    }
    #pragma unroll
    for (int i = 0; i < 2; ++i)
      #pragma unroll
      for (int jn = 0; jn < 2; ++jn)
        g[i][jn] = __builtin_amdgcn_mfma_f32_16x16x32_bf16(a[i], b[jn], g[i][jn], 0, 0, 0);
  }
  for (int h = 0; h < NH; ++h){
    __syncthreads();
    if (tid < 64) wexp[tid] = __expf(sLl[h][63] - sLl[h][tid]) * sdt[h][tid];
    // stage X row-major into sC (vectorized)
    #pragma unroll
    for (int it = 0; it < 2; ++it){
      int idx = it*256 + tid, s = idx >> 3, slot = idx & 7;
      uint4 xv = *(const uint4*)(xa + (size_t)s*CONVD + h*64 + slot*8);
      *(uint4*)((char*)sC + SWZ(s, slot*16)) = xv;
    }
    // build M[t][s]
    #pragma unroll
    for (int i = 0; i < 2; ++i)
      #pragma unroll
      for (int jn = 0; jn < 2; ++jn)
        #pragma unroll
        for (int r = 0; r < 4; ++r){
          int t = mb + i*16 + (l >> 4)*4 + r;
          int s = nb + jn*16 + (l & 15);
          float v = (s <= t) ? g[i][jn][r]*__expf(sLl[h][t]-sLl[h][s])*sdt[h][s] : 0.f;
          *(u16*)((char*)sM + SWZ(t, s*2)) = f2b(v);
        }
    __syncthreads();
    // two-stage transpose: Xt[n][s] = X[s][n]; Bw[n][s] = B[s][n]*wexp[s]
    #pragma unroll
    for (int it = 0; it < 2; ++it){
      int idx = it*256 + tid, n = idx & 63, so = idx >> 6;
      U8 xo, bo;
      #pragma unroll
      for (int k = 0; k < 8; ++k){
        int s = so*8 + k;
        u16 xv = *(u16*)((char*)sC + SWZ(s, n*2));
        u16 bv = *(u16*)((char*)sB + SWZ(s, n*2));
        xo.h[k] = xv;
        bo.h[k] = f2b(b2f(bv) * wexp[s]);
      }
      *(uint4*)((char*)sXt + SWZ(n, so*16)) = xo.v;
      *(uint4*)((char*)sBw + SWZ(n, so*16)) = bo.v;
    }
    __syncthreads();
    // Y1 = M x Xt ; S^T = Xt x Bw
    f32x4 y1a[2][2] = {}, ssa[2][2] = {};
    #pragma unroll
    for (int ks = 0; ks < 64; ks += 32){
      int cb = (ks + (l >> 4)*8)*2;
      bf16x8 am[2], ax[2], bx[2], bw2[2];
      #pragma unroll
      for (int i = 0; i < 2; ++i){
        am[i]  = *(bf16x8*)((char*)sM  + SWZ(mb + i*16 + (l & 15), cb));
        ax[i]  = *(bf16x8*)((char*)sXt + SWZ(mb + i*16 + (l & 15), cb));
        bx[i]  = *(bf16x8*)((char*)sXt + SWZ(nb + i*16 + (l & 15), cb));
        bw2[i] = *(bf16x8*)((char*)sBw + SWZ(nb + i*16 + (l & 15), cb));
      }
      #pragma unroll
      for (int i = 0; i < 2; ++i)
        #pragma unroll
        for (int jn = 0; jn < 2; ++jn){
          y1a[i][jn] = __builtin_amdgcn_mfma_f32_16x16x32_bf16(am[i], bx[jn], y1a[i][jn], 0, 0, 0);
          ssa[i][jn] = __builtin_amdgcn_mfma_f32_16x16x32_bf16(ax[i], bw2[jn], ssa[i][jn], 0, 0, 0);
        }
    }
    __syncthreads();   // all waves done reading sM/sBw
    float dsk = Dskip[dj*NH + h];
    #pragma unroll
    for (int i = 0; i < 2; ++i)
      #pragma unroll
      for (int jn = 0; jn < 2; ++jn)
        #pragma unroll
        for (int r = 0; r < 4; ++r){
          int m = mb + i*16 + (l >> 4)*4 + r, n = nb + jn*16 + (l & 15);
          float xsv = b2f(*(u16*)((char*)sXt + SWZ(n, m*2)));
          *(u16*)((char*)sM  + SWZ(m, n*2)) = f2b(y1a[i][jn][r] + dsk * xsv);
          *(u16*)((char*)sBw + SWZ(m, n*2)) = f2b(ssa[i][jn][r]);
        }
    __syncthreads();
    u16* yr = y1 + ((size_t)dz*LSEQ + row0)*DI + h*64;
    u16* Ep = E + ((size_t)(dz*NCHUNK + c)*NH + h)*4096;
    #pragma unroll
    for (int it = 0; it < 2; ++it){
      int idx = it*256 + tid, r = idx >> 3, slot = idx & 7;
      uint4 vy = *(uint4*)((char*)sM  + SWZ(r, slot*16));
      uint4 ve = *(uint4*)((char*)sBw + SWZ(r, slot*16));
      *(uint4*)(yr + (size_t)r*DI + slot*8) = vy;
      *(uint4*)(Ep + r*64 + slot*8) = ve;
    }
  }
}

// ---------------- sequential carry over chunks, in-place on bf16 E, depth-16 prefetch ----------------
__global__ __launch_bounds__(256) void k_seq(u16* __restrict__ E, const float* __restrict__ ltot, int nd){
  int i = blockIdx.x*256 + threadIdx.x;
  if (i >= nd*16384) return;
  int dz = i >> 14, h = (i >> 12) & 3, np = i & 4095;
  const int stride = 16384;
  size_t base = (size_t)dz*NCHUNK*stride + (size_t)h*4096 + np;
  const float* lt = ltot + (size_t)dz*NCHUNK*NH + h;
  u16 eb[16]; float pb[16];
  #pragma unroll
  for (int q = 0; q < 16; ++q){ eb[q] = E[base + (size_t)q*stride]; pb[q] = lt[q*NH]; }
  float carry = 0.f;
  for (int cc = 0; cc < 256; cc += 16){
    u16 e2[16]; float p2[16];
    if (cc + 16 < 256){
      #pragma unroll
      for (int q = 0; q < 16; ++q){
        e2[q] = E[base + (size_t)(cc+16+q)*stride];
        p2[q] = lt[(cc+16+q)*NH];
      }
    }
    #pragma unroll
    for (int q = 0; q < 16; ++q){
      u16 cv = f2b(carry);
      carry = fmaf(__expf(pb[q]), carry, b2f(eb[q]));
      E[base + (size_t)(cc+q)*stride] = cv;
    }
    #pragma unroll
    for (int q = 0; q < 16; ++q){ eb[q] = e2[q]; pb[q] = p2[q]; }
  }
}

// ---------------- chunk kernel 2: Y2 MFMA; gate+RMS in LDS; fused out_proj; XCD swizzle ----------------
__global__ __launch_bounds__(256) void k_chunk2(const u16* __restrict__ xact, const float* __restrict__ dtb,
    const float* __restrict__ A_log, const u16* __restrict__ zbuf, const u16* __restrict__ y1,
    const u16* __restrict__ E, const float* __restrict__ norm_w, const u16* __restrict__ wo,
    float* __restrict__ x, const float* __restrict__ vecs, const int* __restrict__ sidx,
    u16* __restrict__ multi, int d_base, int j, int nd){
  __shared__ __align__(16) u16 SH[24576];   // 48KB: sC(8K) sHt(8K) Ylds(32K); Bs reuses sC+sHt
  u16* sC   = SH;
  u16* sHt  = SH + 4096;
  u16* Ylds = SH + 8192;
  u16* Bs   = SH;             // phase C weight tile / scatter staging (16KB)
  __shared__ float sLl[4][64];
  __shared__ float nws[256];
  int lin = blockIdx.x + 256*blockIdx.y;
  int work = xcd_work(lin, 256*nd);
  int c = work & 255, dz = work >> 8;
  int tid = threadIdx.x;
  int dj = (d_base+dz)*2 + j;
  int l = tid & 63, w = tid >> 6, wr = w >> 1, wc = w & 1;
  int mb = wr*32, nb = wc*32;
  int row0 = c*64;
  const u16* xa = xact + ((size_t)dz*LSEQ + row0)*CONVD;
  if (tid < 64) ((float4*)nws)[tid] = ((const float4*)(norm_w + (size_t)dj*DI))[tid];
  // dt scan
  {
    float4 d4 = *(const float4*)(dtb + ((size_t)dz*LSEQ + row0 + l)*4);
    float dt = (w==0)?d4.x:((w==1)?d4.y:((w==2)?d4.z:d4.w));
    float A = -__expf(A_log[dj*4 + w]);
    float v = dt * A;
    #pragma unroll
    for (int o = 1; o < 64; o <<= 1){ float pv = __shfl_up(v, o); if (l >= o) v += pv; }
    sLl[w][l] = v;
  }
  // stage C (cols 320..383)
  #pragma unroll
  for (int it = 0; it < 2; ++it){
    int idx = it*256 + tid, t = idx >> 3, slot = idx & 7;
    uint4 vC = *(const uint4*)(xa + (size_t)t*CONVD + 320 + slot*8);
    *(uint4*)((char*)sC + SWZ(t, slot*16)) = vC;
  }
  // phase A: per-head MFMA, scaled Y2 into Ylds
  for (int h = 0; h < NH; ++h){
    __syncthreads();
    const u16* Hp = E + ((size_t)(dz*NCHUNK + c)*NH + h)*4096;
    #pragma unroll
    for (int it = 0; it < 2; ++it){
      int idx = it*256 + tid, p = idx >> 3, ng = idx & 7;
      uint4 v = *(const uint4*)(Hp + (size_t)p*64 + ng*8);
      *(uint4*)((char*)sHt + SWZ(p, ng*16)) = v;
    }
    __syncthreads();
    f32x4 acc[2][2] = {};
    #pragma unroll
    for (int ks = 0; ks < 64; ks += 32){
      int cb = (ks + (l >> 4)*8)*2;
      bf16x8 a[2], b[2];
      #pragma unroll
      for (int i = 0; i < 2; ++i){
        a[i] = *(bf16x8*)((char*)sC  + SWZ(mb + i*16 + (l & 15), cb));
        b[i] = *(bf16x8*)((char*)sHt + SWZ(nb + i*16 + (l & 15), cb));
      }
      #pragma unroll
      for (int i = 0; i < 2; ++i)
        #pragma unroll
        for (int jn = 0; jn < 2; ++jn)
          acc[i][jn] = __builtin_amdgcn_mfma_f32_16x16x32_bf16(a[i], b[jn], acc[i][jn], 0, 0, 0);
    }
    #pragma unroll
    for (int i = 0; i < 2; ++i)
      #pragma unroll
      for (int jn = 0; jn < 2; ++jn)
        #pragma unroll
        for (int r = 0; r < 4; ++r){
          int m = mb + i*16 + (l >> 4)*4 + r, n = nb + jn*16 + (l & 15);
          float e = __expf(sLl[h][m]);
          *(u16*)((char*)Ylds + SWZ4(m, (h*64 + n)*2)) = f2b(e * acc[i][jn][r]);
        }
  }
  __syncthreads();
  // phase B: row-parallel gate + RMSNorm, in-place normalized yn into Ylds
  {
    int r = tid >> 2, q = tid & 3;
    size_t rowbase = ((size_t)dz*LSEQ + row0 + r)*DI + q*64;
    float ssq = 0.f;
    U8 gs[8];
    #pragma unroll
    for (int v = 0; v < 8; ++v){
      U8 y2u; y2u.v = *(uint4*)((char*)Ylds + SWZ4(r, (q*64 + v*8)*2));
      U8 y1u; y1u.v = *(const uint4*)(y1 + rowbase + v*8);
      U8 zu;  zu.v  = *(const uint4*)(zbuf + rowbase + v*8);
      #pragma unroll
      for (int k = 0; k < 8; ++k){
        float gv = (b2f(y1u.h[k]) + b2f(y2u.h[k])) * silu_f(b2f(zu.h[k]));
        ssq += gv*gv;
        gs[v].h[k] = f2b(gv);
      }
    }
    ssq += __shfl_xor(ssq, 1);
    ssq += __shfl_xor(ssq, 2);
    float rr = rsqrtf(ssq * (1.f/256.f) + 1e-5f);
    #pragma unroll
    for (int v = 0; v < 8; ++v){
      U8 o;
      #pragma unroll
      for (int k = 0; k < 8; ++k)
        o.h[k] = f2b(b2f(gs[v].h[k]) * rr * nws[q*64 + v*8 + k]);
      *(uint4*)((char*)Ylds + SWZ4(r, (q*64 + v*8)*2)) = o.v;
    }
  }
  __syncthreads();
  // phase C: out_proj GEMM  yn[64x256] @ wo[dj][128x256]^T
  const u16* Bg = wo + (size_t)dj*DM*DI;
  f32x4 acc2[2][4] = {};
  for (int kt = 0; kt < 4; ++kt){
    #pragma unroll
    for (int it = 0; it < 4; ++it){
      int idx = it*256 + tid, r = idx >> 3, slot = idx & 7;
      uint4 vb = *(const uint4*)(Bg + (size_t)r*DI + kt*64 + slot*8);
      *(uint4*)((char*)Bs + SWZ(r, slot*16)) = vb;
    }
    __syncthreads();
    #pragma unroll
    for (int ks = 0; ks < 64; ks += 32){
      bf16x8 a[2], b[4];
      int cb = (ks + (l >> 4)*8)*2;
      int kcol = kt*64 + ks + (l >> 4)*8;
      #pragma unroll
      for (int i = 0; i < 2; ++i)
        a[i] = *(bf16x8*)((char*)Ylds + SWZ4(wr*32 + i*16 + (l & 15), kcol*2));
      #pragma unroll
      for (int i = 0; i < 4; ++i)
        b[i] = *(bf16x8*)((char*)Bs + SWZ(wc*64 + i*16 + (l & 15), cb));
      #pragma unroll
      for (int i = 0; i < 2; ++i)
        #pragma unroll
        for (int jn = 0; jn < 4; ++jn)
          acc2[i][jn] = __builtin_amdgcn_mfma_f32_16x16x32_bf16(a[i], b[jn], acc2[i][jn], 0, 0, 0);
    }
    __syncthreads();
  }
  float* xr = x + ((size_t)dz*LSEQ + row0)*DM;
  if (j == 0){
    // residual base gathered directly from vectors (xbuf never pre-initialized)
    const int* ip = sidx + (size_t)(d_base+dz)*LSEQ + row0;
    #pragma unroll
    for (int i = 0; i < 2; ++i)
      #pragma unroll
      for (int r = 0; r < 4; ++r){
        int m = wr*32 + i*16 + (l >> 4)*4 + r;
        int src = ip[m];
        #pragma unroll
        for (int jn = 0; jn < 4; ++jn){
          int n = wc*64 + jn*16 + (l & 15);
          xr[(size_t)m*DM + n] = vecs[(size_t)src*DM + n] + acc2[i][jn][r];
        }
      }
  } else {
    // residual + convert -> Bs (64x128), then row-scatter into multi
    #pragma unroll
    for (int i = 0; i < 2; ++i)
      #pragma unroll
      for (int jn = 0; jn < 4; ++jn)
        #pragma unroll
        for (int r = 0; r < 4; ++r){
          int m = wr*32 + i*16 + (l >> 4)*4 + r, n = wc*64 + jn*16 + (l & 15);
          float res = xr[(size_t)m*DM + n] + acc2[i][jn][r];
          Bs[m*128 + n] = f2b(res);
        }
    __syncthreads();
    const int* ip = sidx + (size_t)(d_base+dz)*LSEQ + row0;
    #pragma unroll
    for (int it = 0; it < 4; ++it){
      int e = it*256 + tid, r = e >> 4, slot = e & 15;
      int orig = ip[r];
      uint4 v = *(uint4*)(Bs + r*128 + slot*8);
      *(uint4*)(multi + (size_t)orig*768 + (size_t)(d_base+dz)*128 + slot*8) = v;
    }
  }
}

// ---------------- fuse: fused LN(768) + GEMM + bias + exact gelu; N-split x2 ----------------
__global__ __launch_bounds__(256) void k_fuse(const u16* __restrict__ multi, const u16* __restrict__ wbf,
                                              const float* __restrict__ lnw, const float* __restrict__ lnb,
                                              const float* __restrict__ fb, float* __restrict__ out){
  __shared__ __align__(16) u16 As[64*64];    // 8KB
  __shared__ __align__(16) u16 Bs[64*64];    // 8KB
  __shared__ float swn[768], sbn[768], smu[64], sinv[64];
  int nh = blockIdx.x, mt = blockIdx.y, tid = threadIdx.x;
  int l = tid & 63, w = tid >> 6, wr = w >> 1, wc = w & 1;
  for (int e = tid; e < 192; e += 256){
    ((float4*)swn)[e] = ((const float4*)lnw)[e];
    ((float4*)sbn)[e] = ((const float4*)lnb)[e];
  }
  {
    int r = tid >> 2, q = tid & 3;
    const u16* row = multi + ((size_t)(mt*64 + r))*768 + q*192;
    float s = 0.f, ss = 0.f;
    #pragma unroll
    for (int v = 0; v < 24; ++v){
      U8 u; u.v = *(const uint4*)(row + v*8);
      #pragma unroll
      for (int k = 0; k < 8; ++k){ float f = b2f(u.h[k]); s += f; ss += f*f; }
    }
    s += __shfl_xor(s, 1); s += __shfl_xor(s, 2);
    ss += __shfl_xor(ss, 1); ss += __shfl_xor(ss, 2);
    if (q == 0){
      float mu = s * (1.f/768.f);
      smu[r] = mu;
      sinv[r] = rsqrtf(ss * (1.f/768.f) - mu*mu + 1e-5f);
    }
  }
  __syncthreads();
  const u16* Ag = multi + (size_t)mt*64*768;
  const u16* Wg = wbf + (size_t)nh*64*768;
  f32x4 acc[2][2] = {};
  for (int kt = 0; kt < 12; ++kt){
    #pragma unroll
    for (int it = 0; it < 2; ++it){
      int e = it*256 + tid, r = e >> 3, slot = e & 7;
      U8 u; u.v = *(const uint4*)(Ag + (size_t)r*768 + kt*64 + slot*8);
      float mu = smu[r], inv = sinv[r];
      U8 o;
      #pragma unroll
      for (int k = 0; k < 8; ++k){
        int col = kt*64 + slot*8 + k;
        o.h[k] = f2b((b2f(u.h[k]) - mu)*inv*swn[col] + sbn[col]);
      }
      *(uint4*)((char*)As + SWZ(r, slot*16)) = o.v;
    }
    #pragma unroll
    for (int it = 0; it < 2; ++it){
      int e = it*256 + tid, r = e >> 3, slot = e & 7;
      uint4 vb = *(const uint4*)(Wg + (size_t)r*768 + kt*64 + slot*8);
      *(uint4*)((char*)Bs + SWZ(r, slot*16)) = vb;
    }
    __syncthreads();
    #pragma unroll
    for (int ks = 0; ks < 64; ks += 32){
      bf16x8 a[2], b[2];
      int cb = (ks + (l >> 4)*8)*2;
      #pragma unroll
      for (int i = 0; i < 2; ++i)
        a[i] = *(bf16x8*)((char*)As + SWZ(wr*32 + i*16 + (l & 15), cb));
      #pragma unroll
      for (int i = 0; i < 2; ++i)
        b[i] = *(bf16x8*)((char*)Bs + SWZ(wc*32 + i*16 + (l & 15), cb));
      #pragma unroll
      for (int i = 0; i < 2; ++i)
        #pragma unroll
        for (int jn = 0; jn < 2; ++jn)
          acc[i][jn] = __builtin_amdgcn_mfma_f32_16x16x32_bf16(a[i], b[jn], acc[i][jn], 0, 0, 0);
    }
    __syncthreads();
  }
  #pragma unroll
  for (int i = 0; i < 2; ++i)
    #pragma unroll
    for (int jn = 0; jn < 2; ++jn)
      #pragma unroll
      for (int r = 0; r < 4; ++r){
        int m = wr*32 + i*16 + (l >> 4)*4 + r;
        int n = nh*64 + wc*32 + jn*16 + (l & 15);
        float v = acc[i][jn][r] + fb[n];
        float gl = 0.5f * v * (1.f + erff(v * 0.70710678118654752f));
        out[(size_t)(mt*64 + m)*DM + n] = gl;
      }
}

extern "C" void kernel_launch(void* const* d_in, const int* in_sizes, int n_in,
                              void* d_out, int out_size, void* d_ws, size_t ws_size,
                              hipStream_t stream){
  (void)in_sizes; (void)n_in; (void)out_size;
  const float* vectors  = (const float*)d_in[0];
  const int*   coords   = (const int*)d_in[1];
  const float* ln_w     = (const float*)d_in[2];
  const float* ln_b     = (const float*)d_in[3];
  const float* in_w     = (const float*)d_in[4];
  const float* conv_w   = (const float*)d_in[5];
  const float* conv_b   = (const float*)d_in[6];
  const float* dt_bias  = (const float*)d_in[7];
  const float* A_log    = (const float*)d_in[8];
  const float* D_skip   = (const float*)d_in[9];
  const float* norm_w   = (const float*)d_in[10];
  const float* out_w    = (const float*)d_in[11];
  const float* fuse_lw  = (const float*)d_in[12];
  const float* fuse_lb  = (const float*)d_in[13];
  const float* fuse_w   = (const float*)d_in[14];
  const float* fuse_b   = (const float*)d_in[15];
  float* out = (float*)d_out;

  char* p = (char*)d_ws;
  auto carve = [&](size_t bytes)->char*{
    char* r = p; p += (bytes + 255) & ~(size_t)255; return r;
  };
  int* idxb = (int*)carve((size_t)NDIR*LSEQ*4);
  unsigned long long* skey  = (unsigned long long*)carve((size_t)NDIR*LSEQ*8);
  unsigned long long* skey2 = (unsigned long long*)carve((size_t)NDIR*LSEQ*8);
  int* starts = (int*)carve((size_t)NDIR*1025*4);
  int* cursor = (int*)carve((size_t)NDIR*1024*4);
  u16* multi = (u16*)carve((size_t)LSEQ*768*2);
  u16* wbf_in   = (u16*)carve((size_t)NW0*2);
  u16* wbf_out  = (u16*)carve((size_t)NW1*2);
  u16* wbf_fuse = (u16*)carve((size_t)NW2*2);

  size_t fixed = (size_t)(p - (char*)d_ws);
  auto need = [&](int nd)->size_t{
    size_t s = 0; auto a = [&](size_t b){ s += (b + 255) & ~(size_t)255; };
    a((size_t)nd*LSEQ*DM*4);      // xbuf (f32 residual)
    a((size_t)nd*LSEQ*DI*2);      // zbuf (bf16)
    a((size_t)nd*LSEQ*CONVD*2);   // xact (bf16, conv'd)
    a((size_t)nd*NCHUNK*6*CONVD*2); // bnd (boundary rows)
    a((size_t)nd*LSEQ*NH*4);      // dtb (f32)
    a((size_t)nd*NCHUNK*NH*4);    // ltot (f32)
    a((size_t)nd*LSEQ*DI*2);      // y1 (bf16)
    a((size_t)nd*NCHUNK*NH*DSTATE*HD*2); // E (bf16, in-place scan)
    return s;
  };
  // adaptive batching: largest nd in {6,3,2,1} that fits the workspace
  int nd = 1;
  {
    const int cands[3] = {6, 3, 2};
    for (int ci = 0; ci < 3; ++ci){
      if (fixed + need(cands[ci]) <= ws_size){ nd = cands[ci]; break; }
    }
  }
  if (fixed + need(nd) > ws_size) return;  // insufficient workspace: no-op

  float* xbuf = (float*)carve((size_t)nd*LSEQ*DM*4);
  u16*   zbuf = (u16*)carve((size_t)nd*LSEQ*DI*2);
  u16*   xact = (u16*)carve((size_t)nd*LSEQ*CONVD*2);
  u16*   bnd  = (u16*)carve((size_t)nd*NCHUNK*6*CONVD*2);
  float* dtb  = (float*)carve((size_t)nd*LSEQ*NH*4);
  float* ltot = (float*)carve((size_t)nd*NCHUNK*NH*4);
  u16*   y1b  = (u16*)carve((size_t)nd*LSEQ*DI*2);
  u16*   Ebuf = (u16*)carve((size_t)nd*NCHUNK*NH*DSTATE*HD*2);

  k_cvt         <<<(NW0+NW1+NW2+255)/256, 256, 0, stream>>>(in_w, out_w, fuse_w, wbf_in, wbf_out, wbf_fuse, cursor);
  k_sort1       <<<(NDIR*LSEQ + 255)/256, 256, 0, stream>>>(coords, skey, cursor);
  k_sort_scan   <<<NDIR, 1024, 0, stream>>>(cursor, starts);
  k_sort_scatter<<<(NDIR*LSEQ + 255)/256, 256, 0, stream>>>(skey, skey2, cursor);
  k_sort_rank   <<<(NDIR*LSEQ + 255)/256, 256, 0, stream>>>(skey2, starts, idxb);

  for (int d_base = 0; d_base < NDIR; d_base += nd){
    for (int j = 0; j < 2; ++j){
      k_inproj<<<dim3(3, LSEQ/64, nd), 256, 0, stream>>>(xbuf, vectors, idxb, ln_w, ln_b, wbf_in, dt_bias,
                                                         conv_w, conv_b, zbuf, xact, bnd, dtb, d_base, j, nd);
      k_convfix<<<dim3(NCHUNK, nd), 256, 0, stream>>>(bnd, conv_w, conv_b, xact, d_base, j);
      k_chunk1<<<dim3(NCHUNK, nd), 256, 0, stream>>>(xact, dtb, A_log, D_skip,
                                                     Ebuf, y1b, ltot, d_base, j, nd);
      k_seq   <<<(nd*16384 + 255)/256, 256, 0, stream>>>(Ebuf, ltot, nd);
      k_chunk2<<<dim3(NCHUNK, nd), 256, 0, stream>>>(xact, dtb, A_log, zbuf, y1b, Ebuf,
                                                     norm_w, wbf_out, xbuf, vectors, idxb, multi, d_base, j, nd);
    }
  }
  k_fuse <<<dim3(2, LSEQ/64), 256, 0, stream>>>(multi, wbf_fuse, fuse_lw, fuse_lb, fuse_b, out);
}